// Round 7
// baseline (734.959 us; speedup 1.0000x reference)
//
#include <hip/hip_runtime.h>
#include <hip/hip_bf16.h>
#include <cstdint>
#include <cstddef>

#define NUSERS 200000
#define NITEMS 100000
#define UDIM 64
#define HID 128
#define ODIM 64
#define NREL 5

typedef unsigned short ushortT;
typedef __bf16 bf16x8 __attribute__((ext_vector_type(8)));
typedef float f32x4 __attribute__((ext_vector_type(4)));

static inline size_t align256(size_t x){ return (x + 255) & ~(size_t)255; }
static inline int imin(int a,int b){ return a<b?a:b; }

__device__ __forceinline__ unsigned short f2bf(float f){
  unsigned int u = __builtin_bit_cast(unsigned int, f);
  unsigned int r = (u + 0x7fffu + ((u>>16)&1u)) >> 16;   // RNE
  return (unsigned short)r;
}
__device__ __forceinline__ float b2f(unsigned short u){
  return __builtin_bit_cast(float, ((unsigned int)u)<<16);
}
__device__ __forceinline__ float blo(unsigned u){ return b2f((unsigned short)(u & 0xffff)); }
__device__ __forceinline__ float bhi(unsigned u){ return b2f((unsigned short)(u >> 16)); }
__device__ __forceinline__ void gld_lds16(const void* g, void* s){
  __builtin_amdgcn_global_load_lds((const __attribute__((address_space(1))) void*)g,
                                   (__attribute__((address_space(3))) void*)s, 16, 0, 0);
}

// ---------------- CSR build: segments keyed by (node, relation) ----------------

__global__ void count_edges_k(const int* __restrict__ src, const int* __restrict__ dst,
                              const int* __restrict__ et, int E,
                              int* __restrict__ cnt_i5, int* __restrict__ cnt_u5){
  int e = blockIdx.x*blockDim.x + threadIdx.x;
  if(e < E){
    int t = et[e];
    atomicAdd(&cnt_i5[dst[e]*NREL + t], 1);
    atomicAdd(&cnt_u5[src[e]*NREL + t], 1);
  }
}

__global__ __launch_bounds__(256) void scan_s1f(const int* __restrict__ c, int n, int* __restrict__ btot){
  int t = threadIdx.x;
  int base = blockIdx.x*1024 + t*4;
  int s = 0;
  #pragma unroll
  for(int j=0;j<4;++j){ int i = base+j; if(i<n) s += c[i]; }
  __shared__ int red[256];
  red[t] = s; __syncthreads();
  for(int o=128;o>0;o>>=1){ if(t<o) red[t]+=red[t+o]; __syncthreads(); }
  if(t==0) btot[blockIdx.x] = red[0];
}

__global__ __launch_bounds__(1024) void scan_s2(const int* __restrict__ btot, int nb,
                                                int* __restrict__ boff, int* __restrict__ total_out){
  __shared__ int sh[1024];
  int t = threadIdx.x;
  int v = (t<nb)? btot[t] : 0;
  sh[t] = v; __syncthreads();
  for(int o=1;o<1024;o<<=1){
    int add = (t>=o)? sh[t-o] : 0;
    __syncthreads();
    sh[t] += add;
    __syncthreads();
  }
  if(t<nb) boff[t] = sh[t]-v;
  if(t==1023) *total_out = sh[1023];
}

__global__ __launch_bounds__(256) void scan_s3f(const int* __restrict__ c, int n,
                                                const int* __restrict__ boff, int* __restrict__ off){
  int t = threadIdx.x, b = blockIdx.x;
  int base = b*1024 + t*4;
  int pre[4]; int s = 0;
  #pragma unroll
  for(int j=0;j<4;++j){
    int i = base+j; int d = (i<n)? c[i] : 0;
    pre[j] = s; s += d;
  }
  __shared__ int sh[256];
  sh[t] = s; __syncthreads();
  int inc = s;
  for(int o=1;o<256;o<<=1){
    int add = (t>=o)? sh[t-o] : 0;
    __syncthreads();
    sh[t] += add;
    __syncthreads();
  }
  int texcl = sh[t] - inc;
  int bo = boff[b];
  #pragma unroll
  for(int j=0;j<4;++j){
    int i = base+j;
    if(i<n) off[i] = bo + texcl + pre[j];
  }
}

__global__ void copy_int_k(const int* __restrict__ a, int* __restrict__ b, int n){
  int i = blockIdx.x*blockDim.x + threadIdx.x;
  if(i < n) b[i] = a[i];
}

// adj entries packed (src<<3)|rel; per-edge fp32 scale = 1/cnt(dst-segment)
__global__ void scatter_k(const int* __restrict__ src, const int* __restrict__ dst,
                          const int* __restrict__ et, int E,
                          int* __restrict__ cur_i5, int* __restrict__ cur_u5,
                          const int* __restrict__ cnt_i5, const int* __restrict__ cnt_u5,
                          int* __restrict__ adj_item, int* __restrict__ adj_user,
                          float* __restrict__ sc_item, float* __restrict__ sc_user){
  int e = blockIdx.x*blockDim.x + threadIdx.x;
  if(e < E){
    int s = src[e], d = dst[e], t = et[e];
    int k1 = d*NREL + t;
    int p1 = atomicAdd(&cur_i5[k1], 1);
    adj_item[p1] = (s<<3) | t;
    sc_item[p1] = 1.f/(float)cnt_i5[k1];
    int k2 = s*NREL + t;
    int p2 = atomicAdd(&cur_u5[k2], 1);
    adj_user[p2] = (d<<3) | t;
    sc_user[p2] = 1.f/(float)cnt_u5[k2];
  }
}

// ---------------- dtype prep ----------------

__global__ void f2bf4_k(const float4* __restrict__ a, uint2* __restrict__ b, int n4){
  int i = blockIdx.x*blockDim.x + threadIdx.x;
  if(i < n4){
    float4 v = a[i];
    uint2 o;
    o.x = (unsigned)f2bf(v.x) | ((unsigned)f2bf(v.y)<<16);
    o.y = (unsigned)f2bf(v.z) | ((unsigned)f2bf(v.w)<<16);
    b[i] = o;
  }
}

// BT[Dout][6*Din] = [root; W_0..W_4]^T   (layer-1 B)
__global__ void prep_bt_k(const float* __restrict__ root, const float* __restrict__ W,
                          ushortT* __restrict__ BT, int Din, int Dout){
  int K = 6*Din;
  int idx = blockIdx.x*blockDim.x + threadIdx.x;
  if(idx >= Dout*K) return;
  int n = idx / K, k = idx % K;
  float v = (k < Din) ? root[(size_t)k*Dout + n] : W[(size_t)(k-Din)*Dout + n];
  BT[idx] = f2bf(v);
}

// merged layer-2 B: BT[384][HID]; n<320 -> W[n/64][k][n%64]; n>=320 -> root[k][n-320]
__global__ void prep_btall_k(const float* __restrict__ W, const float* __restrict__ root,
                             ushortT* __restrict__ BT){
  int idx = blockIdx.x*blockDim.x + threadIdx.x;
  if(idx >= 384*HID) return;
  int n = idx / HID, k = idx % HID;
  float v;
  if(n < NREL*ODIM){
    int r = n / ODIM, c = n % ODIM;
    v = W[((size_t)r*HID + k)*ODIM + c];
  } else {
    v = root[(size_t)k*ODIM + (n - NREL*ODIM)];
  }
  BT[idx] = f2bf(v);
}

// BTm[R*C][K] : row n -> W[n/C][k][n%C]   (old H-tier msg weights)
__global__ void prep_w_k(const float* __restrict__ W, ushortT* __restrict__ BT,
                         int Kdim, int C, int total){
  int idx = blockIdx.x*blockDim.x + threadIdx.x;
  if(idx >= total) return;
  int n = idx / Kdim, k = idx % Kdim;
  int r = n / C, c = n % C;
  BT[idx] = f2bf(W[((size_t)r*Kdim + k)*C + c]);
}

// BTr[C][K] : row n -> root[k][n]
__global__ void prep_r_k(const float* __restrict__ root, ushortT* __restrict__ BT,
                         int Kdim, int C){
  int idx = blockIdx.x*blockDim.x + threadIdx.x;
  if(idx >= C*Kdim) return;
  int n = idx / Kdim, k = idx % Kdim;
  BT[idx] = f2bf(root[(size_t)k*C + n]);
}

// ---------------- layer-1 aggregation (D=64): 4 edges/iter via 16-lane groups ----------------

__global__ __launch_bounds__(256) void agg_m64_k(const ushortT* __restrict__ xsrc,
    const int* __restrict__ adj, const int* __restrict__ off5,
    ushortT* __restrict__ Mbuf, int lo, int cn)
{
  int wid  = (int)((blockIdx.x*(size_t)blockDim.x + threadIdx.x) >> 6);
  int l = threadIdx.x & 63;
  if(wid >= cn) return;
  int node = lo + wid;
  int g = l >> 4, sub = l & 15;
  int base = node*NREL;
  int offs[6];
  #pragma unroll
  for(int r=0;r<6;++r) offs[r] = off5[base+r];
  ushortT* mp = Mbuf + (size_t)wid*(NREL*UDIM);
  #pragma unroll
  for(int r=0;r<NREL;++r){
    int e0 = offs[r], e1 = offs[r+1];
    int c = e1 - e0;
    if(c == 0){
      if(l < 16){ uint2 z = {0u,0u}; *(uint2*)(mp + r*UDIM + sub*4) = z; }
      continue;
    }
    float a0=0.f,a1=0.f,a2=0.f,a3=0.f;
    for(int e = e0 + g; e < e1; e += 4){
      int p = adj[e] >> 3;
      uint2 u = *(const uint2*)(xsrc + (size_t)p*UDIM + sub*4);
      a0 += blo(u.x); a1 += bhi(u.x); a2 += blo(u.y); a3 += bhi(u.y);
    }
    a0 += __shfl_xor(a0,16); a1 += __shfl_xor(a1,16); a2 += __shfl_xor(a2,16); a3 += __shfl_xor(a3,16);
    a0 += __shfl_xor(a0,32); a1 += __shfl_xor(a1,32); a2 += __shfl_xor(a2,32); a3 += __shfl_xor(a3,32);
    if(l < 16){
      float sc = 1.f/(float)c;
      uint2 o;
      o.x = (unsigned)f2bf(a0*sc) | ((unsigned)f2bf(a1*sc)<<16);
      o.y = (unsigned)f2bf(a2*sc) | ((unsigned)f2bf(a3*sc)<<16);
      *(uint2*)(mp + r*UDIM + sub*4) = o;
    }
  }
}

// ---------------- layer-2 H aggregation (stride-parameterized) ----------------

__global__ __launch_bounds__(256) void agg_h_k(const ushortT* __restrict__ msg, int msgStride,
    const ushortT* __restrict__ root, int rootStride,
    const int* __restrict__ adj, const float* __restrict__ adjsc,
    const int* __restrict__ off5, const float* __restrict__ bias,
    float* __restrict__ outp, int n)
{
  int wid  = (int)((blockIdx.x*(size_t)blockDim.x + threadIdx.x) >> 6);
  int l = threadIdx.x & 63;
  if(wid >= n) return;
  int g = l >> 4, sub = l & 15;
  int e0 = off5[wid*NREL], e1 = off5[wid*NREL + NREL];
  float a0=0.f,a1=0.f,a2=0.f,a3=0.f;
  int e = e0 + g;
  for(; e + 4 < e1; e += 8){
    int ad1 = adj[e];   float sc1 = adjsc[e];
    int ad2 = adj[e+4]; float sc2 = adjsc[e+4];
    uint2 u = *(const uint2*)(msg + (size_t)(ad1>>3)*msgStride + (ad1&7)*ODIM + sub*4);
    uint2 v = *(const uint2*)(msg + (size_t)(ad2>>3)*msgStride + (ad2&7)*ODIM + sub*4);
    a0 += blo(u.x)*sc1; a1 += bhi(u.x)*sc1; a2 += blo(u.y)*sc1; a3 += bhi(u.y)*sc1;
    a0 += blo(v.x)*sc2; a1 += bhi(v.x)*sc2; a2 += blo(v.y)*sc2; a3 += bhi(v.y)*sc2;
  }
  if(e < e1){
    int ad1 = adj[e]; float sc1 = adjsc[e];
    uint2 u = *(const uint2*)(msg + (size_t)(ad1>>3)*msgStride + (ad1&7)*ODIM + sub*4);
    a0 += blo(u.x)*sc1; a1 += bhi(u.x)*sc1; a2 += blo(u.y)*sc1; a3 += bhi(u.y)*sc1;
  }
  a0 += __shfl_xor(a0,16); a1 += __shfl_xor(a1,16); a2 += __shfl_xor(a2,16); a3 += __shfl_xor(a3,16);
  a0 += __shfl_xor(a0,32); a1 += __shfl_xor(a1,32); a2 += __shfl_xor(a2,32); a3 += __shfl_xor(a3,32);
  if(l < 16){
    uint2 rt = *(const uint2*)(root + (size_t)wid*rootStride + sub*4);
    float4 bv = *(const float4*)(bias + sub*4);
    float4 o;
    o.x = a0 + blo(rt.x) + bv.x;
    o.y = a1 + bhi(rt.x) + bv.y;
    o.z = a2 + blo(rt.y) + bv.z;
    o.w = a3 + bhi(rt.y) + bv.w;
    *(float4*)(outp + (size_t)wid*ODIM + sub*4) = o;
  }
}

// ---------------- fallback M-scheme agg (layer 2, only if ws too small) ----------------

template<int D>
__global__ __launch_bounds__(256) void agg_m_k(const ushortT* __restrict__ xsrc,
    const ushortT* __restrict__ xdst, const int* __restrict__ adj,
    const int* __restrict__ off5, ushortT* __restrict__ Mbuf, int lo, int cn)
{
  int wid  = (int)((blockIdx.x*(size_t)blockDim.x + threadIdx.x) >> 6);
  int lane = threadIdx.x & 63;
  if(wid >= cn) return;
  int node = lo + wid;
  constexpr int V = D/64;
  ushortT* mp = Mbuf + (size_t)wid*(6*D);
  if(V==2) *(unsigned*)(mp + lane*2) = *(const unsigned*)(xdst + (size_t)node*D + lane*2);
  else     mp[lane] = xdst[(size_t)node*D + lane];
  #pragma unroll
  for(int r=0;r<NREL;++r){
    int base = node*NREL + r;
    int e0 = off5[base], e1 = off5[base+1];
    float s0 = 0.f, s1 = 0.f;
    for(int e=e0; e<e1; ++e){
      int p = adj[e] >> 3;
      if(V==2){
        unsigned u = *(const unsigned*)(xsrc + (size_t)p*D + lane*2);
        s0 += blo(u); s1 += bhi(u);
      } else {
        s0 += b2f(xsrc[(size_t)p*D + lane]);
      }
    }
    int c = e1 - e0;
    float sc = 1.f/(float)(c>0? c:1);
    if(V==2){
      unsigned o = (unsigned)f2bf(s0*sc) | ((unsigned)f2bf(s1*sc)<<16);
      *(unsigned*)(mp + D + r*D + lane*2) = o;
    } else {
      mp[D + r*D + lane] = f2bf(s0*sc);
    }
  }
}

// ---------------- B-resident MFMA GEMM: B fully in LDS, A direct global->VGPR ----------------
// No barriers in the M-tile loop. 512 threads = 8 waves (2 row x 4 col).
// A col k: k<KSPLIT -> A0 (lda0) else A1 (lda1). BT is [BN][K] row-major bf16.

template<int BM, int BN, int K, int KSPLIT, bool OUTBF, bool RELU>
__global__ __launch_bounds__(512) void gemm3_k(
    const ushortT* __restrict__ A0, int lda0,
    const ushortT* __restrict__ A1, int lda1,
    const ushortT* __restrict__ BT,
    const float* __restrict__ bias,
    void* __restrict__ Cv, int ldc, int M, int ntiles)
{
  constexpr int NK  = K/32;       // MFMA K-steps
  constexpr int FR  = BM/32;      // A frags per wave (wave rows = BM/2)
  constexpr int FC  = BN/64;      // B frags per wave (wave cols = BN/4)
  constexpr int ROWB= K*2;        // bytes per B row
  constexpr int KB8 = K/8;        // 16B chunks per B row
  constexpr int NCH = BN*KB8;     // total 16B chunks (NCH%512==0 for our shapes)
  __shared__ alignas(16) unsigned char sB[(size_t)BN*ROWB];   // 96 KB for both shapes

  const int tid = threadIdx.x;
  const int w = tid >> 6, l = tid & 63;
  const int wr = w >> 2, wc = w & 3;

  // ---- stage all of B once: linear LDS dest, inverse-swizzled global source ----
  #pragma unroll
  for(int it = 0; it < NCH/512; ++it){
    int c = it*512 + tid;
    int r = c / KB8;
    int jb = (c % KB8) * 16;
    const unsigned char* gp = (const unsigned char*)BT + (size_t)r*ROWB + (jb ^ ((r&7)<<4));
    gld_lds16(gp, sB + (size_t)(it*512 + w*64)*16);
  }
  __syncthreads();

  for(int tile = blockIdx.x; tile < ntiles; tile += gridDim.x){
    const int row0 = tile * BM;
    f32x4 acc[FR][FC];
    #pragma unroll
    for(int i=0;i<FR;++i)
      #pragma unroll
      for(int j=0;j<FC;++j) acc[i][j] = (f32x4){0.f,0.f,0.f,0.f};

    const ushortT* pA0[FR]; const ushortT* pA1[FR];
    #pragma unroll
    for(int i=0;i<FR;++i){
      int r = row0 + wr*(BM/2) + i*16 + (l&15);
      r = (r < M)? r : (M-1);
      pA0[i] = A0 + (size_t)r*lda0 + (l>>4)*8;
      pA1[i] = A1 + (size_t)r*lda1 + (l>>4)*8;
    }
    #pragma unroll
    for(int t=0;t<NK;++t){
      const int k0 = t*32;
      bf16x8 af[FR], bfr[FC];
      #pragma unroll
      for(int i=0;i<FR;++i){
        const ushortT* p = (k0 < KSPLIT) ? (pA0[i] + k0) : (pA1[i] + (k0 - KSPLIT));
        af[i] = *reinterpret_cast<const bf16x8*>(p);
      }
      #pragma unroll
      for(int j=0;j<FC;++j){
        int cN = wc*(BN/4) + j*16 + (l&15);
        bfr[j] = *reinterpret_cast<const bf16x8*>(
            sB + (size_t)cN*ROWB + ((k0*2 + (l>>4)*16) ^ ((cN&7)<<4)));
      }
      #pragma unroll
      for(int i=0;i<FR;++i)
        #pragma unroll
        for(int j=0;j<FC;++j)
          acc[i][j] = __builtin_amdgcn_mfma_f32_16x16x32_bf16(af[i], bfr[j], acc[i][j], 0, 0, 0);
    }
    #pragma unroll
    for(int i=0;i<FR;++i){
      #pragma unroll
      for(int rr=0;rr<4;++rr){
        int grow = row0 + wr*(BM/2) + i*16 + (l>>4)*4 + rr;
        if(grow >= M) continue;
        #pragma unroll
        for(int j=0;j<FC;++j){
          int col = wc*(BN/4) + j*16 + (l&15);
          float v = acc[i][j][rr];
          if(bias) v += bias[col];
          if(RELU) v = fmaxf(v, 0.f);
          if(OUTBF) ((ushortT*)Cv)[(size_t)grow*ldc + col] = f2bf(v);
          else      ((float*)Cv)[(size_t)grow*ldc + col] = v;
        }
      }
    }
  }
}

// ---------------- legacy 2-buffer GEMM (fallback tiers only) ----------------

template<int BN, bool OUTBF, bool RELU>
__global__ __launch_bounds__(256) void gemm2_k(
    const ushortT* __restrict__ A0, int lda0,
    const ushortT* __restrict__ A1, int lda1, int KSPLIT,
    const ushortT* __restrict__ BT, int K,
    const float* __restrict__ bias,
    void* __restrict__ Cv, int ldc, int M)
{
  constexpr int BM = 128;
  constexpr int WCN  = (BN==128)? 2 : 1;
  constexpr int WROWS= (BN==128)? 64 : 32;
  constexpr int FR   = WROWS/16;
  constexpr int FC   = 4;
  __shared__ alignas(16) unsigned char sA[BM*128];
  __shared__ alignas(16) unsigned char sB[BN*128];

  const int tid = threadIdx.x;
  const int w = tid >> 6, l = tid & 63;
  const int wr = w / WCN, wc = w % WCN;
  const int row0 = blockIdx.x * BM;
  const int col0 = blockIdx.y * BN;
  const ushortT* BTp = BT + (size_t)col0 * K;

  f32x4 acc[FR][FC];
  #pragma unroll
  for(int i=0;i<FR;++i)
    #pragma unroll
    for(int j=0;j<FC;++j) acc[i][j] = (f32x4){0.f,0.f,0.f,0.f};

  const int lr  = l >> 3;
  const int lc  = (l & 7) * 16;

  for(int k0=0; k0<K; k0+=64){
    const ushortT* Ab = (k0 < KSPLIT) ? A0 : A1;
    const int ldab    = (k0 < KSPLIT) ? lda0 : lda1;
    const int kc      = (k0 < KSPLIT) ? k0 : (k0 - KSPLIT);
    #pragma unroll
    for(int j=0;j<4;++j){
      int r = w*32 + j*8 + lr;
      int grow = row0 + r; grow = (grow < M) ? grow : (M-1);
      const unsigned char* gp = (const unsigned char*)(Ab + (size_t)grow*ldab + kc) + (lc ^ ((r&7)<<4));
      gld_lds16(gp, sA + (w*32 + j*8)*128);
    }
    #pragma unroll
    for(int j=0;j<BN/32;++j){
      int r = w*(BN/4) + j*8 + lr;
      const unsigned char* gp = (const unsigned char*)(BTp + (size_t)r*K + k0) + (lc ^ ((r&7)<<4));
      gld_lds16(gp, sB + (w*(BN/4) + j*8)*128);
    }
    __syncthreads();
    #pragma unroll
    for(int kk=0;kk<2;++kk){
      const int cb = kk*64 + (l>>4)*16;
      bf16x8 af[FR], bfr[FC];
      #pragma unroll
      for(int i=0;i<FR;++i){
        int r = wr*WROWS + i*16 + (l&15);
        af[i] = *reinterpret_cast<const bf16x8*>(sA + r*128 + (cb ^ ((r&7)<<4)));
      }
      #pragma unroll
      for(int j=0;j<FC;++j){
        int c = wc*64 + j*16 + (l&15);
        bfr[j] = *reinterpret_cast<const bf16x8*>(sB + c*128 + (cb ^ ((c&7)<<4)));
      }
      #pragma unroll
      for(int i=0;i<FR;++i)
        #pragma unroll
        for(int j=0;j<FC;++j)
          acc[i][j] = __builtin_amdgcn_mfma_f32_16x16x32_bf16(af[i], bfr[j], acc[i][j], 0, 0, 0);
    }
    __syncthreads();
  }
  #pragma unroll
  for(int i=0;i<FR;++i){
    #pragma unroll
    for(int rr=0;rr<4;++rr){
      int grow = row0 + wr*WROWS + i*16 + (l>>4)*4 + rr;
      if(grow >= M) continue;
      #pragma unroll
      for(int j=0;j<FC;++j){
        int col = wc*64 + j*16 + (l&15);
        float v = acc[i][j][rr];
        if(bias) v += bias[col0 + col];
        if(RELU) v = fmaxf(v, 0.f);
        if(OUTBF) ((ushortT*)Cv)[(size_t)grow*ldc + col0 + col] = f2bf(v);
        else      ((float*)Cv)[(size_t)grow*ldc + col0 + col] = v;
      }
    }
  }
}

// ---------------- host ----------------

extern "C" void kernel_launch(void* const* d_in, const int* in_sizes, int n_in,
                              void* d_out, int out_size, void* d_ws, size_t ws_size,
                              hipStream_t stream){
  const float* x_user   = (const float*)d_in[0];
  const float* x_item   = (const float*)d_in[1];
  const int*   ei       = (const int*)d_in[2];
  const int*   et       = (const int*)d_in[3];
  const float* W1_ui    = (const float*)d_in[4];
  const float* root1_ui = (const float*)d_in[5];
  const float* b1_ui    = (const float*)d_in[6];
  const float* W1_iu    = (const float*)d_in[7];
  const float* root1_iu = (const float*)d_in[8];
  const float* b1_iu    = (const float*)d_in[9];
  const float* W2_ui    = (const float*)d_in[10];
  const float* root2_ui = (const float*)d_in[11];
  const float* b2_ui    = (const float*)d_in[12];
  const float* W2_iu    = (const float*)d_in[13];
  const float* root2_iu = (const float*)d_in[14];
  const float* b2_iu    = (const float*)d_in[15];
  const int E = in_sizes[3];
  const int* src = ei;
  const int* dst = ei + E;
  float* out = (float*)d_out;

  const int NI5 = NITEMS*NREL, NU5 = NUSERS*NREL;

  uint8_t* ws = (uint8_t*)d_ws;
  size_t o = 0;
  auto alloc = [&](size_t bytes){ size_t r = o; o = align256(o + bytes); return r; };
  int* cnt_i5 = (int*)(ws + alloc((size_t)NI5*4));
  int* cnt_u5 = (int*)(ws + alloc((size_t)NU5*4));
  int* off_i5 = (int*)(ws + alloc((size_t)(NI5+1)*4));
  int* off_u5 = (int*)(ws + alloc((size_t)(NU5+1)*4));
  int* cur_i5 = (int*)(ws + alloc((size_t)NI5*4));
  int* cur_u5 = (int*)(ws + alloc((size_t)NU5*4));
  int* adj_item = (int*)(ws + alloc((size_t)E*4));
  int* adj_user = (int*)(ws + alloc((size_t)E*4));
  float* sc_item = (float*)(ws + alloc((size_t)E*4));
  float* sc_user = (float*)(ws + alloc((size_t)E*4));
  int* btot     = (int*)(ws + alloc(1024*4));
  int* boff     = (int*)(ws + alloc(1024*4));
  ushortT* xu_bf = (ushortT*)(ws + alloc((size_t)NUSERS*UDIM*2));
  ushortT* xi_bf = (ushortT*)(ws + alloc((size_t)NITEMS*UDIM*2));
  ushortT* h1u   = (ushortT*)(ws + alloc((size_t)NUSERS*HID*2));
  ushortT* h1i   = (ushortT*)(ws + alloc((size_t)NITEMS*HID*2));
  ushortT* BT1ui = (ushortT*)(ws + alloc((size_t)HID*(6*UDIM)*2));
  ushortT* BT1iu = (ushortT*)(ws + alloc((size_t)HID*(6*UDIM)*2));
  ushortT* BTallU = (ushortT*)(ws + alloc((size_t)384*HID*2));   // [W2_ui r0..4 | root2_iu]
  ushortT* BTallI = (ushortT*)(ws + alloc((size_t)384*HID*2));   // [W2_iu r0..4 | root2_ui]
  ushortT* BT2ui = (ushortT*)(ws + alloc((size_t)ODIM*(6*HID)*2));   // M-tier fallback
  ushortT* BT2iu = (ushortT*)(ws + alloc((size_t)ODIM*(6*HID)*2));
  ushortT* BTm2ui = (ushortT*)(ws + alloc((size_t)NREL*ODIM*HID*2)); // old-H tier
  ushortT* BTm2iu = (ushortT*)(ws + alloc((size_t)NREL*ODIM*HID*2));
  ushortT* BTr2ui = (ushortT*)(ws + alloc((size_t)ODIM*HID*2));
  ushortT* BTr2iu = (ushortT*)(ws + alloc((size_t)ODIM*HID*2));
  size_t bigoff = o;
  size_t avail = (ws_size > bigoff)? (ws_size - bigoff) : 0;
  uint8_t* big = ws + bigoff;

  size_t needHM = align256((size_t)NUSERS*384*2) + align256((size_t)NITEMS*384*2);
  size_t needH  = align256((size_t)NUSERS*NREL*ODIM*2) + align256((size_t)NITEMS*ODIM*2);
  bool useHM = (avail >= needHM + 4096);
  bool useH  = (avail >= needH + 4096);

  // ---- CSR build keyed by (node, relation) ----
  hipMemsetAsync(cnt_i5, 0, (size_t)NI5*4, stream);
  hipMemsetAsync(cnt_u5, 0, (size_t)NU5*4, stream);
  int eb = (E+255)/256;
  count_edges_k<<<eb,256,0,stream>>>(src,dst,et,E,cnt_i5,cnt_u5);

  int nbI = (NI5+1023)/1024, nbU = (NU5+1023)/1024;
  scan_s1f<<<nbI,256,0,stream>>>(cnt_i5, NI5, btot);
  scan_s2<<<1,1024,0,stream>>>(btot, nbI, boff, off_i5+NI5);
  scan_s3f<<<nbI,256,0,stream>>>(cnt_i5, NI5, boff, off_i5);
  scan_s1f<<<nbU,256,0,stream>>>(cnt_u5, NU5, btot);
  scan_s2<<<1,1024,0,stream>>>(btot, nbU, boff, off_u5+NU5);
  scan_s3f<<<nbU,256,0,stream>>>(cnt_u5, NU5, boff, off_u5);

  copy_int_k<<<(NI5+255)/256,256,0,stream>>>(off_i5, cur_i5, NI5);
  copy_int_k<<<(NU5+255)/256,256,0,stream>>>(off_u5, cur_u5, NU5);
  scatter_k<<<eb,256,0,stream>>>(src,dst,et,E,cur_i5,cur_u5,cnt_i5,cnt_u5,
                                 adj_item,adj_user,sc_item,sc_user);

  // ---- dtype prep ----
  {
    int n4 = NUSERS*UDIM/4;
    f2bf4_k<<<(n4+255)/256,256,0,stream>>>((const float4*)x_user, (uint2*)xu_bf, n4);
    n4 = NITEMS*UDIM/4;
    f2bf4_k<<<(n4+255)/256,256,0,stream>>>((const float4*)x_item, (uint2*)xi_bf, n4);
  }
  prep_bt_k<<<(HID*6*UDIM+255)/256,256,0,stream>>>(root1_ui, W1_ui, BT1ui, UDIM, HID);
  prep_bt_k<<<(HID*6*UDIM+255)/256,256,0,stream>>>(root1_iu, W1_iu, BT1iu, UDIM, HID);
  if(useHM){
    prep_btall_k<<<(384*HID+255)/256,256,0,stream>>>(W2_ui, root2_iu, BTallU);
    prep_btall_k<<<(384*HID+255)/256,256,0,stream>>>(W2_iu, root2_ui, BTallI);
  } else if(useH){
    int tot = NREL*ODIM*HID;
    prep_w_k<<<(tot+255)/256,256,0,stream>>>(W2_ui, BTm2ui, HID, ODIM, tot);
    prep_w_k<<<(tot+255)/256,256,0,stream>>>(W2_iu, BTm2iu, HID, ODIM, tot);
    prep_r_k<<<(ODIM*HID+255)/256,256,0,stream>>>(root2_ui, BTr2ui, HID, ODIM);
    prep_r_k<<<(ODIM*HID+255)/256,256,0,stream>>>(root2_iu, BTr2iu, HID, ODIM);
  } else {
    prep_bt_k<<<(ODIM*6*HID+255)/256,256,0,stream>>>(root2_ui, W2_ui, BT2ui, HID, ODIM);
    prep_bt_k<<<(ODIM*6*HID+255)/256,256,0,stream>>>(root2_iu, W2_iu, BT2iu, HID, ODIM);
  }

  // ---- layer 1: M-scheme agg + B-resident GEMM (split-A: dst feats | means) ----
  {
    ushortT* Mbuf = (ushortT*)big;
    long long c1 = (long long)(avail / ((size_t)NREL*UDIM*2));
    int CH = (int)(c1 > NUSERS ? NUSERS : c1); CH &= ~127; if(CH < 128) CH = 128;
    for(int lo=0; lo<NITEMS; lo+=CH){
      int cn = imin(CH, NITEMS-lo);
      int nt = (cn+127)/128;
      agg_m64_k<<<(cn+3)/4,256,0,stream>>>(xu_bf, adj_item, off_i5 + lo*NREL, Mbuf, 0, cn);
      gemm3_k<128,128,384,64,true,true><<<imin(256,nt),512,0,stream>>>(
          xi_bf + (size_t)lo*UDIM, UDIM, Mbuf, NREL*UDIM,
          BT1ui, b1_ui, h1i + (size_t)lo*HID, HID, cn, nt);
    }
    for(int lo=0; lo<NUSERS; lo+=CH){
      int cn = imin(CH, NUSERS-lo);
      int nt = (cn+127)/128;
      agg_m64_k<<<(cn+3)/4,256,0,stream>>>(xi_bf, adj_user, off_u5 + lo*NREL, Mbuf, 0, cn);
      gemm3_k<128,128,384,64,true,true><<<imin(256,nt),512,0,stream>>>(
          xu_bf + (size_t)lo*UDIM, UDIM, Mbuf, NREL*UDIM,
          BT1iu, b1_iu, h1u + (size_t)lo*HID, HID, cn, nt);
    }
  }

  // ---- layer 2 ----
  float* user2 = out;
  float* item2 = out + (size_t)NUSERS*ODIM;
  if(useHM){
    ushortT* Hall_u = (ushortT*)big;                                    // [NUSERS][384]
    ushortT* Hall_i = (ushortT*)(big + align256((size_t)NUSERS*384*2)); // [NITEMS][384]
    int ntu = (NUSERS+63)/64, nti = (NITEMS+63)/64;
    gemm3_k<64,384,128,0,true,false><<<256,512,0,stream>>>(
        h1u, HID, h1u, HID, BTallU, nullptr, Hall_u, 384, NUSERS, ntu);
    gemm3_k<64,384,128,0,true,false><<<256,512,0,stream>>>(
        h1i, HID, h1i, HID, BTallI, nullptr, Hall_i, 384, NITEMS, nti);
    agg_h_k<<<(NITEMS+3)/4,256,0,stream>>>(Hall_u, 384, Hall_i + NREL*ODIM, 384,
        adj_item, sc_item, off_i5, b2_ui, item2, NITEMS);
    agg_h_k<<<(NUSERS+3)/4,256,0,stream>>>(Hall_i, 384, Hall_u + NREL*ODIM, 384,
        adj_user, sc_user, off_u5, b2_iu, user2, NUSERS);
  } else if(useH){
    ushortT* Hmsg_u = (ushortT*)big;
    ushortT* Hroot_i = (ushortT*)(big + align256((size_t)NUSERS*NREL*ODIM*2));
    gemm2_k<ODIM,true,false><<<dim3((NUSERS+127)/128, NREL),256,0,stream>>>(
        h1u, HID, h1u, HID, HID, BTm2ui, HID, nullptr, Hmsg_u, NREL*ODIM, NUSERS);
    gemm2_k<ODIM,true,false><<<dim3((NITEMS+127)/128, 1),256,0,stream>>>(
        h1i, HID, h1i, HID, HID, BTr2ui, HID, nullptr, Hroot_i, ODIM, NITEMS);
    agg_h_k<<<(NITEMS+3)/4,256,0,stream>>>(Hmsg_u, NREL*ODIM, Hroot_i, ODIM,
        adj_item, sc_item, off_i5, b2_ui, item2, NITEMS);
    ushortT* Hmsg_i = (ushortT*)big;
    ushortT* Hroot_u = (ushortT*)(big + align256((size_t)NITEMS*NREL*ODIM*2));
    gemm2_k<ODIM,true,false><<<dim3((NITEMS+127)/128, NREL),256,0,stream>>>(
        h1i, HID, h1i, HID, HID, BTm2iu, HID, nullptr, Hmsg_i, NREL*ODIM, NITEMS);
    gemm2_k<ODIM,true,false><<<dim3((NUSERS+127)/128, 1),256,0,stream>>>(
        h1u, HID, h1u, HID, HID, BTr2iu, HID, nullptr, Hroot_u, ODIM, NUSERS);
    agg_h_k<<<(NUSERS+3)/4,256,0,stream>>>(Hmsg_i, NREL*ODIM, Hroot_u, ODIM,
        adj_user, sc_user, off_u5, b2_iu, user2, NUSERS);
  } else {
    ushortT* Mbuf = (ushortT*)big;
    long long c2 = (long long)(avail / ((size_t)6*HID*2));
    int CH = (int)(c2 > NUSERS ? NUSERS : c2); CH &= ~127; if(CH < 128) CH = 128;
    for(int lo=0; lo<NITEMS; lo+=CH){
      int cn = imin(CH, NITEMS-lo);
      agg_m_k<HID><<<(cn+3)/4,256,0,stream>>>(h1u, h1i, adj_item, off_i5, Mbuf, lo, cn);
      gemm2_k<ODIM,false,false><<<dim3((cn+127)/128,1),256,0,stream>>>(
          Mbuf, 6*HID, Mbuf, 6*HID, 6*HID, BT2ui, 6*HID, b2_ui, item2 + (size_t)lo*ODIM, ODIM, cn);
    }
    for(int lo=0; lo<NUSERS; lo+=CH){
      int cn = imin(CH, NUSERS-lo);
      agg_m_k<HID><<<(cn+3)/4,256,0,stream>>>(h1i, h1u, adj_user, off_u5, Mbuf, lo, cn);
      gemm2_k<ODIM,false,false><<<dim3((cn+127)/128,1),256,0,stream>>>(
          Mbuf, 6*HID, Mbuf, 6*HID, 6*HID, BT2iu, 6*HID, b2_iu, user2 + (size_t)lo*ODIM, ODIM, cn);
    }
  }
}

// Round 8
// 704.444 us; speedup vs baseline: 1.0433x; 1.0433x over previous
//
#include <hip/hip_runtime.h>
#include <hip/hip_bf16.h>
#include <cstdint>
#include <cstddef>

#define NUSERS 200000
#define NITEMS 100000
#define UDIM 64
#define HID 128
#define ODIM 64
#define NREL 5

typedef unsigned short ushortT;
typedef __bf16 bf16x8 __attribute__((ext_vector_type(8)));
typedef float f32x4 __attribute__((ext_vector_type(4)));

static inline size_t align256(size_t x){ return (x + 255) & ~(size_t)255; }
static inline int imin(int a,int b){ return a<b?a:b; }

__device__ __forceinline__ unsigned short f2bf(float f){
  unsigned int u = __builtin_bit_cast(unsigned int, f);
  unsigned int r = (u + 0x7fffu + ((u>>16)&1u)) >> 16;   // RNE
  return (unsigned short)r;
}
__device__ __forceinline__ float b2f(unsigned short u){
  return __builtin_bit_cast(float, ((unsigned int)u)<<16);
}
__device__ __forceinline__ float blo(unsigned u){ return b2f((unsigned short)(u & 0xffff)); }
__device__ __forceinline__ float bhi(unsigned u){ return b2f((unsigned short)(u >> 16)); }
__device__ __forceinline__ void gld_lds16(const void* g, void* s){
  __builtin_amdgcn_global_load_lds((const __attribute__((address_space(1))) void*)g,
                                   (__attribute__((address_space(3))) void*)s, 16, 0, 0);
}

// ---------------- CSR build: segments keyed by (node, relation) ----------------

__global__ void count_edges_k(const int* __restrict__ src, const int* __restrict__ dst,
                              const int* __restrict__ et, int E,
                              int* __restrict__ cnt_i5, int* __restrict__ cnt_u5){
  int e = blockIdx.x*blockDim.x + threadIdx.x;
  if(e < E){
    int t = et[e];
    atomicAdd(&cnt_i5[dst[e]*NREL + t], 1);
    atomicAdd(&cnt_u5[src[e]*NREL + t], 1);
  }
}

__global__ __launch_bounds__(256) void scan_s1f(const int* __restrict__ c, int n, int* __restrict__ btot){
  int t = threadIdx.x;
  int base = blockIdx.x*1024 + t*4;
  int s = 0;
  #pragma unroll
  for(int j=0;j<4;++j){ int i = base+j; if(i<n) s += c[i]; }
  __shared__ int red[256];
  red[t] = s; __syncthreads();
  for(int o=128;o>0;o>>=1){ if(t<o) red[t]+=red[t+o]; __syncthreads(); }
  if(t==0) btot[blockIdx.x] = red[0];
}

__global__ __launch_bounds__(1024) void scan_s2(const int* __restrict__ btot, int nb,
                                                int* __restrict__ boff, int* __restrict__ total_out){
  __shared__ int sh[1024];
  int t = threadIdx.x;
  int v = (t<nb)? btot[t] : 0;
  sh[t] = v; __syncthreads();
  for(int o=1;o<1024;o<<=1){
    int add = (t>=o)? sh[t-o] : 0;
    __syncthreads();
    sh[t] += add;
    __syncthreads();
  }
  if(t<nb) boff[t] = sh[t]-v;
  if(t==1023) *total_out = sh[1023];
}

__global__ __launch_bounds__(256) void scan_s3f(const int* __restrict__ c, int n,
                                                const int* __restrict__ boff, int* __restrict__ off){
  int t = threadIdx.x, b = blockIdx.x;
  int base = b*1024 + t*4;
  int pre[4]; int s = 0;
  #pragma unroll
  for(int j=0;j<4;++j){
    int i = base+j; int d = (i<n)? c[i] : 0;
    pre[j] = s; s += d;
  }
  __shared__ int sh[256];
  sh[t] = s; __syncthreads();
  int inc = s;
  for(int o=1;o<256;o<<=1){
    int add = (t>=o)? sh[t-o] : 0;
    __syncthreads();
    sh[t] += add;
    __syncthreads();
  }
  int texcl = sh[t] - inc;
  int bo = boff[b];
  #pragma unroll
  for(int j=0;j<4;++j){
    int i = base+j;
    if(i<n) off[i] = bo + texcl + pre[j];
  }
}

__global__ void copy_int_k(const int* __restrict__ a, int* __restrict__ b, int n){
  int i = blockIdx.x*blockDim.x + threadIdx.x;
  if(i < n) b[i] = a[i];
}

// adj entries packed (src<<3)|rel; per-edge fp32 scale = 1/cnt(dst-segment)
__global__ void scatter_k(const int* __restrict__ src, const int* __restrict__ dst,
                          const int* __restrict__ et, int E,
                          int* __restrict__ cur_i5, int* __restrict__ cur_u5,
                          const int* __restrict__ cnt_i5, const int* __restrict__ cnt_u5,
                          int* __restrict__ adj_item, int* __restrict__ adj_user,
                          float* __restrict__ sc_item, float* __restrict__ sc_user){
  int e = blockIdx.x*blockDim.x + threadIdx.x;
  if(e < E){
    int s = src[e], d = dst[e], t = et[e];
    int k1 = d*NREL + t;
    int p1 = atomicAdd(&cur_i5[k1], 1);
    adj_item[p1] = (s<<3) | t;
    sc_item[p1] = 1.f/(float)cnt_i5[k1];
    int k2 = s*NREL + t;
    int p2 = atomicAdd(&cur_u5[k2], 1);
    adj_user[p2] = (d<<3) | t;
    sc_user[p2] = 1.f/(float)cnt_u5[k2];
  }
}

// ---------------- dtype prep ----------------

__global__ void f2bf4_k(const float4* __restrict__ a, uint2* __restrict__ b, int n4){
  int i = blockIdx.x*blockDim.x + threadIdx.x;
  if(i < n4){
    float4 v = a[i];
    uint2 o;
    o.x = (unsigned)f2bf(v.x) | ((unsigned)f2bf(v.y)<<16);
    o.y = (unsigned)f2bf(v.z) | ((unsigned)f2bf(v.w)<<16);
    b[i] = o;
  }
}

// BT[Dout][6*Din] = [root; W_0..W_4]^T   (layer-1 B)
__global__ void prep_bt_k(const float* __restrict__ root, const float* __restrict__ W,
                          ushortT* __restrict__ BT, int Din, int Dout){
  int K = 6*Din;
  int idx = blockIdx.x*blockDim.x + threadIdx.x;
  if(idx >= Dout*K) return;
  int n = idx / K, k = idx % K;
  float v = (k < Din) ? root[(size_t)k*Dout + n] : W[(size_t)(k-Din)*Dout + n];
  BT[idx] = f2bf(v);
}

// merged layer-2 B: BT[384][HID]; n<320 -> W[n/64][k][n%64]; n>=320 -> root[k][n-320]
__global__ void prep_btall_k(const float* __restrict__ W, const float* __restrict__ root,
                             ushortT* __restrict__ BT){
  int idx = blockIdx.x*blockDim.x + threadIdx.x;
  if(idx >= 384*HID) return;
  int n = idx / HID, k = idx % HID;
  float v;
  if(n < NREL*ODIM){
    int r = n / ODIM, c = n % ODIM;
    v = W[((size_t)r*HID + k)*ODIM + c];
  } else {
    v = root[(size_t)k*ODIM + (n - NREL*ODIM)];
  }
  BT[idx] = f2bf(v);
}

// BTm[R*C][K] : row n -> W[n/C][k][n%C]   (old H-tier msg weights)
__global__ void prep_w_k(const float* __restrict__ W, ushortT* __restrict__ BT,
                         int Kdim, int C, int total){
  int idx = blockIdx.x*blockDim.x + threadIdx.x;
  if(idx >= total) return;
  int n = idx / Kdim, k = idx % Kdim;
  int r = n / C, c = n % C;
  BT[idx] = f2bf(W[((size_t)r*Kdim + k)*C + c]);
}

// BTr[C][K] : row n -> root[k][n]
__global__ void prep_r_k(const float* __restrict__ root, ushortT* __restrict__ BT,
                         int Kdim, int C){
  int idx = blockIdx.x*blockDim.x + threadIdx.x;
  if(idx >= C*Kdim) return;
  int n = idx / Kdim, k = idx % Kdim;
  BT[idx] = f2bf(root[(size_t)k*C + n]);
}

// ---------------- layer-1 aggregation (D=64): 4 edges/iter via 16-lane groups ----------------

__global__ __launch_bounds__(256) void agg_m64_k(const ushortT* __restrict__ xsrc,
    const int* __restrict__ adj, const int* __restrict__ off5,
    ushortT* __restrict__ Mbuf, int lo, int cn)
{
  int wid  = (int)((blockIdx.x*(size_t)blockDim.x + threadIdx.x) >> 6);
  int l = threadIdx.x & 63;
  if(wid >= cn) return;
  int node = lo + wid;
  int g = l >> 4, sub = l & 15;
  int base = node*NREL;
  int offs[6];
  #pragma unroll
  for(int r=0;r<6;++r) offs[r] = off5[base+r];
  ushortT* mp = Mbuf + (size_t)wid*(NREL*UDIM);
  #pragma unroll
  for(int r=0;r<NREL;++r){
    int e0 = offs[r], e1 = offs[r+1];
    int c = e1 - e0;
    if(c == 0){
      if(l < 16){ uint2 z = {0u,0u}; *(uint2*)(mp + r*UDIM + sub*4) = z; }
      continue;
    }
    float a0=0.f,a1=0.f,a2=0.f,a3=0.f;
    for(int e = e0 + g; e < e1; e += 4){
      int p = adj[e] >> 3;
      uint2 u = *(const uint2*)(xsrc + (size_t)p*UDIM + sub*4);
      a0 += blo(u.x); a1 += bhi(u.x); a2 += blo(u.y); a3 += bhi(u.y);
    }
    a0 += __shfl_xor(a0,16); a1 += __shfl_xor(a1,16); a2 += __shfl_xor(a2,16); a3 += __shfl_xor(a3,16);
    a0 += __shfl_xor(a0,32); a1 += __shfl_xor(a1,32); a2 += __shfl_xor(a2,32); a3 += __shfl_xor(a3,32);
    if(l < 16){
      float sc = 1.f/(float)c;
      uint2 o;
      o.x = (unsigned)f2bf(a0*sc) | ((unsigned)f2bf(a1*sc)<<16);
      o.y = (unsigned)f2bf(a2*sc) | ((unsigned)f2bf(a3*sc)<<16);
      *(uint2*)(mp + r*UDIM + sub*4) = o;
    }
  }
}

// ---------------- layer-2 H aggregation (stride-parameterized) ----------------

__global__ __launch_bounds__(256) void agg_h_k(const ushortT* __restrict__ msg, int msgStride,
    const ushortT* __restrict__ root, int rootStride,
    const int* __restrict__ adj, const float* __restrict__ adjsc,
    const int* __restrict__ off5, const float* __restrict__ bias,
    float* __restrict__ outp, int n)
{
  int wid  = (int)((blockIdx.x*(size_t)blockDim.x + threadIdx.x) >> 6);
  int l = threadIdx.x & 63;
  if(wid >= n) return;
  int g = l >> 4, sub = l & 15;
  int e0 = off5[wid*NREL], e1 = off5[wid*NREL + NREL];
  float a0=0.f,a1=0.f,a2=0.f,a3=0.f;
  int e = e0 + g;
  for(; e + 4 < e1; e += 8){
    int ad1 = adj[e];   float sc1 = adjsc[e];
    int ad2 = adj[e+4]; float sc2 = adjsc[e+4];
    uint2 u = *(const uint2*)(msg + (size_t)(ad1>>3)*msgStride + (ad1&7)*ODIM + sub*4);
    uint2 v = *(const uint2*)(msg + (size_t)(ad2>>3)*msgStride + (ad2&7)*ODIM + sub*4);
    a0 += blo(u.x)*sc1; a1 += bhi(u.x)*sc1; a2 += blo(u.y)*sc1; a3 += bhi(u.y)*sc1;
    a0 += blo(v.x)*sc2; a1 += bhi(v.x)*sc2; a2 += blo(v.y)*sc2; a3 += bhi(v.y)*sc2;
  }
  if(e < e1){
    int ad1 = adj[e]; float sc1 = adjsc[e];
    uint2 u = *(const uint2*)(msg + (size_t)(ad1>>3)*msgStride + (ad1&7)*ODIM + sub*4);
    a0 += blo(u.x)*sc1; a1 += bhi(u.x)*sc1; a2 += blo(u.y)*sc1; a3 += bhi(u.y)*sc1;
  }
  a0 += __shfl_xor(a0,16); a1 += __shfl_xor(a1,16); a2 += __shfl_xor(a2,16); a3 += __shfl_xor(a3,16);
  a0 += __shfl_xor(a0,32); a1 += __shfl_xor(a1,32); a2 += __shfl_xor(a2,32); a3 += __shfl_xor(a3,32);
  if(l < 16){
    uint2 rt = *(const uint2*)(root + (size_t)wid*rootStride + sub*4);
    float4 bv = *(const float4*)(bias + sub*4);
    float4 o;
    o.x = a0 + blo(rt.x) + bv.x;
    o.y = a1 + bhi(rt.x) + bv.y;
    o.z = a2 + blo(rt.y) + bv.z;
    o.w = a3 + bhi(rt.y) + bv.w;
    *(float4*)(outp + (size_t)wid*ODIM + sub*4) = o;
  }
}

// ---------------- fallback M-scheme agg (layer 2, only if ws too small) ----------------

template<int D>
__global__ __launch_bounds__(256) void agg_m_k(const ushortT* __restrict__ xsrc,
    const ushortT* __restrict__ xdst, const int* __restrict__ adj,
    const int* __restrict__ off5, ushortT* __restrict__ Mbuf, int lo, int cn)
{
  int wid  = (int)((blockIdx.x*(size_t)blockDim.x + threadIdx.x) >> 6);
  int lane = threadIdx.x & 63;
  if(wid >= cn) return;
  int node = lo + wid;
  constexpr int V = D/64;
  ushortT* mp = Mbuf + (size_t)wid*(6*D);
  if(V==2) *(unsigned*)(mp + lane*2) = *(const unsigned*)(xdst + (size_t)node*D + lane*2);
  else     mp[lane] = xdst[(size_t)node*D + lane];
  #pragma unroll
  for(int r=0;r<NREL;++r){
    int base = node*NREL + r;
    int e0 = off5[base], e1 = off5[base+1];
    float s0 = 0.f, s1 = 0.f;
    for(int e=e0; e<e1; ++e){
      int p = adj[e] >> 3;
      if(V==2){
        unsigned u = *(const unsigned*)(xsrc + (size_t)p*D + lane*2);
        s0 += blo(u); s1 += bhi(u);
      } else {
        s0 += b2f(xsrc[(size_t)p*D + lane]);
      }
    }
    int c = e1 - e0;
    float sc = 1.f/(float)(c>0? c:1);
    if(V==2){
      unsigned o = (unsigned)f2bf(s0*sc) | ((unsigned)f2bf(s1*sc)<<16);
      *(unsigned*)(mp + D + r*D + lane*2) = o;
    } else {
      mp[D + r*D + lane] = f2bf(s0*sc);
    }
  }
}

// ---------------- single-stage MFMA GEMM: whole A-tile + whole B staged once ----------------
// One burst of global_load_lds (latency amortized across ~16 in-flight 1KB loads/wave),
// ONE barrier, then an unbroken MFMA sequence over all of K. No K-loop drains.
// 512 threads = 8 waves (2 row-groups x 4 col-groups).
// A col k: k<KSPLIT -> A0 (lda0) else A1 (lda1). BT is [BN][K] row-major bf16.

template<int BM, int BN, int K, int KSPLIT, bool OUTBF, bool RELU>
__global__ __launch_bounds__(512) void gemmS_k(
    const ushortT* __restrict__ A0, int lda0,
    const ushortT* __restrict__ A1, int lda1,
    const ushortT* __restrict__ BT,
    const float* __restrict__ bias,
    void* __restrict__ Cv, int ldc, int M)
{
  constexpr int ROWB = K*2;         // bytes per LDS row
  constexpr int KB8  = K/8;         // 16B chunks per row
  constexpr int ACH  = BM*KB8;      // A chunks (multiple of 512 for our shapes)
  constexpr int BCH  = BN*KB8;
  constexpr int FR   = BM/32;       // A frags per wave (wave rows = BM/2)
  constexpr int FC   = BN/64;       // B frags per wave (wave cols = BN/4)
  constexpr int NK   = K/32;
  __shared__ alignas(16) unsigned char sA[(size_t)BM*ROWB];
  __shared__ alignas(16) unsigned char sB[(size_t)BN*ROWB];

  const int tid = threadIdx.x;
  const int w = tid >> 6, l = tid & 63;
  const int wr = w >> 2, wc = w & 3;
  const int row0 = blockIdx.x * BM;

  // ---- stage A tile [BM][K] (linear LDS dest, inverse-swizzled source; split at KSPLIT) ----
  #pragma unroll
  for(int it=0; it<ACH/512; ++it){
    int c = it*512 + tid;
    int r = c / KB8;
    int jb = (c % KB8) * 16;
    int grow = row0 + r; grow = (grow < M) ? grow : (M-1);
    int jbx = jb ^ ((r&7)<<4);       // swizzle stays within 128B blocks -> split preserved
    const unsigned char* gp;
    if(jbx < KSPLIT*2) gp = (const unsigned char*)(A0 + (size_t)grow*lda0) + jbx;
    else               gp = (const unsigned char*)(A1 + (size_t)grow*lda1) + (jbx - KSPLIT*2);
    gld_lds16(gp, sA + (size_t)(it*512 + w*64)*16);
  }
  // ---- stage B [BN][K] ----
  #pragma unroll
  for(int it=0; it<BCH/512; ++it){
    int c = it*512 + tid;
    int r = c / KB8;
    int jb = (c % KB8) * 16;
    const unsigned char* gp = (const unsigned char*)BT + (size_t)r*ROWB + (jb ^ ((r&7)<<4));
    gld_lds16(gp, sB + (size_t)(it*512 + w*64)*16);
  }
  __syncthreads();

  f32x4 acc[FR][FC];
  #pragma unroll
  for(int i=0;i<FR;++i)
    #pragma unroll
    for(int j=0;j<FC;++j) acc[i][j] = (f32x4){0.f,0.f,0.f,0.f};

  #pragma unroll
  for(int kk=0;kk<NK;++kk){
    const int cb = kk*64 + (l>>4)*16;
    bf16x8 af[FR], bfr[FC];
    #pragma unroll
    for(int i=0;i<FR;++i){
      int r = wr*(BM/2) + i*16 + (l&15);
      af[i] = *reinterpret_cast<const bf16x8*>(sA + (size_t)r*ROWB + (cb ^ ((r&7)<<4)));
    }
    #pragma unroll
    for(int j=0;j<FC;++j){
      int cN = wc*(BN/4) + j*16 + (l&15);
      bfr[j] = *reinterpret_cast<const bf16x8*>(sB + (size_t)cN*ROWB + (cb ^ ((cN&7)<<4)));
    }
    #pragma unroll
    for(int i=0;i<FR;++i)
      #pragma unroll
      for(int j=0;j<FC;++j)
        acc[i][j] = __builtin_amdgcn_mfma_f32_16x16x32_bf16(af[i], bfr[j], acc[i][j], 0, 0, 0);
  }

  #pragma unroll
  for(int i=0;i<FR;++i){
    #pragma unroll
    for(int rr=0;rr<4;++rr){
      int grow = row0 + wr*(BM/2) + i*16 + (l>>4)*4 + rr;
      if(grow >= M) continue;
      #pragma unroll
      for(int j=0;j<FC;++j){
        int col = wc*(BN/4) + j*16 + (l&15);
        float v = acc[i][j][rr];
        if(bias) v += bias[col];
        if(RELU) v = fmaxf(v, 0.f);
        if(OUTBF) ((ushortT*)Cv)[(size_t)grow*ldc + col] = f2bf(v);
        else      ((float*)Cv)[(size_t)grow*ldc + col] = v;
      }
    }
  }
}

// ---------------- legacy 2-buffer GEMM (fallback tiers only) ----------------

template<int BN, bool OUTBF, bool RELU>
__global__ __launch_bounds__(256) void gemm2_k(
    const ushortT* __restrict__ A0, int lda0,
    const ushortT* __restrict__ A1, int lda1, int KSPLIT,
    const ushortT* __restrict__ BT, int K,
    const float* __restrict__ bias,
    void* __restrict__ Cv, int ldc, int M)
{
  constexpr int BM = 128;
  constexpr int WCN  = (BN==128)? 2 : 1;
  constexpr int WROWS= (BN==128)? 64 : 32;
  constexpr int FR   = WROWS/16;
  constexpr int FC   = 4;
  __shared__ alignas(16) unsigned char sA[2][BM*128];
  __shared__ alignas(16) unsigned char sB[2][BN*128];

  const int tid = threadIdx.x;
  const int w = tid >> 6, l = tid & 63;
  const int wr = w / WCN, wc = w % WCN;
  const int row0 = blockIdx.x * BM;
  const int col0 = blockIdx.y * BN;
  const ushortT* BTp = BT + (size_t)col0 * K;

  f32x4 acc[FR][FC];
  #pragma unroll
  for(int i=0;i<FR;++i)
    #pragma unroll
    for(int j=0;j<FC;++j) acc[i][j] = (f32x4){0.f,0.f,0.f,0.f};

  const int lr  = l >> 3;
  const int lc  = (l & 7) * 16;

  auto stage = [&](int buf, int k0){
    const ushortT* Ab = (k0 < KSPLIT) ? A0 : A1;
    const int ldab    = (k0 < KSPLIT) ? lda0 : lda1;
    const int kc      = (k0 < KSPLIT) ? k0 : (k0 - KSPLIT);
    #pragma unroll
    for(int j=0;j<4;++j){
      int r = w*32 + j*8 + lr;
      int grow = row0 + r; grow = (grow < M) ? grow : (M-1);
      const unsigned char* gp = (const unsigned char*)(Ab + (size_t)grow*ldab + kc) + (lc ^ ((r&7)<<4));
      gld_lds16(gp, &sA[buf][(w*32 + j*8)*128]);
    }
    #pragma unroll
    for(int j=0;j<BN/32;++j){
      int r = w*(BN/4) + j*8 + lr;
      const unsigned char* gp = (const unsigned char*)(BTp + (size_t)r*K + k0) + (lc ^ ((r&7)<<4));
      gld_lds16(gp, &sB[buf][(w*(BN/4) + j*8)*128]);
    }
  };

  const int NT = K >> 6;
  stage(0, 0);
  __syncthreads();
  int cur = 0;
  for(int t=0; t<NT; ++t){
    if(t+1 < NT) stage(cur^1, (t+1)<<6);
    #pragma unroll
    for(int kk=0;kk<2;++kk){
      const int cb = kk*64 + (l>>4)*16;
      bf16x8 af[FR], bfr[FC];
      #pragma unroll
      for(int i=0;i<FR;++i){
        int r = wr*WROWS + i*16 + (l&15);
        af[i] = *reinterpret_cast<const bf16x8*>(&sA[cur][r*128 + (cb ^ ((r&7)<<4))]);
      }
      #pragma unroll
      for(int j=0;j<FC;++j){
        int c = wc*64 + j*16 + (l&15);
        bfr[j] = *reinterpret_cast<const bf16x8*>(&sB[cur][c*128 + (cb ^ ((c&7)<<4))]);
      }
      #pragma unroll
      for(int i=0;i<FR;++i)
        #pragma unroll
        for(int j=0;j<FC;++j)
          acc[i][j] = __builtin_amdgcn_mfma_f32_16x16x32_bf16(af[i], bfr[j], acc[i][j], 0, 0, 0);
    }
    __syncthreads();
    cur ^= 1;
  }
  #pragma unroll
  for(int i=0;i<FR;++i){
    #pragma unroll
    for(int rr=0;rr<4;++rr){
      int grow = row0 + wr*WROWS + i*16 + (l>>4)*4 + rr;
      if(grow >= M) continue;
      #pragma unroll
      for(int j=0;j<FC;++j){
        int col = wc*64 + j*16 + (l&15);
        float v = acc[i][j][rr];
        if(bias) v += bias[col0 + col];
        if(RELU) v = fmaxf(v, 0.f);
        if(OUTBF) ((ushortT*)Cv)[(size_t)grow*ldc + col0 + col] = f2bf(v);
        else      ((float*)Cv)[(size_t)grow*ldc + col0 + col] = v;
      }
    }
  }
}

// ---------------- host ----------------

extern "C" void kernel_launch(void* const* d_in, const int* in_sizes, int n_in,
                              void* d_out, int out_size, void* d_ws, size_t ws_size,
                              hipStream_t stream){
  const float* x_user   = (const float*)d_in[0];
  const float* x_item   = (const float*)d_in[1];
  const int*   ei       = (const int*)d_in[2];
  const int*   et       = (const int*)d_in[3];
  const float* W1_ui    = (const float*)d_in[4];
  const float* root1_ui = (const float*)d_in[5];
  const float* b1_ui    = (const float*)d_in[6];
  const float* W1_iu    = (const float*)d_in[7];
  const float* root1_iu = (const float*)d_in[8];
  const float* b1_iu    = (const float*)d_in[9];
  const float* W2_ui    = (const float*)d_in[10];
  const float* root2_ui = (const float*)d_in[11];
  const float* b2_ui    = (const float*)d_in[12];
  const float* W2_iu    = (const float*)d_in[13];
  const float* root2_iu = (const float*)d_in[14];
  const float* b2_iu    = (const float*)d_in[15];
  const int E = in_sizes[3];
  const int* src = ei;
  const int* dst = ei + E;
  float* out = (float*)d_out;

  const int NI5 = NITEMS*NREL, NU5 = NUSERS*NREL;

  uint8_t* ws = (uint8_t*)d_ws;
  size_t o = 0;
  auto alloc = [&](size_t bytes){ size_t r = o; o = align256(o + bytes); return r; };
  int* cnt_i5 = (int*)(ws + alloc((size_t)NI5*4));
  int* cnt_u5 = (int*)(ws + alloc((size_t)NU5*4));
  int* off_i5 = (int*)(ws + alloc((size_t)(NI5+1)*4));
  int* off_u5 = (int*)(ws + alloc((size_t)(NU5+1)*4));
  int* cur_i5 = (int*)(ws + alloc((size_t)NI5*4));
  int* cur_u5 = (int*)(ws + alloc((size_t)NU5*4));
  int* adj_item = (int*)(ws + alloc((size_t)E*4));
  int* adj_user = (int*)(ws + alloc((size_t)E*4));
  float* sc_item = (float*)(ws + alloc((size_t)E*4));
  float* sc_user = (float*)(ws + alloc((size_t)E*4));
  int* btot     = (int*)(ws + alloc(1024*4));
  int* boff     = (int*)(ws + alloc(1024*4));
  ushortT* xu_bf = (ushortT*)(ws + alloc((size_t)NUSERS*UDIM*2));
  ushortT* xi_bf = (ushortT*)(ws + alloc((size_t)NITEMS*UDIM*2));
  ushortT* h1u   = (ushortT*)(ws + alloc((size_t)NUSERS*HID*2));
  ushortT* h1i   = (ushortT*)(ws + alloc((size_t)NITEMS*HID*2));
  ushortT* BT1ui = (ushortT*)(ws + alloc((size_t)HID*(6*UDIM)*2));
  ushortT* BT1iu = (ushortT*)(ws + alloc((size_t)HID*(6*UDIM)*2));
  ushortT* BTallU = (ushortT*)(ws + alloc((size_t)384*HID*2));   // [W2_ui r0..4 | root2_iu]
  ushortT* BTallI = (ushortT*)(ws + alloc((size_t)384*HID*2));   // [W2_iu r0..4 | root2_ui]
  ushortT* BT2ui = (ushortT*)(ws + alloc((size_t)ODIM*(6*HID)*2));   // M-tier fallback
  ushortT* BT2iu = (ushortT*)(ws + alloc((size_t)ODIM*(6*HID)*2));
  ushortT* BTm2ui = (ushortT*)(ws + alloc((size_t)NREL*ODIM*HID*2)); // old-H tier
  ushortT* BTm2iu = (ushortT*)(ws + alloc((size_t)NREL*ODIM*HID*2));
  ushortT* BTr2ui = (ushortT*)(ws + alloc((size_t)ODIM*HID*2));
  ushortT* BTr2iu = (ushortT*)(ws + alloc((size_t)ODIM*HID*2));
  size_t bigoff = o;
  size_t avail = (ws_size > bigoff)? (ws_size - bigoff) : 0;
  uint8_t* big = ws + bigoff;

  size_t needHM = align256((size_t)NUSERS*384*2) + align256((size_t)NITEMS*384*2);
  size_t needH  = align256((size_t)NUSERS*NREL*ODIM*2) + align256((size_t)NITEMS*ODIM*2);
  bool useHM = (avail >= needHM + 4096);
  bool useH  = (avail >= needH + 4096);

  // ---- CSR build keyed by (node, relation) ----
  hipMemsetAsync(cnt_i5, 0, (size_t)NI5*4, stream);
  hipMemsetAsync(cnt_u5, 0, (size_t)NU5*4, stream);
  int eb = (E+255)/256;
  count_edges_k<<<eb,256,0,stream>>>(src,dst,et,E,cnt_i5,cnt_u5);

  int nbI = (NI5+1023)/1024, nbU = (NU5+1023)/1024;
  scan_s1f<<<nbI,256,0,stream>>>(cnt_i5, NI5, btot);
  scan_s2<<<1,1024,0,stream>>>(btot, nbI, boff, off_i5+NI5);
  scan_s3f<<<nbI,256,0,stream>>>(cnt_i5, NI5, boff, off_i5);
  scan_s1f<<<nbU,256,0,stream>>>(cnt_u5, NU5, btot);
  scan_s2<<<1,1024,0,stream>>>(btot, nbU, boff, off_u5+NU5);
  scan_s3f<<<nbU,256,0,stream>>>(cnt_u5, NU5, boff, off_u5);

  copy_int_k<<<(NI5+255)/256,256,0,stream>>>(off_i5, cur_i5, NI5);
  copy_int_k<<<(NU5+255)/256,256,0,stream>>>(off_u5, cur_u5, NU5);
  scatter_k<<<eb,256,0,stream>>>(src,dst,et,E,cur_i5,cur_u5,cnt_i5,cnt_u5,
                                 adj_item,adj_user,sc_item,sc_user);

  // ---- dtype prep ----
  {
    int n4 = NUSERS*UDIM/4;
    f2bf4_k<<<(n4+255)/256,256,0,stream>>>((const float4*)x_user, (uint2*)xu_bf, n4);
    n4 = NITEMS*UDIM/4;
    f2bf4_k<<<(n4+255)/256,256,0,stream>>>((const float4*)x_item, (uint2*)xi_bf, n4);
  }
  prep_bt_k<<<(HID*6*UDIM+255)/256,256,0,stream>>>(root1_ui, W1_ui, BT1ui, UDIM, HID);
  prep_bt_k<<<(HID*6*UDIM+255)/256,256,0,stream>>>(root1_iu, W1_iu, BT1iu, UDIM, HID);
  if(useHM){
    prep_btall_k<<<(384*HID+255)/256,256,0,stream>>>(W2_ui, root2_iu, BTallU);
    prep_btall_k<<<(384*HID+255)/256,256,0,stream>>>(W2_iu, root2_ui, BTallI);
  } else if(useH){
    int tot = NREL*ODIM*HID;
    prep_w_k<<<(tot+255)/256,256,0,stream>>>(W2_ui, BTm2ui, HID, ODIM, tot);
    prep_w_k<<<(tot+255)/256,256,0,stream>>>(W2_iu, BTm2iu, HID, ODIM, tot);
    prep_r_k<<<(ODIM*HID+255)/256,256,0,stream>>>(root2_ui, BTr2ui, HID, ODIM);
    prep_r_k<<<(ODIM*HID+255)/256,256,0,stream>>>(root2_iu, BTr2iu, HID, ODIM);
  } else {
    prep_bt_k<<<(ODIM*6*HID+255)/256,256,0,stream>>>(root2_ui, W2_ui, BT2ui, HID, ODIM);
    prep_bt_k<<<(ODIM*6*HID+255)/256,256,0,stream>>>(root2_iu, W2_iu, BT2iu, HID, ODIM);
  }

  // ---- layer 1: M-scheme agg + single-stage GEMM (split-A: dst feats | means) ----
  {
    ushortT* Mbuf = (ushortT*)big;
    long long c1 = (long long)(avail / ((size_t)NREL*UDIM*2));
    int CH = (int)(c1 > 65536 ? 65536 : c1); CH &= ~127; if(CH < 128) CH = 128;
    for(int lo=0; lo<NITEMS; lo+=CH){
      int cn = imin(CH, NITEMS-lo);
      agg_m64_k<<<(cn+3)/4,256,0,stream>>>(xu_bf, adj_item, off_i5 + lo*NREL, Mbuf, 0, cn);
      gemmS_k<64,128,384,64,true,true><<<(cn+63)/64,512,0,stream>>>(
          xi_bf + (size_t)lo*UDIM, UDIM, Mbuf, NREL*UDIM,
          BT1ui, b1_ui, h1i + (size_t)lo*HID, HID, cn);
    }
    for(int lo=0; lo<NUSERS; lo+=CH){
      int cn = imin(CH, NUSERS-lo);
      agg_m64_k<<<(cn+3)/4,256,0,stream>>>(xi_bf, adj_user, off_u5 + lo*NREL, Mbuf, 0, cn);
      gemmS_k<64,128,384,64,true,true><<<(cn+63)/64,512,0,stream>>>(
          xu_bf + (size_t)lo*UDIM, UDIM, Mbuf, NREL*UDIM,
          BT1iu, b1_iu, h1u + (size_t)lo*HID, HID, cn);
    }
  }

  // ---- layer 2 ----
  float* user2 = out;
  float* item2 = out + (size_t)NUSERS*ODIM;
  if(useHM){
    ushortT* Hall_u = (ushortT*)big;                                    // [NUSERS][384]
    ushortT* Hall_i = (ushortT*)(big + align256((size_t)NUSERS*384*2)); // [NITEMS][384]
    gemmS_k<128,384,128,0,true,false><<<(NUSERS+127)/128,512,0,stream>>>(
        h1u, HID, h1u, HID, BTallU, nullptr, Hall_u, 384, NUSERS);
    gemmS_k<128,384,128,0,true,false><<<(NITEMS+127)/128,512,0,stream>>>(
        h1i, HID, h1i, HID, BTallI, nullptr, Hall_i, 384, NITEMS);
    agg_h_k<<<(NITEMS+3)/4,256,0,stream>>>(Hall_u, 384, Hall_i + NREL*ODIM, 384,
        adj_item, sc_item, off_i5, b2_ui, item2, NITEMS);
    agg_h_k<<<(NUSERS+3)/4,256,0,stream>>>(Hall_i, 384, Hall_u + NREL*ODIM, 384,
        adj_user, sc_user, off_u5, b2_iu, user2, NUSERS);
  } else if(useH){
    ushortT* Hmsg_u = (ushortT*)big;
    ushortT* Hroot_i = (ushortT*)(big + align256((size_t)NUSERS*NREL*ODIM*2));
    gemm2_k<ODIM,true,false><<<dim3((NUSERS+127)/128, NREL),256,0,stream>>>(
        h1u, HID, h1u, HID, HID, BTm2ui, HID, nullptr, Hmsg_u, NREL*ODIM, NUSERS);
    gemm2_k<ODIM,true,false><<<dim3((NITEMS+127)/128, 1),256,0,stream>>>(
        h1i, HID, h1i, HID, HID, BTr2ui, HID, nullptr, Hroot_i, ODIM, NITEMS);
    agg_h_k<<<(NITEMS+3)/4,256,0,stream>>>(Hmsg_u, NREL*ODIM, Hroot_i, ODIM,
        adj_item, sc_item, off_i5, b2_ui, item2, NITEMS);
    ushortT* Hmsg_i = (ushortT*)big;
    ushortT* Hroot_u = (ushortT*)(big + align256((size_t)NITEMS*NREL*ODIM*2));
    gemm2_k<ODIM,true,false><<<dim3((NITEMS+127)/128, NREL),256,0,stream>>>(
        h1i, HID, h1i, HID, HID, BTm2iu, HID, nullptr, Hmsg_i, NREL*ODIM, NITEMS);
    gemm2_k<ODIM,true,false><<<dim3((NUSERS+127)/128, 1),256,0,stream>>>(
        h1u, HID, h1u, HID, HID, BTr2iu, HID, nullptr, Hroot_u, ODIM, NUSERS);
    agg_h_k<<<(NUSERS+3)/4,256,0,stream>>>(Hmsg_i, NREL*ODIM, Hroot_u, ODIM,
        adj_user, sc_user, off_u5, b2_iu, user2, NUSERS);
  } else {
    ushortT* Mbuf = (ushortT*)big;
    long long c2 = (long long)(avail / ((size_t)6*HID*2));
    int CH = (int)(c2 > NUSERS ? NUSERS : c2); CH &= ~127; if(CH < 128) CH = 128;
    for(int lo=0; lo<NITEMS; lo+=CH){
      int cn = imin(CH, NITEMS-lo);
      agg_m_k<HID><<<(cn+3)/4,256,0,stream>>>(h1u, h1i, adj_item, off_i5, Mbuf, lo, cn);
      gemm2_k<ODIM,false,false><<<dim3((cn+127)/128,1),256,0,stream>>>(
          Mbuf, 6*HID, Mbuf, 6*HID, 6*HID, BT2ui, 6*HID, b2_ui, item2 + (size_t)lo*ODIM, ODIM, cn);
    }
    for(int lo=0; lo<NUSERS; lo+=CH){
      int cn = imin(CH, NUSERS-lo);
      agg_m_k<HID><<<(cn+3)/4,256,0,stream>>>(h1i, h1u, adj_user, off_u5, Mbuf, lo, cn);
      gemm2_k<ODIM,false,false><<<dim3((cn+127)/128,1),256,0,stream>>>(
          Mbuf, 6*HID, Mbuf, 6*HID, 6*HID, BT2iu, 6*HID, b2_iu, user2 + (size_t)lo*ODIM, ODIM, cn);
    }
  }
}

// Round 9
// 638.124 us; speedup vs baseline: 1.1518x; 1.1039x over previous
//
#include <hip/hip_runtime.h>
#include <hip/hip_bf16.h>
#include <cstdint>
#include <cstddef>

#define NUSERS 200000
#define NITEMS 100000
#define UDIM 64
#define HID 128
#define ODIM 64
#define NREL 5

typedef unsigned short ushortT;
typedef __bf16 bf16x8 __attribute__((ext_vector_type(8)));
typedef float f32x4 __attribute__((ext_vector_type(4)));

static inline size_t align256(size_t x){ return (x + 255) & ~(size_t)255; }
static inline int imin(int a,int b){ return a<b?a:b; }

__device__ __forceinline__ unsigned short f2bf(float f){
  unsigned int u = __builtin_bit_cast(unsigned int, f);
  unsigned int r = (u + 0x7fffu + ((u>>16)&1u)) >> 16;   // RNE
  return (unsigned short)r;
}
__device__ __forceinline__ float b2f(unsigned short u){
  return __builtin_bit_cast(float, ((unsigned int)u)<<16);
}
__device__ __forceinline__ float blo(unsigned u){ return b2f((unsigned short)(u & 0xffff)); }
__device__ __forceinline__ float bhi(unsigned u){ return b2f((unsigned short)(u >> 16)); }
__device__ __forceinline__ void gld_lds16(const void* g, void* s){
  __builtin_amdgcn_global_load_lds((const __attribute__((address_space(1))) void*)g,
                                   (__attribute__((address_space(3))) void*)s, 16, 0, 0);
}

// ---------------- CSR build: ONE combined (node,relation) key space ----------------
// keys: item side [0, NI5), user side [NI5, NI5+NU5). adj/sc sized 2E.

__global__ void count_edges_k(const int* __restrict__ src, const int* __restrict__ dst,
                              const int* __restrict__ et, int E, int* __restrict__ cnt){
  int e = blockIdx.x*blockDim.x + threadIdx.x;
  if(e < E){
    int t = et[e];
    atomicAdd(&cnt[dst[e]*NREL + t], 1);
    atomicAdd(&cnt[NITEMS*NREL + src[e]*NREL + t], 1);
  }
}

// 2048 elems per block (8/thread) so nb <= 1024 for n = 1.5M
__global__ __launch_bounds__(256) void scan_s1f(const int* __restrict__ c, int n, int* __restrict__ btot){
  int t = threadIdx.x;
  int base = blockIdx.x*2048 + t*8;
  int s = 0;
  #pragma unroll
  for(int j=0;j<8;++j){ int i = base+j; if(i<n) s += c[i]; }
  __shared__ int red[256];
  red[t] = s; __syncthreads();
  for(int o=128;o>0;o>>=1){ if(t<o) red[t]+=red[t+o]; __syncthreads(); }
  if(t==0) btot[blockIdx.x] = red[0];
}

__global__ __launch_bounds__(1024) void scan_s2(const int* __restrict__ btot, int nb,
                                                int* __restrict__ boff, int* __restrict__ total_out){
  __shared__ int sh[1024];
  int t = threadIdx.x;
  int v = (t<nb)? btot[t] : 0;
  sh[t] = v; __syncthreads();
  for(int o=1;o<1024;o<<=1){
    int add = (t>=o)? sh[t-o] : 0;
    __syncthreads();
    sh[t] += add;
    __syncthreads();
  }
  if(t<nb) boff[t] = sh[t]-v;
  if(t==1023) *total_out = sh[1023];
}

__global__ __launch_bounds__(256) void scan_s3f(const int* __restrict__ c, int n,
                                                const int* __restrict__ boff, int* __restrict__ off){
  int t = threadIdx.x, b = blockIdx.x;
  int base = b*2048 + t*8;
  int pre[8]; int s = 0;
  #pragma unroll
  for(int j=0;j<8;++j){
    int i = base+j; int d = (i<n)? c[i] : 0;
    pre[j] = s; s += d;
  }
  __shared__ int sh[256];
  sh[t] = s; __syncthreads();
  int inc = s;
  for(int o=1;o<256;o<<=1){
    int add = (t>=o)? sh[t-o] : 0;
    __syncthreads();
    sh[t] += add;
    __syncthreads();
  }
  int texcl = sh[t] - inc;
  int bo = boff[b];
  #pragma unroll
  for(int j=0;j<8;++j){
    int i = base+j;
    if(i<n) off[i] = bo + texcl + pre[j];
  }
}

__global__ void copy_int_k(const int* __restrict__ a, int* __restrict__ b, int n){
  int i = blockIdx.x*blockDim.x + threadIdx.x;
  if(i < n) b[i] = a[i];
}

// adj entries packed (peer<<3)|rel; per-edge fp32 scale = 1/segment_count (from off diffs)
__global__ void scatter_k(const int* __restrict__ src, const int* __restrict__ dst,
                          const int* __restrict__ et, int E,
                          int* __restrict__ cur, const int* __restrict__ off,
                          int* __restrict__ adj, float* __restrict__ sc){
  int e = blockIdx.x*blockDim.x + threadIdx.x;
  if(e < E){
    int s = src[e], d = dst[e], t = et[e];
    int k1 = d*NREL + t;
    int p1 = atomicAdd(&cur[k1], 1);
    adj[p1] = (s<<3) | t;
    sc[p1] = 1.f/(float)(off[k1+1]-off[k1]);
    int k2 = NITEMS*NREL + s*NREL + t;
    int p2 = atomicAdd(&cur[k2], 1);
    adj[p2] = (d<<3) | t;
    sc[p2] = 1.f/(float)(off[k2+1]-off[k2]);
  }
}

// ---------------- dtype prep ----------------

__global__ void f2bf4_k(const float4* __restrict__ a, uint2* __restrict__ b, int n4){
  int i = blockIdx.x*blockDim.x + threadIdx.x;
  if(i < n4){
    float4 v = a[i];
    uint2 o;
    o.x = (unsigned)f2bf(v.x) | ((unsigned)f2bf(v.y)<<16);
    o.y = (unsigned)f2bf(v.z) | ((unsigned)f2bf(v.w)<<16);
    b[i] = o;
  }
}

// BT[Dout][6*Din] = [root; W_0..W_4]^T   (layer-1 B)
__global__ void prep_bt_k(const float* __restrict__ root, const float* __restrict__ W,
                          ushortT* __restrict__ BT, int Din, int Dout){
  int K = 6*Din;
  int idx = blockIdx.x*blockDim.x + threadIdx.x;
  if(idx >= Dout*K) return;
  int n = idx / K, k = idx % K;
  float v = (k < Din) ? root[(size_t)k*Dout + n] : W[(size_t)(k-Din)*Dout + n];
  BT[idx] = f2bf(v);
}

// BTm[R*C][K] : row n -> W[n/C][k][n%C]   (layer-2 message weights, transposed)
__global__ void prep_w_k(const float* __restrict__ W, ushortT* __restrict__ BT,
                         int Kdim, int C, int total){
  int idx = blockIdx.x*blockDim.x + threadIdx.x;
  if(idx >= total) return;
  int n = idx / Kdim, k = idx % Kdim;
  int r = n / C, c = n % C;
  BT[idx] = f2bf(W[((size_t)r*Kdim + k)*C + c]);
}

// BTr[C][K] : row n -> root[k][n]
__global__ void prep_r_k(const float* __restrict__ root, ushortT* __restrict__ BT,
                         int Kdim, int C){
  int idx = blockIdx.x*blockDim.x + threadIdx.x;
  if(idx >= C*Kdim) return;
  int n = idx / Kdim, k = idx % Kdim;
  BT[idx] = f2bf(root[(size_t)k*C + n]);
}

// ---------------- layer-1 aggregation (D=64): 4 edges/iter via 16-lane groups ----------------

__global__ __launch_bounds__(256) void agg_m64_k(const ushortT* __restrict__ xsrc,
    const int* __restrict__ adj, const int* __restrict__ off5,
    ushortT* __restrict__ Mbuf, int lo, int cn)
{
  int wid  = (int)((blockIdx.x*(size_t)blockDim.x + threadIdx.x) >> 6);
  int l = threadIdx.x & 63;
  if(wid >= cn) return;
  int node = lo + wid;
  int g = l >> 4, sub = l & 15;
  int base = node*NREL;
  int offs[6];
  #pragma unroll
  for(int r=0;r<6;++r) offs[r] = off5[base+r];
  ushortT* mp = Mbuf + (size_t)wid*(NREL*UDIM);
  #pragma unroll
  for(int r=0;r<NREL;++r){
    int e0 = offs[r], e1 = offs[r+1];
    int c = e1 - e0;
    if(c == 0){
      if(l < 16){ uint2 z = {0u,0u}; *(uint2*)(mp + r*UDIM + sub*4) = z; }
      continue;
    }
    float a0=0.f,a1=0.f,a2=0.f,a3=0.f;
    for(int e = e0 + g; e < e1; e += 4){
      int p = adj[e] >> 3;
      uint2 u = *(const uint2*)(xsrc + (size_t)p*UDIM + sub*4);
      a0 += blo(u.x); a1 += bhi(u.x); a2 += blo(u.y); a3 += bhi(u.y);
    }
    a0 += __shfl_xor(a0,16); a1 += __shfl_xor(a1,16); a2 += __shfl_xor(a2,16); a3 += __shfl_xor(a3,16);
    a0 += __shfl_xor(a0,32); a1 += __shfl_xor(a1,32); a2 += __shfl_xor(a2,32); a3 += __shfl_xor(a3,32);
    if(l < 16){
      float sc = 1.f/(float)c;
      uint2 o;
      o.x = (unsigned)f2bf(a0*sc) | ((unsigned)f2bf(a1*sc)<<16);
      o.y = (unsigned)f2bf(a2*sc) | ((unsigned)f2bf(a3*sc)<<16);
      *(uint2*)(mp + r*UDIM + sub*4) = o;
    }
  }
}

// ---------------- layer-2 H aggregation ----------------
// out[node] = sum_e sc_e * msg[peer_e*msgStride + rel_e*64 ..] + root[node*rootStride ..] + bias

__global__ __launch_bounds__(256) void agg_h_k(const ushortT* __restrict__ msg, int msgStride,
    const ushortT* __restrict__ root, int rootStride,
    const int* __restrict__ adj, const float* __restrict__ adjsc,
    const int* __restrict__ off5, const float* __restrict__ bias,
    float* __restrict__ outp, int n)
{
  int wid  = (int)((blockIdx.x*(size_t)blockDim.x + threadIdx.x) >> 6);
  int l = threadIdx.x & 63;
  if(wid >= n) return;
  int g = l >> 4, sub = l & 15;
  int e0 = off5[wid*NREL], e1 = off5[wid*NREL + NREL];
  float a0=0.f,a1=0.f,a2=0.f,a3=0.f;
  int e = e0 + g;
  for(; e + 4 < e1; e += 8){
    int ad1 = adj[e];   float sc1 = adjsc[e];
    int ad2 = adj[e+4]; float sc2 = adjsc[e+4];
    uint2 u = *(const uint2*)(msg + (size_t)(ad1>>3)*msgStride + (ad1&7)*ODIM + sub*4);
    uint2 v = *(const uint2*)(msg + (size_t)(ad2>>3)*msgStride + (ad2&7)*ODIM + sub*4);
    a0 += blo(u.x)*sc1; a1 += bhi(u.x)*sc1; a2 += blo(u.y)*sc1; a3 += bhi(u.y)*sc1;
    a0 += blo(v.x)*sc2; a1 += bhi(v.x)*sc2; a2 += blo(v.y)*sc2; a3 += bhi(v.y)*sc2;
  }
  if(e < e1){
    int ad1 = adj[e]; float sc1 = adjsc[e];
    uint2 u = *(const uint2*)(msg + (size_t)(ad1>>3)*msgStride + (ad1&7)*ODIM + sub*4);
    a0 += blo(u.x)*sc1; a1 += bhi(u.x)*sc1; a2 += blo(u.y)*sc1; a3 += bhi(u.y)*sc1;
  }
  a0 += __shfl_xor(a0,16); a1 += __shfl_xor(a1,16); a2 += __shfl_xor(a2,16); a3 += __shfl_xor(a3,16);
  a0 += __shfl_xor(a0,32); a1 += __shfl_xor(a1,32); a2 += __shfl_xor(a2,32); a3 += __shfl_xor(a3,32);
  if(l < 16){
    uint2 rt = *(const uint2*)(root + (size_t)wid*rootStride + sub*4);
    float4 bv = *(const float4*)(bias + sub*4);
    float4 o;
    o.x = a0 + blo(rt.x) + bv.x;
    o.y = a1 + bhi(rt.x) + bv.y;
    o.z = a2 + blo(rt.y) + bv.z;
    o.w = a3 + bhi(rt.y) + bv.w;
    *(float4*)(outp + (size_t)wid*ODIM + sub*4) = o;
  }
}

// ---------------- fallback M-scheme agg (layer 2, only if ws too small) ----------------

template<int D>
__global__ __launch_bounds__(256) void agg_m_k(const ushortT* __restrict__ xsrc,
    const ushortT* __restrict__ xdst, const int* __restrict__ adj,
    const int* __restrict__ off5, ushortT* __restrict__ Mbuf, int lo, int cn)
{
  int wid  = (int)((blockIdx.x*(size_t)blockDim.x + threadIdx.x) >> 6);
  int lane = threadIdx.x & 63;
  if(wid >= cn) return;
  int node = lo + wid;
  constexpr int V = D/64;
  ushortT* mp = Mbuf + (size_t)wid*(6*D);
  if(V==2) *(unsigned*)(mp + lane*2) = *(const unsigned*)(xdst + (size_t)node*D + lane*2);
  else     mp[lane] = xdst[(size_t)node*D + lane];
  #pragma unroll
  for(int r=0;r<NREL;++r){
    int base = node*NREL + r;
    int e0 = off5[base], e1 = off5[base+1];
    float s0 = 0.f, s1 = 0.f;
    for(int e=e0; e<e1; ++e){
      int p = adj[e] >> 3;
      if(V==2){
        unsigned u = *(const unsigned*)(xsrc + (size_t)p*D + lane*2);
        s0 += blo(u); s1 += bhi(u);
      } else {
        s0 += b2f(xsrc[(size_t)p*D + lane]);
      }
    }
    int c = e1 - e0;
    float sc = 1.f/(float)(c>0? c:1);
    if(V==2){
      unsigned o = (unsigned)f2bf(s0*sc) | ((unsigned)f2bf(s1*sc)<<16);
      *(unsigned*)(mp + D + r*D + lane*2) = o;
    } else {
      mp[D + r*D + lane] = f2bf(s0*sc);
    }
  }
}

// ---------------- bf16 MFMA GEMM: BM=64, dbuf, col-tiles on blockIdx.x ----------------
// grid = dim3(ncolTiles, nrowTiles). 256 threads = 4 waves.
// Small LDS (32-48KB) -> 3-5 resident blocks/CU; cross-block TLP hides staging.
// A col k: k<KSPLIT -> A0 (lda0) else A1 (lda1). BT is [Ntot][K] row-major bf16.

template<int BM, int BN, bool OUTBF, bool RELU>
__global__ __launch_bounds__(256) void gemm2v_k(
    const ushortT* __restrict__ A0, int lda0,
    const ushortT* __restrict__ A1, int lda1, int KSPLIT,
    const ushortT* __restrict__ BT, int K,
    const float* __restrict__ bias,
    void* __restrict__ Cv, int ldc, int M)
{
  constexpr int WGC = (BN>=128)? 2 : 1;   // wave-grid cols
  constexpr int WGR = 4/WGC;              // wave-grid rows
  constexpr int FR  = BM/(16*WGR);
  constexpr int FC  = BN/(16*WGC);
  constexpr int ACH = BM*8;               // 16B chunks per 64-col K-tile
  constexpr int BCH = BN*8;
  __shared__ alignas(16) unsigned char sA[2][BM*128];
  __shared__ alignas(16) unsigned char sB[2][BN*128];

  const int tid = threadIdx.x;
  const int w = tid >> 6, l = tid & 63;
  const int wr = w / WGC, wc = w % WGC;
  const int row0 = blockIdx.y * BM;
  const int col0 = blockIdx.x * BN;
  const ushortT* BTp = BT + (size_t)col0 * K;

  f32x4 acc[FR][FC];
  #pragma unroll
  for(int i=0;i<FR;++i)
    #pragma unroll
    for(int j=0;j<FC;++j) acc[i][j] = (f32x4){0.f,0.f,0.f,0.f};

  auto stage = [&](int buf, int k0){
    const ushortT* Ab = (k0 < KSPLIT) ? A0 : A1;
    const int ldab    = (k0 < KSPLIT) ? lda0 : lda1;
    const int kc      = (k0 < KSPLIT) ? k0 : (k0 - KSPLIT);
    #pragma unroll
    for(int j=0;j<ACH/256;++j){
      int c = j*256 + tid;
      int r = c >> 3;
      int jb = (c & 7) * 16;
      int grow = row0 + r; grow = (grow < M) ? grow : (M-1);
      const unsigned char* gp = (const unsigned char*)(Ab + (size_t)grow*ldab + kc) + (jb ^ ((r&7)<<4));
      gld_lds16(gp, &sA[buf][(j*256 + w*64)*16]);
    }
    #pragma unroll
    for(int j=0;j<BCH/256;++j){
      int c = j*256 + tid;
      int r = c >> 3;
      int jb = (c & 7) * 16;
      const unsigned char* gp = (const unsigned char*)(BTp + (size_t)r*K + k0) + (jb ^ ((r&7)<<4));
      gld_lds16(gp, &sB[buf][(j*256 + w*64)*16]);
    }
  };

  const int NT = K >> 6;
  stage(0, 0);
  __syncthreads();
  int cur = 0;
  for(int t=0; t<NT; ++t){
    if(t+1 < NT) stage(cur^1, (t+1)<<6);
    #pragma unroll
    for(int kk=0;kk<2;++kk){
      const int cb = kk*64 + (l>>4)*16;
      bf16x8 af[FR], bfr[FC];
      #pragma unroll
      for(int i=0;i<FR;++i){
        int r = wr*(16*FR) + i*16 + (l&15);
        af[i] = *reinterpret_cast<const bf16x8*>(&sA[cur][r*128 + (cb ^ ((r&7)<<4))]);
      }
      #pragma unroll
      for(int j=0;j<FC;++j){
        int c = wc*(16*FC) + j*16 + (l&15);
        bfr[j] = *reinterpret_cast<const bf16x8*>(&sB[cur][c*128 + (cb ^ ((c&7)<<4))]);
      }
      #pragma unroll
      for(int i=0;i<FR;++i)
        #pragma unroll
        for(int j=0;j<FC;++j)
          acc[i][j] = __builtin_amdgcn_mfma_f32_16x16x32_bf16(af[i], bfr[j], acc[i][j], 0, 0, 0);
    }
    __syncthreads();
    cur ^= 1;
  }
  #pragma unroll
  for(int i=0;i<FR;++i){
    #pragma unroll
    for(int rr=0;rr<4;++rr){
      int grow = row0 + wr*(16*FR) + i*16 + (l>>4)*4 + rr;
      if(grow >= M) continue;
      #pragma unroll
      for(int j=0;j<FC;++j){
        int col = col0 + wc*(16*FC) + j*16 + (l&15);
        float v = acc[i][j][rr];
        if(bias) v += bias[col];
        if(RELU) v = fmaxf(v, 0.f);
        if(OUTBF) ((ushortT*)Cv)[(size_t)grow*ldc + col] = f2bf(v);
        else      ((float*)Cv)[(size_t)grow*ldc + col] = v;
      }
    }
  }
}

// ---------------- host ----------------

extern "C" void kernel_launch(void* const* d_in, const int* in_sizes, int n_in,
                              void* d_out, int out_size, void* d_ws, size_t ws_size,
                              hipStream_t stream){
  const float* x_user   = (const float*)d_in[0];
  const float* x_item   = (const float*)d_in[1];
  const int*   ei       = (const int*)d_in[2];
  const int*   et       = (const int*)d_in[3];
  const float* W1_ui    = (const float*)d_in[4];
  const float* root1_ui = (const float*)d_in[5];
  const float* b1_ui    = (const float*)d_in[6];
  const float* W1_iu    = (const float*)d_in[7];
  const float* root1_iu = (const float*)d_in[8];
  const float* b1_iu    = (const float*)d_in[9];
  const float* W2_ui    = (const float*)d_in[10];
  const float* root2_ui = (const float*)d_in[11];
  const float* b2_ui    = (const float*)d_in[12];
  const float* W2_iu    = (const float*)d_in[13];
  const float* root2_iu = (const float*)d_in[14];
  const float* b2_iu    = (const float*)d_in[15];
  const int E = in_sizes[3];
  const int* src = ei;
  const int* dst = ei + E;
  float* out = (float*)d_out;

  const int NI5 = NITEMS*NREL, NU5 = NUSERS*NREL;
  const int NK5 = NI5 + NU5;

  uint8_t* ws = (uint8_t*)d_ws;
  size_t o = 0;
  auto alloc = [&](size_t bytes){ size_t r = o; o = align256(o + bytes); return r; };
  int* cnt  = (int*)(ws + alloc((size_t)NK5*4));
  int* off  = (int*)(ws + alloc((size_t)(NK5+1)*4));
  int* cur  = (int*)(ws + alloc((size_t)NK5*4));
  int* adj  = (int*)(ws + alloc((size_t)2*E*4));
  float* sc = (float*)(ws + alloc((size_t)2*E*4));
  int* btot = (int*)(ws + alloc(1024*4));
  int* boff = (int*)(ws + alloc(1024*4));
  ushortT* xu_bf = (ushortT*)(ws + alloc((size_t)NUSERS*UDIM*2));
  ushortT* xi_bf = (ushortT*)(ws + alloc((size_t)NITEMS*UDIM*2));
  ushortT* h1u   = (ushortT*)(ws + alloc((size_t)NUSERS*HID*2));
  ushortT* h1i   = (ushortT*)(ws + alloc((size_t)NITEMS*HID*2));
  ushortT* BT1ui = (ushortT*)(ws + alloc((size_t)HID*(6*UDIM)*2));
  ushortT* BT1iu = (ushortT*)(ws + alloc((size_t)HID*(6*UDIM)*2));
  ushortT* BTm2ui = (ushortT*)(ws + alloc((size_t)NREL*ODIM*HID*2));
  ushortT* BTm2iu = (ushortT*)(ws + alloc((size_t)NREL*ODIM*HID*2));
  ushortT* BTr2ui = (ushortT*)(ws + alloc((size_t)ODIM*HID*2));
  ushortT* BTr2iu = (ushortT*)(ws + alloc((size_t)ODIM*HID*2));
  ushortT* BT2ui = (ushortT*)(ws + alloc((size_t)ODIM*(6*HID)*2));   // M-fallback
  ushortT* BT2iu = (ushortT*)(ws + alloc((size_t)ODIM*(6*HID)*2));
  size_t bigoff = o;
  size_t avail = (ws_size > bigoff)? (ws_size - bigoff) : 0;
  uint8_t* big = ws + bigoff;

  const int* off_i = off;            // item-side segments
  const int* off_u = off + NI5;      // user-side segments

  size_t needH = align256((size_t)NUSERS*NREL*ODIM*2) + align256((size_t)NITEMS*ODIM*2);
  bool useH = (avail >= needH + 4096);

  // ---- CSR build (combined) ----
  hipMemsetAsync(cnt, 0, (size_t)NK5*4, stream);
  int eb = (E+255)/256;
  count_edges_k<<<eb,256,0,stream>>>(src,dst,et,E,cnt);
  int nb = (NK5+2047)/2048;
  scan_s1f<<<nb,256,0,stream>>>(cnt, NK5, btot);
  scan_s2<<<1,1024,0,stream>>>(btot, nb, boff, off+NK5);
  scan_s3f<<<nb,256,0,stream>>>(cnt, NK5, boff, off);
  copy_int_k<<<(NK5+255)/256,256,0,stream>>>(off, cur, NK5);
  scatter_k<<<eb,256,0,stream>>>(src,dst,et,E,cur,off,adj,sc);

  // ---- dtype prep ----
  {
    int n4 = NUSERS*UDIM/4;
    f2bf4_k<<<(n4+255)/256,256,0,stream>>>((const float4*)x_user, (uint2*)xu_bf, n4);
    n4 = NITEMS*UDIM/4;
    f2bf4_k<<<(n4+255)/256,256,0,stream>>>((const float4*)x_item, (uint2*)xi_bf, n4);
  }
  prep_bt_k<<<(HID*6*UDIM+255)/256,256,0,stream>>>(root1_ui, W1_ui, BT1ui, UDIM, HID);
  prep_bt_k<<<(HID*6*UDIM+255)/256,256,0,stream>>>(root1_iu, W1_iu, BT1iu, UDIM, HID);
  if(useH){
    int tot = NREL*ODIM*HID;
    prep_w_k<<<(tot+255)/256,256,0,stream>>>(W2_ui, BTm2ui, HID, ODIM, tot);
    prep_w_k<<<(tot+255)/256,256,0,stream>>>(W2_iu, BTm2iu, HID, ODIM, tot);
    prep_r_k<<<(ODIM*HID+255)/256,256,0,stream>>>(root2_ui, BTr2ui, HID, ODIM);
    prep_r_k<<<(ODIM*HID+255)/256,256,0,stream>>>(root2_iu, BTr2iu, HID, ODIM);
  } else {
    prep_bt_k<<<(ODIM*6*HID+255)/256,256,0,stream>>>(root2_ui, W2_ui, BT2ui, HID, ODIM);
    prep_bt_k<<<(ODIM*6*HID+255)/256,256,0,stream>>>(root2_iu, W2_iu, BT2iu, HID, ODIM);
  }

  // ---- layer 1: M-scheme agg + gemm2v (split-A: dst feats | means) ----
  {
    ushortT* Mbuf = (ushortT*)big;
    long long c1 = (long long)(avail / ((size_t)NREL*UDIM*2));
    int CH = (int)(c1 > NUSERS ? NUSERS : c1); CH &= ~127; if(CH < 128) CH = 128;
    for(int lo=0; lo<NITEMS; lo+=CH){
      int cn = imin(CH, NITEMS-lo);
      agg_m64_k<<<(cn+3)/4,256,0,stream>>>(xu_bf, adj, off_i + lo*NREL, Mbuf, 0, cn);
      gemm2v_k<64,128,true,true><<<dim3(1,(cn+63)/64),256,0,stream>>>(
          xi_bf + (size_t)lo*UDIM, UDIM, Mbuf, NREL*UDIM, UDIM,
          BT1ui, 6*UDIM, b1_ui, h1i + (size_t)lo*HID, HID, cn);
    }
    for(int lo=0; lo<NUSERS; lo+=CH){
      int cn = imin(CH, NUSERS-lo);
      agg_m64_k<<<(cn+3)/4,256,0,stream>>>(xi_bf, adj, off_u + lo*NREL, Mbuf, 0, cn);
      gemm2v_k<64,128,true,true><<<dim3(1,(cn+63)/64),256,0,stream>>>(
          xu_bf + (size_t)lo*UDIM, UDIM, Mbuf, NREL*UDIM, UDIM,
          BT1iu, b1_iu ? 6*UDIM : 6*UDIM, b1_iu, h1u + (size_t)lo*HID, HID, cn);
    }
  }

  // ---- layer 2: phased H-scheme ----
  float* user2 = out;
  float* item2 = out + (size_t)NUSERS*ODIM;
  if(useH){
    // phase A: user->item messages (single-pass over h1u via col-tiles on x) + item root
    ushortT* Hmsg_u  = (ushortT*)big;                                        // [NUSERS][320]
    ushortT* Hroot_i = (ushortT*)(big + align256((size_t)NUSERS*NREL*ODIM*2)); // [NITEMS][64]
    gemm2v_k<64,64,true,false><<<dim3(NREL,(NUSERS+63)/64),256,0,stream>>>(
        h1u, HID, h1u, HID, HID, BTm2ui, HID, nullptr, Hmsg_u, NREL*ODIM, NUSERS);
    gemm2v_k<64,64,true,false><<<dim3(1,(NITEMS+63)/64),256,0,stream>>>(
        h1i, HID, h1i, HID, HID, BTr2ui, HID, nullptr, Hroot_i, ODIM, NITEMS);
    agg_h_k<<<(NITEMS+3)/4,256,0,stream>>>(Hmsg_u, NREL*ODIM, Hroot_i, ODIM,
        adj, sc, off_i, b2_ui, item2, NITEMS);
    // phase B: item->user messages + user root (overlay phase-A buffers)
    ushortT* Hmsg_i  = (ushortT*)big;                                        // [NITEMS][320]
    ushortT* Hroot_u = (ushortT*)(big + align256((size_t)NITEMS*NREL*ODIM*2)); // [NUSERS][64]
    gemm2v_k<64,64,true,false><<<dim3(NREL,(NITEMS+63)/64),256,0,stream>>>(
        h1i, HID, h1i, HID, HID, BTm2iu, HID, nullptr, Hmsg_i, NREL*ODIM, NITEMS);
    gemm2v_k<64,64,true,false><<<dim3(1,(NUSERS+63)/64),256,0,stream>>>(
        h1u, HID, h1u, HID, HID, BTr2iu, HID, nullptr, Hroot_u, ODIM, NUSERS);
    agg_h_k<<<(NUSERS+3)/4,256,0,stream>>>(Hmsg_i, NREL*ODIM, Hroot_u, ODIM,
        adj, sc, off_u, b2_iu, user2, NUSERS);
  } else {
    // fallback M-scheme
    ushortT* Mbuf = (ushortT*)big;
    long long c2 = (long long)(avail / ((size_t)6*HID*2));
    int CH = (int)(c2 > NUSERS ? NUSERS : c2); CH &= ~127; if(CH < 128) CH = 128;
    for(int lo=0; lo<NITEMS; lo+=CH){
      int cn = imin(CH, NITEMS-lo);
      agg_m_k<HID><<<(cn+3)/4,256,0,stream>>>(h1u, h1i, adj, off_i, Mbuf, lo, cn);
      gemm2v_k<64,64,false,false><<<dim3(1,(cn+63)/64),256,0,stream>>>(
          Mbuf, 6*HID, Mbuf, 6*HID, 6*HID, BT2ui, 6*HID, b2_ui, item2 + (size_t)lo*ODIM, ODIM, cn);
    }
    for(int lo=0; lo<NUSERS; lo+=CH){
      int cn = imin(CH, NUSERS-lo);
      agg_m_k<HID><<<(cn+3)/4,256,0,stream>>>(h1i, h1u, adj, off_u, Mbuf, lo, cn);
      gemm2v_k<64,64,false,false><<<dim3(1,(cn+63)/64),256,0,stream>>>(
          Mbuf, 6*HID, Mbuf, 6*HID, 6*HID, BT2iu, 6*HID, b2_iu, user2 + (size_t)lo*ODIM, ODIM, cn);
    }
  }
}

// Round 10
// 609.245 us; speedup vs baseline: 1.2063x; 1.0474x over previous
//
#include <hip/hip_runtime.h>
#include <hip/hip_bf16.h>
#include <cstdint>
#include <cstddef>

#define NUSERS 200000
#define NITEMS 100000
#define UDIM 64
#define HID 128
#define ODIM 64
#define NREL 5

typedef unsigned short ushortT;
typedef __bf16 bf16x8 __attribute__((ext_vector_type(8)));
typedef __bf16 bf16x4p __attribute__((ext_vector_type(4)));
typedef float f32x4 __attribute__((ext_vector_type(4)));

static inline size_t align256(size_t x){ return (x + 255) & ~(size_t)255; }
static inline int imin(int a,int b){ return a<b?a:b; }

__device__ __forceinline__ unsigned short f2bf(float f){
  unsigned int u = __builtin_bit_cast(unsigned int, f);
  unsigned int r = (u + 0x7fffu + ((u>>16)&1u)) >> 16;   // RNE
  return (unsigned short)r;
}
__device__ __forceinline__ float b2f(unsigned short u){
  return __builtin_bit_cast(float, ((unsigned int)u)<<16);
}
__device__ __forceinline__ float blo(unsigned u){ return b2f((unsigned short)(u & 0xffff)); }
__device__ __forceinline__ float bhi(unsigned u){ return b2f((unsigned short)(u >> 16)); }
__device__ __forceinline__ uint2 pk4(float a, float b, float c, float d){
  bf16x4p t; t[0]=(__bf16)a; t[1]=(__bf16)b; t[2]=(__bf16)c; t[3]=(__bf16)d;
  return __builtin_bit_cast(uint2, t);   // compiler emits v_cvt_pk_bf16_f32 pairs
}
__device__ __forceinline__ void gld_lds16(const void* g, void* s){
  __builtin_amdgcn_global_load_lds((const __attribute__((address_space(1))) void*)g,
                                   (__attribute__((address_space(3))) void*)s, 16, 0, 0);
}

// ---------------- CSR build: ONE combined (node,relation) key space ----------------
// keys: item side [0, NI5), user side [NI5, NI5+NU5). adj/sc sized 2E.

__global__ void count_edges_k(const int* __restrict__ src, const int* __restrict__ dst,
                              const int* __restrict__ et, int E, int* __restrict__ cnt){
  int e = blockIdx.x*blockDim.x + threadIdx.x;
  if(e < E){
    int t = et[e];
    atomicAdd(&cnt[dst[e]*NREL + t], 1);
    atomicAdd(&cnt[NITEMS*NREL + src[e]*NREL + t], 1);
  }
}

// 2048 elems per block (8/thread) so nb <= 1024 for n = 1.5M
__global__ __launch_bounds__(256) void scan_s1f(const int* __restrict__ c, int n, int* __restrict__ btot){
  int t = threadIdx.x;
  int base = blockIdx.x*2048 + t*8;
  int s = 0;
  #pragma unroll
  for(int j=0;j<8;++j){ int i = base+j; if(i<n) s += c[i]; }
  __shared__ int red[256];
  red[t] = s; __syncthreads();
  for(int o=128;o>0;o>>=1){ if(t<o) red[t]+=red[t+o]; __syncthreads(); }
  if(t==0) btot[blockIdx.x] = red[0];
}

__global__ __launch_bounds__(1024) void scan_s2(const int* __restrict__ btot, int nb,
                                                int* __restrict__ boff, int* __restrict__ total_out){
  __shared__ int sh[1024];
  int t = threadIdx.x;
  int v = (t<nb)? btot[t] : 0;
  sh[t] = v; __syncthreads();
  for(int o=1;o<1024;o<<=1){
    int add = (t>=o)? sh[t-o] : 0;
    __syncthreads();
    sh[t] += add;
    __syncthreads();
  }
  if(t<nb) boff[t] = sh[t]-v;
  if(t==1023) *total_out = sh[1023];
}

__global__ __launch_bounds__(256) void scan_s3f(const int* __restrict__ c, int n,
                                                const int* __restrict__ boff, int* __restrict__ off){
  int t = threadIdx.x, b = blockIdx.x;
  int base = b*2048 + t*8;
  int pre[8]; int s = 0;
  #pragma unroll
  for(int j=0;j<8;++j){
    int i = base+j; int d = (i<n)? c[i] : 0;
    pre[j] = s; s += d;
  }
  __shared__ int sh[256];
  sh[t] = s; __syncthreads();
  int inc = s;
  for(int o=1;o<256;o<<=1){
    int add = (t>=o)? sh[t-o] : 0;
    __syncthreads();
    sh[t] += add;
    __syncthreads();
  }
  int texcl = sh[t] - inc;
  int bo = boff[b];
  #pragma unroll
  for(int j=0;j<8;++j){
    int i = base+j;
    if(i<n) off[i] = bo + texcl + pre[j];
  }
}

__global__ void copy_int_k(const int* __restrict__ a, int* __restrict__ b, int n){
  int i = blockIdx.x*blockDim.x + threadIdx.x;
  if(i < n) b[i] = a[i];
}

// adj entries packed (peer<<3)|rel; per-edge fp32 scale = 1/segment_count (from off diffs)
__global__ void scatter_k(const int* __restrict__ src, const int* __restrict__ dst,
                          const int* __restrict__ et, int E,
                          int* __restrict__ cur, const int* __restrict__ off,
                          int* __restrict__ adj, float* __restrict__ sc){
  int e = blockIdx.x*blockDim.x + threadIdx.x;
  if(e < E){
    int s = src[e], d = dst[e], t = et[e];
    int k1 = d*NREL + t;
    int p1 = atomicAdd(&cur[k1], 1);
    adj[p1] = (s<<3) | t;
    sc[p1] = 1.f/(float)(off[k1+1]-off[k1]);
    int k2 = NITEMS*NREL + s*NREL + t;
    int p2 = atomicAdd(&cur[k2], 1);
    adj[p2] = (d<<3) | t;
    sc[p2] = 1.f/(float)(off[k2+1]-off[k2]);
  }
}

// ---------------- dtype prep ----------------

__global__ void f2bf4_k(const float4* __restrict__ a, uint2* __restrict__ b, int n4){
  int i = blockIdx.x*blockDim.x + threadIdx.x;
  if(i < n4){
    float4 v = a[i];
    uint2 o;
    o.x = (unsigned)f2bf(v.x) | ((unsigned)f2bf(v.y)<<16);
    o.y = (unsigned)f2bf(v.z) | ((unsigned)f2bf(v.w)<<16);
    b[i] = o;
  }
}

// BT[Dout][6*Din] = [root; W_0..W_4]^T   (layer-1 B)
__global__ void prep_bt_k(const float* __restrict__ root, const float* __restrict__ W,
                          ushortT* __restrict__ BT, int Din, int Dout){
  int K = 6*Din;
  int idx = blockIdx.x*blockDim.x + threadIdx.x;
  if(idx >= Dout*K) return;
  int n = idx / K, k = idx % K;
  float v = (k < Din) ? root[(size_t)k*Dout + n] : W[(size_t)(k-Din)*Dout + n];
  BT[idx] = f2bf(v);
}

// BTm[R*C][K] : row n -> W[n/C][k][n%C]   (layer-2 message weights, transposed)
__global__ void prep_w_k(const float* __restrict__ W, ushortT* __restrict__ BT,
                         int Kdim, int C, int total){
  int idx = blockIdx.x*blockDim.x + threadIdx.x;
  if(idx >= total) return;
  int n = idx / Kdim, k = idx % Kdim;
  int r = n / C, c = n % C;
  BT[idx] = f2bf(W[((size_t)r*Kdim + k)*C + c]);
}

// BTr[C][K] : row n -> root[k][n]
__global__ void prep_r_k(const float* __restrict__ root, ushortT* __restrict__ BT,
                         int Kdim, int C){
  int idx = blockIdx.x*blockDim.x + threadIdx.x;
  if(idx >= C*Kdim) return;
  int n = idx / Kdim, k = idx % Kdim;
  BT[idx] = f2bf(root[(size_t)k*C + n]);
}

// ---------------- layer-1 aggregation (D=64): 16-lane group per node, no shuffles ----------------
// lane sub owns channels [4*sub, 4*sub+4). Serial edge loop per (node,rel) segment
// (avg segment len ~0.5-1 edge). Mbuf row = [mean_r0 | ... | mean_r4].

__global__ __launch_bounds__(256) void agg_m64_k(const ushortT* __restrict__ xsrc,
    const int* __restrict__ adj, const int* __restrict__ off5,
    ushortT* __restrict__ Mbuf, int cn)
{
  int gid = blockIdx.x*blockDim.x + threadIdx.x;
  int wid = gid >> 4;
  int sub = gid & 15;
  if(wid >= cn) return;
  const int* op = off5 + wid*NREL;
  int offs[6];
  #pragma unroll
  for(int r=0;r<6;++r) offs[r] = op[r];
  ushortT* mp = Mbuf + (size_t)wid*(NREL*UDIM) + sub*4;
  const ushortT* xp = xsrc + sub*4;
  #pragma unroll
  for(int r=0;r<NREL;++r){
    int e0 = offs[r], e1 = offs[r+1];
    uint2 o = {0u, 0u};
    if(e1 > e0){
      float s0=0.f, s1=0.f, s2=0.f, s3=0.f;
      for(int e=e0; e<e1; ++e){
        int p = adj[e] >> 3;
        uint2 u = *(const uint2*)(xp + (size_t)p*UDIM);
        s0 += blo(u.x); s1 += bhi(u.x); s2 += blo(u.y); s3 += bhi(u.y);
      }
      float scv = 1.f/(float)(e1-e0);
      o = pk4(s0*scv, s1*scv, s2*scv, s3*scv);
    }
    *(uint2*)(mp + r*UDIM) = o;
  }
}

// ---------------- layer-2 H aggregation ----------------
// out[node] = sum_e sc_e * msg[peer_e*msgStride + rel_e*64 ..] + root[node*rootStride ..] + bias

__global__ __launch_bounds__(256) void agg_h_k(const ushortT* __restrict__ msg, int msgStride,
    const ushortT* __restrict__ root, int rootStride,
    const int* __restrict__ adj, const float* __restrict__ adjsc,
    const int* __restrict__ off5, const float* __restrict__ bias,
    float* __restrict__ outp, int n)
{
  int wid  = (int)((blockIdx.x*(size_t)blockDim.x + threadIdx.x) >> 6);
  int l = threadIdx.x & 63;
  if(wid >= n) return;
  int g = l >> 4, sub = l & 15;
  int e0 = off5[wid*NREL], e1 = off5[wid*NREL + NREL];
  float a0=0.f,a1=0.f,a2=0.f,a3=0.f;
  int e = e0 + g;
  for(; e + 4 < e1; e += 8){
    int ad1 = adj[e];   float sc1 = adjsc[e];
    int ad2 = adj[e+4]; float sc2 = adjsc[e+4];
    uint2 u = *(const uint2*)(msg + (size_t)(ad1>>3)*msgStride + (ad1&7)*ODIM + sub*4);
    uint2 v = *(const uint2*)(msg + (size_t)(ad2>>3)*msgStride + (ad2&7)*ODIM + sub*4);
    a0 += blo(u.x)*sc1; a1 += bhi(u.x)*sc1; a2 += blo(u.y)*sc1; a3 += bhi(u.y)*sc1;
    a0 += blo(v.x)*sc2; a1 += bhi(v.x)*sc2; a2 += blo(v.y)*sc2; a3 += bhi(v.y)*sc2;
  }
  if(e < e1){
    int ad1 = adj[e]; float sc1 = adjsc[e];
    uint2 u = *(const uint2*)(msg + (size_t)(ad1>>3)*msgStride + (ad1&7)*ODIM + sub*4);
    a0 += blo(u.x)*sc1; a1 += bhi(u.x)*sc1; a2 += blo(u.y)*sc1; a3 += bhi(u.y)*sc1;
  }
  a0 += __shfl_xor(a0,16); a1 += __shfl_xor(a1,16); a2 += __shfl_xor(a2,16); a3 += __shfl_xor(a3,16);
  a0 += __shfl_xor(a0,32); a1 += __shfl_xor(a1,32); a2 += __shfl_xor(a2,32); a3 += __shfl_xor(a3,32);
  if(l < 16){
    uint2 rt = *(const uint2*)(root + (size_t)wid*rootStride + sub*4);
    float4 bv = *(const float4*)(bias + sub*4);
    float4 o;
    o.x = a0 + blo(rt.x) + bv.x;
    o.y = a1 + bhi(rt.x) + bv.y;
    o.z = a2 + blo(rt.y) + bv.z;
    o.w = a3 + bhi(rt.y) + bv.w;
    *(float4*)(outp + (size_t)wid*ODIM + sub*4) = o;
  }
}

// ---------------- fallback M-scheme agg (layer 2, only if ws too small) ----------------

template<int D>
__global__ __launch_bounds__(256) void agg_m_k(const ushortT* __restrict__ xsrc,
    const ushortT* __restrict__ xdst, const int* __restrict__ adj,
    const int* __restrict__ off5, ushortT* __restrict__ Mbuf, int lo, int cn)
{
  int wid  = (int)((blockIdx.x*(size_t)blockDim.x + threadIdx.x) >> 6);
  int lane = threadIdx.x & 63;
  if(wid >= cn) return;
  int node = lo + wid;
  constexpr int V = D/64;
  ushortT* mp = Mbuf + (size_t)wid*(6*D);
  if(V==2) *(unsigned*)(mp + lane*2) = *(const unsigned*)(xdst + (size_t)node*D + lane*2);
  else     mp[lane] = xdst[(size_t)node*D + lane];
  #pragma unroll
  for(int r=0;r<NREL;++r){
    int base = node*NREL + r;
    int e0 = off5[base], e1 = off5[base+1];
    float s0 = 0.f, s1 = 0.f;
    for(int e=e0; e<e1; ++e){
      int p = adj[e] >> 3;
      if(V==2){
        unsigned u = *(const unsigned*)(xsrc + (size_t)p*D + lane*2);
        s0 += blo(u); s1 += bhi(u);
      } else {
        s0 += b2f(xsrc[(size_t)p*D + lane]);
      }
    }
    int c = e1 - e0;
    float sc = 1.f/(float)(c>0? c:1);
    if(V==2){
      unsigned o = (unsigned)f2bf(s0*sc) | ((unsigned)f2bf(s1*sc)<<16);
      *(unsigned*)(mp + D + r*D + lane*2) = o;
    } else {
      mp[D + r*D + lane] = f2bf(s0*sc);
    }
  }
}

// ---------------- bf16 MFMA GEMM: BM=64, dbuf, col-tiles on blockIdx.x ----------------
// grid = dim3(ncolTiles, nrowTiles). 256 threads = 4 waves.
// Small LDS (32-48KB) -> 3-5 resident blocks/CU; cross-block TLP hides staging.
// A col k: k<KSPLIT -> A0 (lda0) else A1 (lda1). BT is [Ntot][K] row-major bf16.

template<int BM, int BN, bool OUTBF, bool RELU>
__global__ __launch_bounds__(256) void gemm2v_k(
    const ushortT* __restrict__ A0, int lda0,
    const ushortT* __restrict__ A1, int lda1, int KSPLIT,
    const ushortT* __restrict__ BT, int K,
    const float* __restrict__ bias,
    void* __restrict__ Cv, int ldc, int M)
{
  constexpr int WGC = (BN>=128)? 2 : 1;   // wave-grid cols
  constexpr int WGR = 4/WGC;              // wave-grid rows
  constexpr int FR  = BM/(16*WGR);
  constexpr int FC  = BN/(16*WGC);
  constexpr int ACH = BM*8;               // 16B chunks per 64-col K-tile
  constexpr int BCH = BN*8;
  __shared__ alignas(16) unsigned char sA[2][BM*128];
  __shared__ alignas(16) unsigned char sB[2][BN*128];

  const int tid = threadIdx.x;
  const int w = tid >> 6, l = tid & 63;
  const int wr = w / WGC, wc = w % WGC;
  const int row0 = blockIdx.y * BM;
  const int col0 = blockIdx.x * BN;
  const ushortT* BTp = BT + (size_t)col0 * K;

  f32x4 acc[FR][FC];
  #pragma unroll
  for(int i=0;i<FR;++i)
    #pragma unroll
    for(int j=0;j<FC;++j) acc[i][j] = (f32x4){0.f,0.f,0.f,0.f};

  auto stage = [&](int buf, int k0){
    const ushortT* Ab = (k0 < KSPLIT) ? A0 : A1;
    const int ldab    = (k0 < KSPLIT) ? lda0 : lda1;
    const int kc      = (k0 < KSPLIT) ? k0 : (k0 - KSPLIT);
    #pragma unroll
    for(int j=0;j<ACH/256;++j){
      int c = j*256 + tid;
      int r = c >> 3;
      int jb = (c & 7) * 16;
      int grow = row0 + r; grow = (grow < M) ? grow : (M-1);
      const unsigned char* gp = (const unsigned char*)(Ab + (size_t)grow*ldab + kc) + (jb ^ ((r&7)<<4));
      gld_lds16(gp, &sA[buf][(j*256 + w*64)*16]);
    }
    #pragma unroll
    for(int j=0;j<BCH/256;++j){
      int c = j*256 + tid;
      int r = c >> 3;
      int jb = (c & 7) * 16;
      const unsigned char* gp = (const unsigned char*)(BTp + (size_t)r*K + k0) + (jb ^ ((r&7)<<4));
      gld_lds16(gp, &sB[buf][(j*256 + w*64)*16]);
    }
  };

  const int NT = K >> 6;
  stage(0, 0);
  __syncthreads();
  int cur = 0;
  for(int t=0; t<NT; ++t){
    if(t+1 < NT) stage(cur^1, (t+1)<<6);
    #pragma unroll
    for(int kk=0;kk<2;++kk){
      const int cb = kk*64 + (l>>4)*16;
      bf16x8 af[FR], bfr[FC];
      #pragma unroll
      for(int i=0;i<FR;++i){
        int r = wr*(16*FR) + i*16 + (l&15);
        af[i] = *reinterpret_cast<const bf16x8*>(&sA[cur][r*128 + (cb ^ ((r&7)<<4))]);
      }
      #pragma unroll
      for(int j=0;j<FC;++j){
        int c = wc*(16*FC) + j*16 + (l&15);
        bfr[j] = *reinterpret_cast<const bf16x8*>(&sB[cur][c*128 + (cb ^ ((c&7)<<4))]);
      }
      #pragma unroll
      for(int i=0;i<FR;++i)
        #pragma unroll
        for(int j=0;j<FC;++j)
          acc[i][j] = __builtin_amdgcn_mfma_f32_16x16x32_bf16(af[i], bfr[j], acc[i][j], 0, 0, 0);
    }
    __syncthreads();
    cur ^= 1;
  }
  #pragma unroll
  for(int i=0;i<FR;++i){
    #pragma unroll
    for(int rr=0;rr<4;++rr){
      int grow = row0 + wr*(16*FR) + i*16 + (l>>4)*4 + rr;
      if(grow >= M) continue;
      #pragma unroll
      for(int j=0;j<FC;++j){
        int col = col0 + wc*(16*FC) + j*16 + (l&15);
        float v = acc[i][j][rr];
        if(bias) v += bias[col];
        if(RELU) v = fmaxf(v, 0.f);
        if(OUTBF) ((ushortT*)Cv)[(size_t)grow*ldc + col] = f2bf(v);
        else      ((float*)Cv)[(size_t)grow*ldc + col] = v;
      }
    }
  }
}

// ---------------- host ----------------

extern "C" void kernel_launch(void* const* d_in, const int* in_sizes, int n_in,
                              void* d_out, int out_size, void* d_ws, size_t ws_size,
                              hipStream_t stream){
  const float* x_user   = (const float*)d_in[0];
  const float* x_item   = (const float*)d_in[1];
  const int*   ei       = (const int*)d_in[2];
  const int*   et       = (const int*)d_in[3];
  const float* W1_ui    = (const float*)d_in[4];
  const float* root1_ui = (const float*)d_in[5];
  const float* b1_ui    = (const float*)d_in[6];
  const float* W1_iu    = (const float*)d_in[7];
  const float* root1_iu = (const float*)d_in[8];
  const float* b1_iu    = (const float*)d_in[9];
  const float* W2_ui    = (const float*)d_in[10];
  const float* root2_ui = (const float*)d_in[11];
  const float* b2_ui    = (const float*)d_in[12];
  const float* W2_iu    = (const float*)d_in[13];
  const float* root2_iu = (const float*)d_in[14];
  const float* b2_iu    = (const float*)d_in[15];
  const int E = in_sizes[3];
  const int* src = ei;
  const int* dst = ei + E;
  float* out = (float*)d_out;

  const int NI5 = NITEMS*NREL, NU5 = NUSERS*NREL;
  const int NK5 = NI5 + NU5;

  uint8_t* ws = (uint8_t*)d_ws;
  size_t o = 0;
  auto alloc = [&](size_t bytes){ size_t r = o; o = align256(o + bytes); return r; };
  int* cnt  = (int*)(ws + alloc((size_t)NK5*4));
  int* off  = (int*)(ws + alloc((size_t)(NK5+1)*4));
  int* cur  = (int*)(ws + alloc((size_t)NK5*4));
  int* adj  = (int*)(ws + alloc((size_t)2*E*4));
  float* sc = (float*)(ws + alloc((size_t)2*E*4));
  int* btot = (int*)(ws + alloc(1024*4));
  int* boff = (int*)(ws + alloc(1024*4));
  ushortT* xu_bf = (ushortT*)(ws + alloc((size_t)NUSERS*UDIM*2));
  ushortT* xi_bf = (ushortT*)(ws + alloc((size_t)NITEMS*UDIM*2));
  ushortT* h1u   = (ushortT*)(ws + alloc((size_t)NUSERS*HID*2));
  ushortT* h1i   = (ushortT*)(ws + alloc((size_t)NITEMS*HID*2));
  ushortT* BT1ui = (ushortT*)(ws + alloc((size_t)HID*(6*UDIM)*2));
  ushortT* BT1iu = (ushortT*)(ws + alloc((size_t)HID*(6*UDIM)*2));
  ushortT* BTm2ui = (ushortT*)(ws + alloc((size_t)NREL*ODIM*HID*2));
  ushortT* BTm2iu = (ushortT*)(ws + alloc((size_t)NREL*ODIM*HID*2));
  ushortT* BTr2ui = (ushortT*)(ws + alloc((size_t)ODIM*HID*2));
  ushortT* BTr2iu = (ushortT*)(ws + alloc((size_t)ODIM*HID*2));
  ushortT* BT2ui = (ushortT*)(ws + alloc((size_t)ODIM*(6*HID)*2));   // M-fallback
  ushortT* BT2iu = (ushortT*)(ws + alloc((size_t)ODIM*(6*HID)*2));
  size_t bigoff = o;
  size_t avail = (ws_size > bigoff)? (ws_size - bigoff) : 0;
  uint8_t* big = ws + bigoff;

  const int* off_i = off;            // item-side segments
  const int* off_u = off + NI5;      // user-side segments

  size_t needH = align256((size_t)NUSERS*NREL*ODIM*2) + align256((size_t)NITEMS*ODIM*2);
  bool useH = (avail >= needH + 4096);

  // ---- CSR build (combined) ----
  hipMemsetAsync(cnt, 0, (size_t)NK5*4, stream);
  int eb = (E+255)/256;
  count_edges_k<<<eb,256,0,stream>>>(src,dst,et,E,cnt);
  int nb = (NK5+2047)/2048;
  scan_s1f<<<nb,256,0,stream>>>(cnt, NK5, btot);
  scan_s2<<<1,1024,0,stream>>>(btot, nb, boff, off+NK5);
  scan_s3f<<<nb,256,0,stream>>>(cnt, NK5, boff, off);
  copy_int_k<<<(NK5+255)/256,256,0,stream>>>(off, cur, NK5);
  scatter_k<<<eb,256,0,stream>>>(src,dst,et,E,cur,off,adj,sc);

  // ---- dtype prep ----
  {
    int n4 = NUSERS*UDIM/4;
    f2bf4_k<<<(n4+255)/256,256,0,stream>>>((const float4*)x_user, (uint2*)xu_bf, n4);
    n4 = NITEMS*UDIM/4;
    f2bf4_k<<<(n4+255)/256,256,0,stream>>>((const float4*)x_item, (uint2*)xi_bf, n4);
  }
  prep_bt_k<<<(HID*6*UDIM+255)/256,256,0,stream>>>(root1_ui, W1_ui, BT1ui, UDIM, HID);
  prep_bt_k<<<(HID*6*UDIM+255)/256,256,0,stream>>>(root1_iu, W1_iu, BT1iu, UDIM, HID);
  if(useH){
    int tot = NREL*ODIM*HID;
    prep_w_k<<<(tot+255)/256,256,0,stream>>>(W2_ui, BTm2ui, HID, ODIM, tot);
    prep_w_k<<<(tot+255)/256,256,0,stream>>>(W2_iu, BTm2iu, HID, ODIM, tot);
    prep_r_k<<<(ODIM*HID+255)/256,256,0,stream>>>(root2_ui, BTr2ui, HID, ODIM);
    prep_r_k<<<(ODIM*HID+255)/256,256,0,stream>>>(root2_iu, BTr2iu, HID, ODIM);
  } else {
    prep_bt_k<<<(ODIM*6*HID+255)/256,256,0,stream>>>(root2_ui, W2_ui, BT2ui, HID, ODIM);
    prep_bt_k<<<(ODIM*6*HID+255)/256,256,0,stream>>>(root2_iu, W2_iu, BT2iu, HID, ODIM);
  }

  // ---- layer 1: M-scheme agg (no-shuffle) + gemm2v (split-A: dst feats | means) ----
  // CH=65536 -> Mbuf 40MB stays L3-resident between agg write and GEMM read.
  {
    ushortT* Mbuf = (ushortT*)big;
    long long c1 = (long long)(avail / ((size_t)NREL*UDIM*2));
    int CH = (int)(c1 > 65536 ? 65536 : c1); CH &= ~127; if(CH < 128) CH = 128;
    for(int lo=0; lo<NITEMS; lo+=CH){
      int cn = imin(CH, NITEMS-lo);
      agg_m64_k<<<(cn+15)/16,256,0,stream>>>(xu_bf, adj, off_i + lo*NREL, Mbuf, cn);
      gemm2v_k<64,128,true,true><<<dim3(1,(cn+63)/64),256,0,stream>>>(
          xi_bf + (size_t)lo*UDIM, UDIM, Mbuf, NREL*UDIM, UDIM,
          BT1ui, 6*UDIM, b1_ui, h1i + (size_t)lo*HID, HID, cn);
    }
    for(int lo=0; lo<NUSERS; lo+=CH){
      int cn = imin(CH, NUSERS-lo);
      agg_m64_k<<<(cn+15)/16,256,0,stream>>>(xi_bf, adj, off_u + lo*NREL, Mbuf, cn);
      gemm2v_k<64,128,true,true><<<dim3(1,(cn+63)/64),256,0,stream>>>(
          xu_bf + (size_t)lo*UDIM, UDIM, Mbuf, NREL*UDIM, UDIM,
          BT1iu, 6*UDIM, b1_iu, h1u + (size_t)lo*HID, HID, cn);
    }
  }

  // ---- layer 2: phased H-scheme ----
  float* user2 = out;
  float* item2 = out + (size_t)NUSERS*ODIM;
  if(useH){
    // phase A: user->item messages + item root
    ushortT* Hmsg_u  = (ushortT*)big;                                        // [NUSERS][320]
    ushortT* Hroot_i = (ushortT*)(big + align256((size_t)NUSERS*NREL*ODIM*2)); // [NITEMS][64]
    gemm2v_k<64,64,true,false><<<dim3(NREL,(NUSERS+63)/64),256,0,stream>>>(
        h1u, HID, h1u, HID, HID, BTm2ui, HID, nullptr, Hmsg_u, NREL*ODIM, NUSERS);
    gemm2v_k<64,64,true,false><<<dim3(1,(NITEMS+63)/64),256,0,stream>>>(
        h1i, HID, h1i, HID, HID, BTr2ui, HID, nullptr, Hroot_i, ODIM, NITEMS);
    agg_h_k<<<(NITEMS+3)/4,256,0,stream>>>(Hmsg_u, NREL*ODIM, Hroot_i, ODIM,
        adj, sc, off_i, b2_ui, item2, NITEMS);
    // phase B: item->user messages + user root (overlay)
    ushortT* Hmsg_i  = (ushortT*)big;                                        // [NITEMS][320]
    ushortT* Hroot_u = (ushortT*)(big + align256((size_t)NITEMS*NREL*ODIM*2)); // [NUSERS][64]
    gemm2v_k<64,64,true,false><<<dim3(NREL,(NITEMS+63)/64),256,0,stream>>>(
        h1i, HID, h1i, HID, HID, BTm2iu, HID, nullptr, Hmsg_i, NREL*ODIM, NITEMS);
    gemm2v_k<64,64,true,false><<<dim3(1,(NUSERS+63)/64),256,0,stream>>>(
        h1u, HID, h1u, HID, HID, BTr2iu, HID, nullptr, Hroot_u, ODIM, NUSERS);
    agg_h_k<<<(NUSERS+3)/4,256,0,stream>>>(Hmsg_i, NREL*ODIM, Hroot_u, ODIM,
        adj, sc, off_u, b2_iu, user2, NUSERS);
  } else {
    // fallback M-scheme
    ushortT* Mbuf = (ushortT*)big;
    long long c2 = (long long)(avail / ((size_t)6*HID*2));
    int CH = (int)(c2 > NUSERS ? NUSERS : c2); CH &= ~127; if(CH < 128) CH = 128;
    for(int lo=0; lo<NITEMS; lo+=CH){
      int cn = imin(CH, NITEMS-lo);
      agg_m_k<HID><<<(cn+3)/4,256,0,stream>>>(h1u, h1i, adj, off_i, Mbuf, lo, cn);
      gemm2v_k<64,64,false,false><<<dim3(1,(cn+63)/64),256,0,stream>>>(
          Mbuf, 6*HID, Mbuf, 6*HID, 6*HID, BT2ui, 6*HID, b2_ui, item2 + (size_t)lo*ODIM, ODIM, cn);
    }
    for(int lo=0; lo<NUSERS; lo+=CH){
      int cn = imin(CH, NUSERS-lo);
      agg_m_k<HID><<<(cn+3)/4,256,0,stream>>>(h1i, h1u, adj, off_u, Mbuf, lo, cn);
      gemm2v_k<64,64,false,false><<<dim3(1,(cn+63)/64),256,0,stream>>>(
          Mbuf, 6*HID, Mbuf, 6*HID, 6*HID, BT2iu, 6*HID, b2_iu, user2 + (size_t)lo*ODIM, ODIM, cn);
    }
  }
}

// Round 11
// 572.121 us; speedup vs baseline: 1.2846x; 1.0649x over previous
//
#include <hip/hip_runtime.h>
#include <hip/hip_bf16.h>
#include <cstdint>
#include <cstddef>

#define NUSERS 200000
#define NITEMS 100000
#define UDIM 64
#define HID 128
#define ODIM 64
#define NREL 5

typedef unsigned short ushortT;
typedef __bf16 bf16x8 __attribute__((ext_vector_type(8)));
typedef __bf16 bf16x4p __attribute__((ext_vector_type(4)));
typedef float f32x4 __attribute__((ext_vector_type(4)));

static inline size_t align256(size_t x){ return (x + 255) & ~(size_t)255; }
static inline int imin(int a,int b){ return a<b?a:b; }

__device__ __forceinline__ unsigned short f2bf(float f){
  unsigned int u = __builtin_bit_cast(unsigned int, f);
  unsigned int r = (u + 0x7fffu + ((u>>16)&1u)) >> 16;   // RNE
  return (unsigned short)r;
}
__device__ __forceinline__ float b2f(unsigned short u){
  return __builtin_bit_cast(float, ((unsigned int)u)<<16);
}
__device__ __forceinline__ float blo(unsigned u){ return b2f((unsigned short)(u & 0xffff)); }
__device__ __forceinline__ float bhi(unsigned u){ return b2f((unsigned short)(u >> 16)); }
__device__ __forceinline__ uint2 pk4(float a, float b, float c, float d){
  bf16x4p t; t[0]=(__bf16)a; t[1]=(__bf16)b; t[2]=(__bf16)c; t[3]=(__bf16)d;
  return __builtin_bit_cast(uint2, t);   // compiler emits v_cvt_pk_bf16_f32 pairs
}
__device__ __forceinline__ void gld_lds16(const void* g, void* s){
  __builtin_amdgcn_global_load_lds((const __attribute__((address_space(1))) void*)g,
                                   (__attribute__((address_space(3))) void*)s, 16, 0, 0);
}

// ---------------- CSR build: ONE combined (node,relation) key space ----------------
// keys: item side [0, NI5), user side [NI5, NI5+NU5). edg sized 2E: {(peer<<3)|rel, scaleBits}.

__global__ void count_edges_k(const int* __restrict__ src, const int* __restrict__ dst,
                              const int* __restrict__ et, int E, int* __restrict__ cnt){
  int e = blockIdx.x*blockDim.x + threadIdx.x;
  if(e < E){
    int t = et[e];
    atomicAdd(&cnt[dst[e]*NREL + t], 1);
    atomicAdd(&cnt[NITEMS*NREL + src[e]*NREL + t], 1);
  }
}

// 2048 elems per block (8/thread) so nb <= 1024 for n = 1.5M
__global__ __launch_bounds__(256) void scan_s1f(const int* __restrict__ c, int n, int* __restrict__ btot){
  int t = threadIdx.x;
  int base = blockIdx.x*2048 + t*8;
  int s = 0;
  #pragma unroll
  for(int j=0;j<8;++j){ int i = base+j; if(i<n) s += c[i]; }
  __shared__ int red[256];
  red[t] = s; __syncthreads();
  for(int o=128;o>0;o>>=1){ if(t<o) red[t]+=red[t+o]; __syncthreads(); }
  if(t==0) btot[blockIdx.x] = red[0];
}

__global__ __launch_bounds__(1024) void scan_s2(const int* __restrict__ btot, int nb,
                                                int* __restrict__ boff, int* __restrict__ total_out){
  __shared__ int sh[1024];
  int t = threadIdx.x;
  int v = (t<nb)? btot[t] : 0;
  sh[t] = v; __syncthreads();
  for(int o=1;o<1024;o<<=1){
    int add = (t>=o)? sh[t-o] : 0;
    __syncthreads();
    sh[t] += add;
    __syncthreads();
  }
  if(t<nb) boff[t] = sh[t]-v;
  if(t==1023) *total_out = sh[1023];
}

__global__ __launch_bounds__(256) void scan_s3f(const int* __restrict__ c, int n,
                                                const int* __restrict__ boff, int* __restrict__ off){
  int t = threadIdx.x, b = blockIdx.x;
  int base = b*2048 + t*8;
  int pre[8]; int s = 0;
  #pragma unroll
  for(int j=0;j<8;++j){
    int i = base+j; int d = (i<n)? c[i] : 0;
    pre[j] = s; s += d;
  }
  __shared__ int sh[256];
  sh[t] = s; __syncthreads();
  int inc = s;
  for(int o=1;o<256;o<<=1){
    int add = (t>=o)? sh[t-o] : 0;
    __syncthreads();
    sh[t] += add;
    __syncthreads();
  }
  int texcl = sh[t] - inc;
  int bo = boff[b];
  #pragma unroll
  for(int j=0;j<8;++j){
    int i = base+j;
    if(i<n) off[i] = bo + texcl + pre[j];
  }
}

__global__ void copy_int_k(const int* __restrict__ a, int* __restrict__ b, int n){
  int i = blockIdx.x*blockDim.x + threadIdx.x;
  if(i < n) b[i] = a[i];
}

// edg entries: {.x = (peer<<3)|rel, .y = bitcast(1/segment_count)}
__global__ void scatter_k(const int* __restrict__ src, const int* __restrict__ dst,
                          const int* __restrict__ et, int E,
                          int* __restrict__ cur, const int* __restrict__ off,
                          int2* __restrict__ edg){
  int e = blockIdx.x*blockDim.x + threadIdx.x;
  if(e < E){
    int s = src[e], d = dst[e], t = et[e];
    int k1 = d*NREL + t;
    int p1 = atomicAdd(&cur[k1], 1);
    edg[p1] = make_int2((s<<3)|t,
        __builtin_bit_cast(int, 1.f/(float)(off[k1+1]-off[k1])));
    int k2 = NITEMS*NREL + s*NREL + t;
    int p2 = atomicAdd(&cur[k2], 1);
    edg[p2] = make_int2((d<<3)|t,
        __builtin_bit_cast(int, 1.f/(float)(off[k2+1]-off[k2])));
  }
}

// ---------------- dtype prep ----------------

__global__ void f2bf4_k(const float4* __restrict__ a, uint2* __restrict__ b, int n4){
  int i = blockIdx.x*blockDim.x + threadIdx.x;
  if(i < n4){
    float4 v = a[i];
    uint2 o;
    o.x = (unsigned)f2bf(v.x) | ((unsigned)f2bf(v.y)<<16);
    o.y = (unsigned)f2bf(v.z) | ((unsigned)f2bf(v.w)<<16);
    b[i] = o;
  }
}

// BT[Dout][6*Din] = [root; W_0..W_4]^T   (layer-1 B)
__global__ void prep_bt_k(const float* __restrict__ root, const float* __restrict__ W,
                          ushortT* __restrict__ BT, int Din, int Dout){
  int K = 6*Din;
  int idx = blockIdx.x*blockDim.x + threadIdx.x;
  if(idx >= Dout*K) return;
  int n = idx / K, k = idx % K;
  float v = (k < Din) ? root[(size_t)k*Dout + n] : W[(size_t)(k-Din)*Dout + n];
  BT[idx] = f2bf(v);
}

// BTm[R*C][K] : row n -> W[n/C][k][n%C]   (layer-2 message weights, transposed)
__global__ void prep_w_k(const float* __restrict__ W, ushortT* __restrict__ BT,
                         int Kdim, int C, int total){
  int idx = blockIdx.x*blockDim.x + threadIdx.x;
  if(idx >= total) return;
  int n = idx / Kdim, k = idx % Kdim;
  int r = n / C, c = n % C;
  BT[idx] = f2bf(W[((size_t)r*Kdim + k)*C + c]);
}

// BTr[C][K] : row n -> root[k][n]
__global__ void prep_r_k(const float* __restrict__ root, ushortT* __restrict__ BT,
                         int Kdim, int C){
  int idx = blockIdx.x*blockDim.x + threadIdx.x;
  if(idx >= C*Kdim) return;
  int n = idx / Kdim, k = idx % Kdim;
  BT[idx] = f2bf(root[(size_t)k*C + n]);
}

// ---------------- layer-1 aggregation (D=64): 16-lane group per node, no shuffles ----------------

__global__ __launch_bounds__(256) void agg_m64_k(const ushortT* __restrict__ xsrc,
    const int2* __restrict__ edg, const int* __restrict__ off5,
    ushortT* __restrict__ Mbuf, int cn)
{
  int gid = blockIdx.x*blockDim.x + threadIdx.x;
  int wid = gid >> 4;
  int sub = gid & 15;
  if(wid >= cn) return;
  const int* op = off5 + wid*NREL;
  int offs[6];
  #pragma unroll
  for(int r=0;r<6;++r) offs[r] = op[r];
  ushortT* mp = Mbuf + (size_t)wid*(NREL*UDIM) + sub*4;
  const ushortT* xp = xsrc + sub*4;
  #pragma unroll
  for(int r=0;r<NREL;++r){
    int e0 = offs[r], e1 = offs[r+1];
    uint2 o = {0u, 0u};
    if(e1 > e0){
      float s0=0.f, s1=0.f, s2=0.f, s3=0.f;
      for(int e=e0; e<e1; ++e){
        int p = edg[e].x >> 3;
        uint2 u = *(const uint2*)(xp + (size_t)p*UDIM);
        s0 += blo(u.x); s1 += bhi(u.x); s2 += blo(u.y); s3 += bhi(u.y);
      }
      float scv = 1.f/(float)(e1-e0);
      o = pk4(s0*scv, s1*scv, s2*scv, s3*scv);
    }
    *(uint2*)(mp + r*UDIM) = o;
  }
}

// ---------------- layer-2 H aggregation: 16-lane group per node, no shuffles ----------------
// out[node] = sum_e sc_e * msg[peer_e*msgStride + rel_e*64 ..] + root[node*rootStride ..] + bias

__global__ __launch_bounds__(256) void agg_h_k(const ushortT* __restrict__ msg, int msgStride,
    const ushortT* __restrict__ root, int rootStride,
    const int2* __restrict__ edg, const int* __restrict__ off5,
    const float* __restrict__ bias, float* __restrict__ outp, int n)
{
  int gid = blockIdx.x*blockDim.x + threadIdx.x;
  int node = gid >> 4;
  int sub = gid & 15;
  if(node >= n) return;
  int e0 = off5[node*NREL], e1 = off5[node*NREL + NREL];
  float a0=0.f,a1=0.f,a2=0.f,a3=0.f;
  for(int e=e0; e<e1; ++e){
    int2 ed = edg[e];
    float scv = __builtin_bit_cast(float, ed.y);
    uint2 u = *(const uint2*)(msg + (size_t)(ed.x>>3)*msgStride + (ed.x&7)*ODIM + sub*4);
    a0 += blo(u.x)*scv; a1 += bhi(u.x)*scv; a2 += blo(u.y)*scv; a3 += bhi(u.y)*scv;
  }
  uint2 rt = *(const uint2*)(root + (size_t)node*rootStride + sub*4);
  float4 bv = *(const float4*)(bias + sub*4);
  float4 o;
  o.x = a0 + blo(rt.x) + bv.x;
  o.y = a1 + bhi(rt.x) + bv.y;
  o.z = a2 + blo(rt.y) + bv.z;
  o.w = a3 + bhi(rt.y) + bv.w;
  *(float4*)(outp + (size_t)node*ODIM + sub*4) = o;
}

// ---------------- fallback M-scheme agg (layer 2, only if ws too small) ----------------

template<int D>
__global__ __launch_bounds__(256) void agg_m_k(const ushortT* __restrict__ xsrc,
    const ushortT* __restrict__ xdst, const int2* __restrict__ edg,
    const int* __restrict__ off5, ushortT* __restrict__ Mbuf, int lo, int cn)
{
  int wid  = (int)((blockIdx.x*(size_t)blockDim.x + threadIdx.x) >> 6);
  int lane = threadIdx.x & 63;
  if(wid >= cn) return;
  int node = lo + wid;
  constexpr int V = D/64;
  ushortT* mp = Mbuf + (size_t)wid*(6*D);
  if(V==2) *(unsigned*)(mp + lane*2) = *(const unsigned*)(xdst + (size_t)node*D + lane*2);
  else     mp[lane] = xdst[(size_t)node*D + lane];
  #pragma unroll
  for(int r=0;r<NREL;++r){
    int base = node*NREL + r;
    int e0 = off5[base], e1 = off5[base+1];
    float s0 = 0.f, s1 = 0.f;
    for(int e=e0; e<e1; ++e){
      int p = edg[e].x >> 3;
      if(V==2){
        unsigned u = *(const unsigned*)(xsrc + (size_t)p*D + lane*2);
        s0 += blo(u); s1 += bhi(u);
      } else {
        s0 += b2f(xsrc[(size_t)p*D + lane]);
      }
    }
    int c = e1 - e0;
    float sc = 1.f/(float)(c>0? c:1);
    if(V==2){
      unsigned o = (unsigned)f2bf(s0*sc) | ((unsigned)f2bf(s1*sc)<<16);
      *(unsigned*)(mp + D + r*D + lane*2) = o;
    } else {
      mp[D + r*D + lane] = f2bf(s0*sc);
    }
  }
}

// ---------------- bf16 MFMA GEMM: BM=64, dbuf, col-tiles on blockIdx.x ----------------
// grid = dim3(ncolTiles, nrowTiles). 256 threads = 4 waves.
// Small LDS (32-48KB) -> 3-5 resident blocks/CU; cross-block TLP hides staging.
// A col k: k<KSPLIT -> A0 (lda0) else A1 (lda1). BT is [Ntot][K] row-major bf16.

template<int BM, int BN, bool OUTBF, bool RELU>
__global__ __launch_bounds__(256) void gemm2v_k(
    const ushortT* __restrict__ A0, int lda0,
    const ushortT* __restrict__ A1, int lda1, int KSPLIT,
    const ushortT* __restrict__ BT, int K,
    const float* __restrict__ bias,
    void* __restrict__ Cv, int ldc, int M)
{
  constexpr int WGC = (BN>=128)? 2 : 1;   // wave-grid cols
  constexpr int WGR = 4/WGC;              // wave-grid rows
  constexpr int FR  = BM/(16*WGR);
  constexpr int FC  = BN/(16*WGC);
  constexpr int ACH = BM*8;               // 16B chunks per 64-col K-tile
  constexpr int BCH = BN*8;
  __shared__ alignas(16) unsigned char sA[2][BM*128];
  __shared__ alignas(16) unsigned char sB[2][BN*128];

  const int tid = threadIdx.x;
  const int w = tid >> 6, l = tid & 63;
  const int wr = w / WGC, wc = w % WGC;
  const int row0 = blockIdx.y * BM;
  const int col0 = blockIdx.x * BN;
  const ushortT* BTp = BT + (size_t)col0 * K;

  f32x4 acc[FR][FC];
  #pragma unroll
  for(int i=0;i<FR;++i)
    #pragma unroll
    for(int j=0;j<FC;++j) acc[i][j] = (f32x4){0.f,0.f,0.f,0.f};

  auto stage = [&](int buf, int k0){
    const ushortT* Ab = (k0 < KSPLIT) ? A0 : A1;
    const int ldab    = (k0 < KSPLIT) ? lda0 : lda1;
    const int kc      = (k0 < KSPLIT) ? k0 : (k0 - KSPLIT);
    #pragma unroll
    for(int j=0;j<ACH/256;++j){
      int c = j*256 + tid;
      int r = c >> 3;
      int jb = (c & 7) * 16;
      int grow = row0 + r; grow = (grow < M) ? grow : (M-1);
      const unsigned char* gp = (const unsigned char*)(Ab + (size_t)grow*ldab + kc) + (jb ^ ((r&7)<<4));
      gld_lds16(gp, &sA[buf][(j*256 + w*64)*16]);
    }
    #pragma unroll
    for(int j=0;j<BCH/256;++j){
      int c = j*256 + tid;
      int r = c >> 3;
      int jb = (c & 7) * 16;
      const unsigned char* gp = (const unsigned char*)(BTp + (size_t)r*K + k0) + (jb ^ ((r&7)<<4));
      gld_lds16(gp, &sB[buf][(j*256 + w*64)*16]);
    }
  };

  const int NT = K >> 6;
  stage(0, 0);
  __syncthreads();
  int cur = 0;
  for(int t=0; t<NT; ++t){
    if(t+1 < NT) stage(cur^1, (t+1)<<6);
    #pragma unroll
    for(int kk=0;kk<2;++kk){
      const int cb = kk*64 + (l>>4)*16;
      bf16x8 af[FR], bfr[FC];
      #pragma unroll
      for(int i=0;i<FR;++i){
        int r = wr*(16*FR) + i*16 + (l&15);
        af[i] = *reinterpret_cast<const bf16x8*>(&sA[cur][r*128 + (cb ^ ((r&7)<<4))]);
      }
      #pragma unroll
      for(int j=0;j<FC;++j){
        int c = wc*(16*FC) + j*16 + (l&15);
        bfr[j] = *reinterpret_cast<const bf16x8*>(&sB[cur][c*128 + (cb ^ ((c&7)<<4))]);
      }
      #pragma unroll
      for(int i=0;i<FR;++i)
        #pragma unroll
        for(int j=0;j<FC;++j)
          acc[i][j] = __builtin_amdgcn_mfma_f32_16x16x32_bf16(af[i], bfr[j], acc[i][j], 0, 0, 0);
    }
    __syncthreads();
    cur ^= 1;
  }
  #pragma unroll
  for(int i=0;i<FR;++i){
    #pragma unroll
    for(int rr=0;rr<4;++rr){
      int grow = row0 + wr*(16*FR) + i*16 + (l>>4)*4 + rr;
      if(grow >= M) continue;
      #pragma unroll
      for(int j=0;j<FC;++j){
        int col = col0 + wc*(16*FC) + j*16 + (l&15);
        float v = acc[i][j][rr];
        if(bias) v += bias[col];
        if(RELU) v = fmaxf(v, 0.f);
        if(OUTBF) ((ushortT*)Cv)[(size_t)grow*ldc + col] = f2bf(v);
        else      ((float*)Cv)[(size_t)grow*ldc + col] = v;
      }
    }
  }
}

// ---------------- host ----------------

extern "C" void kernel_launch(void* const* d_in, const int* in_sizes, int n_in,
                              void* d_out, int out_size, void* d_ws, size_t ws_size,
                              hipStream_t stream){
  const float* x_user   = (const float*)d_in[0];
  const float* x_item   = (const float*)d_in[1];
  const int*   ei       = (const int*)d_in[2];
  const int*   et       = (const int*)d_in[3];
  const float* W1_ui    = (const float*)d_in[4];
  const float* root1_ui = (const float*)d_in[5];
  const float* b1_ui    = (const float*)d_in[6];
  const float* W1_iu    = (const float*)d_in[7];
  const float* root1_iu = (const float*)d_in[8];
  const float* b1_iu    = (const float*)d_in[9];
  const float* W2_ui    = (const float*)d_in[10];
  const float* root2_ui = (const float*)d_in[11];
  const float* b2_ui    = (const float*)d_in[12];
  const float* W2_iu    = (const float*)d_in[13];
  const float* root2_iu = (const float*)d_in[14];
  const float* b2_iu    = (const float*)d_in[15];
  const int E = in_sizes[3];
  const int* src = ei;
  const int* dst = ei + E;
  float* out = (float*)d_out;

  const int NI5 = NITEMS*NREL, NU5 = NUSERS*NREL;
  const int NK5 = NI5 + NU5;

  uint8_t* ws = (uint8_t*)d_ws;
  size_t o = 0;
  auto alloc = [&](size_t bytes){ size_t r = o; o = align256(o + bytes); return r; };
  int* cnt  = (int*)(ws + alloc((size_t)NK5*4));
  int* off  = (int*)(ws + alloc((size_t)(NK5+1)*4));
  int* cur  = (int*)(ws + alloc((size_t)NK5*4));
  int2* edg = (int2*)(ws + alloc((size_t)2*E*8));
  int* btot = (int*)(ws + alloc(1024*4));
  int* boff = (int*)(ws + alloc(1024*4));
  ushortT* xu_bf = (ushortT*)(ws + alloc((size_t)NUSERS*UDIM*2));
  ushortT* xi_bf = (ushortT*)(ws + alloc((size_t)NITEMS*UDIM*2));
  ushortT* h1u   = (ushortT*)(ws + alloc((size_t)NUSERS*HID*2));
  ushortT* h1i   = (ushortT*)(ws + alloc((size_t)NITEMS*HID*2));
  ushortT* BT1ui = (ushortT*)(ws + alloc((size_t)HID*(6*UDIM)*2));
  ushortT* BT1iu = (ushortT*)(ws + alloc((size_t)HID*(6*UDIM)*2));
  ushortT* BTm2ui = (ushortT*)(ws + alloc((size_t)NREL*ODIM*HID*2));
  ushortT* BTm2iu = (ushortT*)(ws + alloc((size_t)NREL*ODIM*HID*2));
  ushortT* BTr2ui = (ushortT*)(ws + alloc((size_t)ODIM*HID*2));
  ushortT* BTr2iu = (ushortT*)(ws + alloc((size_t)ODIM*HID*2));
  ushortT* BT2ui = (ushortT*)(ws + alloc((size_t)ODIM*(6*HID)*2));   // M-fallback
  ushortT* BT2iu = (ushortT*)(ws + alloc((size_t)ODIM*(6*HID)*2));
  size_t bigoff = o;
  size_t avail = (ws_size > bigoff)? (ws_size - bigoff) : 0;
  uint8_t* big = ws + bigoff;

  const int* off_i = off;            // item-side segments
  const int* off_u = off + NI5;      // user-side segments

  size_t needH = align256((size_t)NUSERS*NREL*ODIM*2) + align256((size_t)NITEMS*ODIM*2);
  bool useH = (avail >= needH + 4096);

  // ---- CSR build (combined) ----
  hipMemsetAsync(cnt, 0, (size_t)NK5*4, stream);
  int eb = (E+255)/256;
  count_edges_k<<<eb,256,0,stream>>>(src,dst,et,E,cnt);
  int nb = (NK5+2047)/2048;
  scan_s1f<<<nb,256,0,stream>>>(cnt, NK5, btot);
  scan_s2<<<1,1024,0,stream>>>(btot, nb, boff, off+NK5);
  scan_s3f<<<nb,256,0,stream>>>(cnt, NK5, boff, off);
  copy_int_k<<<(NK5+255)/256,256,0,stream>>>(off, cur, NK5);
  scatter_k<<<eb,256,0,stream>>>(src,dst,et,E,cur,off,edg);

  // ---- dtype prep ----
  {
    int n4 = NUSERS*UDIM/4;
    f2bf4_k<<<(n4+255)/256,256,0,stream>>>((const float4*)x_user, (uint2*)xu_bf, n4);
    n4 = NITEMS*UDIM/4;
    f2bf4_k<<<(n4+255)/256,256,0,stream>>>((const float4*)x_item, (uint2*)xi_bf, n4);
  }
  prep_bt_k<<<(HID*6*UDIM+255)/256,256,0,stream>>>(root1_ui, W1_ui, BT1ui, UDIM, HID);
  prep_bt_k<<<(HID*6*UDIM+255)/256,256,0,stream>>>(root1_iu, W1_iu, BT1iu, UDIM, HID);
  if(useH){
    int tot = NREL*ODIM*HID;
    prep_w_k<<<(tot+255)/256,256,0,stream>>>(W2_ui, BTm2ui, HID, ODIM, tot);
    prep_w_k<<<(tot+255)/256,256,0,stream>>>(W2_iu, BTm2iu, HID, ODIM, tot);
    prep_r_k<<<(ODIM*HID+255)/256,256,0,stream>>>(root2_ui, BTr2ui, HID, ODIM);
    prep_r_k<<<(ODIM*HID+255)/256,256,0,stream>>>(root2_iu, BTr2iu, HID, ODIM);
  } else {
    prep_bt_k<<<(ODIM*6*HID+255)/256,256,0,stream>>>(root2_ui, W2_ui, BT2ui, HID, ODIM);
    prep_bt_k<<<(ODIM*6*HID+255)/256,256,0,stream>>>(root2_iu, W2_iu, BT2iu, HID, ODIM);
  }

  // ---- layer 1: M-scheme agg (no-shuffle) + gemm2v (split-A: dst feats | means) ----
  // CH=65536 -> Mbuf 40MB stays L3-resident between agg write and GEMM read.
  {
    ushortT* Mbuf = (ushortT*)big;
    long long c1 = (long long)(avail / ((size_t)NREL*UDIM*2));
    int CH = (int)(c1 > 65536 ? 65536 : c1); CH &= ~127; if(CH < 128) CH = 128;
    for(int lo=0; lo<NITEMS; lo+=CH){
      int cn = imin(CH, NITEMS-lo);
      agg_m64_k<<<(cn+15)/16,256,0,stream>>>(xu_bf, edg, off_i + lo*NREL, Mbuf, cn);
      gemm2v_k<64,128,true,true><<<dim3(1,(cn+63)/64),256,0,stream>>>(
          xi_bf + (size_t)lo*UDIM, UDIM, Mbuf, NREL*UDIM, UDIM,
          BT1ui, 6*UDIM, b1_ui, h1i + (size_t)lo*HID, HID, cn);
    }
    for(int lo=0; lo<NUSERS; lo+=CH){
      int cn = imin(CH, NUSERS-lo);
      agg_m64_k<<<(cn+15)/16,256,0,stream>>>(xi_bf, edg, off_u + lo*NREL, Mbuf, cn);
      gemm2v_k<64,128,true,true><<<dim3(1,(cn+63)/64),256,0,stream>>>(
          xu_bf + (size_t)lo*UDIM, UDIM, Mbuf, NREL*UDIM, UDIM,
          BT1iu, 6*UDIM, b1_iu, h1u + (size_t)lo*HID, HID, cn);
    }
  }

  // ---- layer 2: phased H-scheme ----
  float* user2 = out;
  float* item2 = out + (size_t)NUSERS*ODIM;
  if(useH){
    // phase A: user->item messages + item root
    ushortT* Hmsg_u  = (ushortT*)big;                                        // [NUSERS][320]
    ushortT* Hroot_i = (ushortT*)(big + align256((size_t)NUSERS*NREL*ODIM*2)); // [NITEMS][64]
    gemm2v_k<64,64,true,false><<<dim3(NREL,(NUSERS+63)/64),256,0,stream>>>(
        h1u, HID, h1u, HID, HID, BTm2ui, HID, nullptr, Hmsg_u, NREL*ODIM, NUSERS);
    gemm2v_k<64,64,true,false><<<dim3(1,(NITEMS+63)/64),256,0,stream>>>(
        h1i, HID, h1i, HID, HID, BTr2ui, HID, nullptr, Hroot_i, ODIM, NITEMS);
    agg_h_k<<<(NITEMS+15)/16,256,0,stream>>>(Hmsg_u, NREL*ODIM, Hroot_i, ODIM,
        edg, off_i, b2_ui, item2, NITEMS);
    // phase B: item->user messages + user root (overlay)
    ushortT* Hmsg_i  = (ushortT*)big;                                        // [NITEMS][320]
    ushortT* Hroot_u = (ushortT*)(big + align256((size_t)NITEMS*NREL*ODIM*2)); // [NUSERS][64]
    gemm2v_k<64,64,true,false><<<dim3(NREL,(NITEMS+63)/64),256,0,stream>>>(
        h1i, HID, h1i, HID, HID, BTm2iu, HID, nullptr, Hmsg_i, NREL*ODIM, NITEMS);
    gemm2v_k<64,64,true,false><<<dim3(1,(NUSERS+63)/64),256,0,stream>>>(
        h1u, HID, h1u, HID, HID, BTr2iu, HID, nullptr, Hroot_u, ODIM, NUSERS);
    agg_h_k<<<(NUSERS+15)/16,256,0,stream>>>(Hmsg_i, NREL*ODIM, Hroot_u, ODIM,
        edg, off_u, b2_iu, user2, NUSERS);
  } else {
    // fallback M-scheme
    ushortT* Mbuf = (ushortT*)big;
    long long c2 = (long long)(avail / ((size_t)6*HID*2));
    int CH = (int)(c2 > NUSERS ? NUSERS : c2); CH &= ~127; if(CH < 128) CH = 128;
    for(int lo=0; lo<NITEMS; lo+=CH){
      int cn = imin(CH, NITEMS-lo);
      agg_m_k<HID><<<(cn+3)/4,256,0,stream>>>(h1u, h1i, edg, off_i, Mbuf, lo, cn);
      gemm2v_k<64,64,false,false><<<dim3(1,(cn+63)/64),256,0,stream>>>(
          Mbuf, 6*HID, Mbuf, 6*HID, 6*HID, BT2ui, 6*HID, b2_ui, item2 + (size_t)lo*ODIM, ODIM, cn);
    }
    for(int lo=0; lo<NUSERS; lo+=CH){
      int cn = imin(CH, NUSERS-lo);
      agg_m_k<HID><<<(cn+3)/4,256,0,stream>>>(h1i, h1u, edg, off_u, Mbuf, lo, cn);
      gemm2v_k<64,64,false,false><<<dim3(1,(cn+63)/64),256,0,stream>>>(
          Mbuf, 6*HID, Mbuf, 6*HID, 6*HID, BT2iu, 6*HID, b2_iu, user2 + (size_t)lo*ODIM, ODIM, cn);
    }
  }
}

// Round 12
// 551.887 us; speedup vs baseline: 1.3317x; 1.0367x over previous
//
#include <hip/hip_runtime.h>
#include <hip/hip_bf16.h>
#include <cstdint>
#include <cstddef>

#define NUSERS 200000
#define NITEMS 100000
#define UDIM 64
#define HID 128
#define ODIM 64
#define NREL 5

typedef unsigned short ushortT;
typedef __bf16 bf16x8 __attribute__((ext_vector_type(8)));
typedef __bf16 bf16x4p __attribute__((ext_vector_type(4)));
typedef float f32x4 __attribute__((ext_vector_type(4)));

static inline size_t align256(size_t x){ return (x + 255) & ~(size_t)255; }
static inline int imin(int a,int b){ return a<b?a:b; }

__device__ __forceinline__ unsigned short f2bf(float f){
  unsigned int u = __builtin_bit_cast(unsigned int, f);
  unsigned int r = (u + 0x7fffu + ((u>>16)&1u)) >> 16;   // RNE
  return (unsigned short)r;
}
__device__ __forceinline__ float b2f(unsigned short u){
  return __builtin_bit_cast(float, ((unsigned int)u)<<16);
}
__device__ __forceinline__ float blo(unsigned u){ return b2f((unsigned short)(u & 0xffff)); }
__device__ __forceinline__ float bhi(unsigned u){ return b2f((unsigned short)(u >> 16)); }
__device__ __forceinline__ uint2 pk4(float a, float b, float c, float d){
  bf16x4p t; t[0]=(__bf16)a; t[1]=(__bf16)b; t[2]=(__bf16)c; t[3]=(__bf16)d;
  return __builtin_bit_cast(uint2, t);
}
__device__ __forceinline__ void gld_lds16(const void* g, void* s){
  __builtin_amdgcn_global_load_lds((const __attribute__((address_space(1))) void*)g,
                                   (__attribute__((address_space(3))) void*)s, 16, 0, 0);
}

// ---------------- CSR build: ONE combined (node,relation) key space ----------------
// keys: item side [0, NI5), user side [NI5, NI5+NU5). edg sized 2E: {(peer<<3)|rel, scaleBits}.

__global__ void count_edges_k(const int* __restrict__ src, const int* __restrict__ dst,
                              const int* __restrict__ et, int E, int* __restrict__ cnt){
  int e = blockIdx.x*blockDim.x + threadIdx.x;
  if(e < E){
    int t = et[e];
    atomicAdd(&cnt[dst[e]*NREL + t], 1);
    atomicAdd(&cnt[NITEMS*NREL + src[e]*NREL + t], 1);
  }
}

__global__ __launch_bounds__(256) void scan_s1f(const int* __restrict__ c, int n, int* __restrict__ btot){
  int t = threadIdx.x;
  int base = blockIdx.x*2048 + t*8;
  int s = 0;
  #pragma unroll
  for(int j=0;j<8;++j){ int i = base+j; if(i<n) s += c[i]; }
  __shared__ int red[256];
  red[t] = s; __syncthreads();
  for(int o=128;o>0;o>>=1){ if(t<o) red[t]+=red[t+o]; __syncthreads(); }
  if(t==0) btot[blockIdx.x] = red[0];
}

__global__ __launch_bounds__(1024) void scan_s2(const int* __restrict__ btot, int nb,
                                                int* __restrict__ boff, int* __restrict__ total_out){
  __shared__ int sh[1024];
  int t = threadIdx.x;
  int v = (t<nb)? btot[t] : 0;
  sh[t] = v; __syncthreads();
  for(int o=1;o<1024;o<<=1){
    int add = (t>=o)? sh[t-o] : 0;
    __syncthreads();
    sh[t] += add;
    __syncthreads();
  }
  if(t<nb) boff[t] = sh[t]-v;
  if(t==1023) *total_out = sh[1023];
}

__global__ __launch_bounds__(256) void scan_s3f(const int* __restrict__ c, int n,
                                                const int* __restrict__ boff, int* __restrict__ off){
  int t = threadIdx.x, b = blockIdx.x;
  int base = b*2048 + t*8;
  int pre[8]; int s = 0;
  #pragma unroll
  for(int j=0;j<8;++j){
    int i = base+j; int d = (i<n)? c[i] : 0;
    pre[j] = s; s += d;
  }
  __shared__ int sh[256];
  sh[t] = s; __syncthreads();
  int inc = s;
  for(int o=1;o<256;o<<=1){
    int add = (t>=o)? sh[t-o] : 0;
    __syncthreads();
    sh[t] += add;
    __syncthreads();
  }
  int texcl = sh[t] - inc;
  int bo = boff[b];
  #pragma unroll
  for(int j=0;j<8;++j){
    int i = base+j;
    if(i<n) off[i] = bo + texcl + pre[j];
  }
}

__global__ void copy_int_k(const int* __restrict__ a, int* __restrict__ b, int n){
  int i = blockIdx.x*blockDim.x + threadIdx.x;
  if(i < n) b[i] = a[i];
}

// edg entries: {.x = (peer<<3)|rel, .y = bitcast(1/segment_count)}
__global__ void scatter_k(const int* __restrict__ src, const int* __restrict__ dst,
                          const int* __restrict__ et, int E,
                          int* __restrict__ cur, const int* __restrict__ off,
                          int2* __restrict__ edg){
  int e = blockIdx.x*blockDim.x + threadIdx.x;
  if(e < E){
    int s = src[e], d = dst[e], t = et[e];
    int k1 = d*NREL + t;
    int p1 = atomicAdd(&cur[k1], 1);
    edg[p1] = make_int2((s<<3)|t,
        __builtin_bit_cast(int, 1.f/(float)(off[k1+1]-off[k1])));
    int k2 = NITEMS*NREL + s*NREL + t;
    int p2 = atomicAdd(&cur[k2], 1);
    edg[p2] = make_int2((d<<3)|t,
        __builtin_bit_cast(int, 1.f/(float)(off[k2+1]-off[k2])));
  }
}

// ---------------- dtype prep ----------------

__global__ void f2bf4_k(const float4* __restrict__ a, uint2* __restrict__ b, int n4){
  int i = blockIdx.x*blockDim.x + threadIdx.x;
  if(i < n4){
    float4 v = a[i];
    uint2 o;
    o.x = (unsigned)f2bf(v.x) | ((unsigned)f2bf(v.y)<<16);
    o.y = (unsigned)f2bf(v.z) | ((unsigned)f2bf(v.w)<<16);
    b[i] = o;
  }
}

// BT[Dout][6*Din] = [root; W_0..W_4]^T   (layer-1 B)
__global__ void prep_bt_k(const float* __restrict__ root, const float* __restrict__ W,
                          ushortT* __restrict__ BT, int Din, int Dout){
  int K = 6*Din;
  int idx = blockIdx.x*blockDim.x + threadIdx.x;
  if(idx >= Dout*K) return;
  int n = idx / K, k = idx % K;
  float v = (k < Din) ? root[(size_t)k*Dout + n] : W[(size_t)(k-Din)*Dout + n];
  BT[idx] = f2bf(v);
}

// BTm[R*C][K] : row n -> W[n/C][k][n%C]   (layer-2 message weights, transposed)
__global__ void prep_w_k(const float* __restrict__ W, ushortT* __restrict__ BT,
                         int Kdim, int C, int total){
  int idx = blockIdx.x*blockDim.x + threadIdx.x;
  if(idx >= total) return;
  int n = idx / Kdim, k = idx % Kdim;
  int r = n / C, c = n % C;
  BT[idx] = f2bf(W[((size_t)r*Kdim + k)*C + c]);
}

// BTr[C][K] : row n -> root[k][n]
__global__ void prep_r_k(const float* __restrict__ root, ushortT* __restrict__ BT,
                         int Kdim, int C){
  int idx = blockIdx.x*blockDim.x + threadIdx.x;
  if(idx >= C*Kdim) return;
  int n = idx / Kdim, k = idx % Kdim;
  BT[idx] = f2bf(root[(size_t)k*C + n]);
}

// ---------------- layer-1 aggregation (D=64): 16-lane group per node, no shuffles ----------------

__global__ __launch_bounds__(256) void agg_m64_k(const ushortT* __restrict__ xsrc,
    const int2* __restrict__ edg, const int* __restrict__ off5,
    ushortT* __restrict__ Mbuf, int cn)
{
  int gid = blockIdx.x*blockDim.x + threadIdx.x;
  int wid = gid >> 4;
  int sub = gid & 15;
  if(wid >= cn) return;
  const int* op = off5 + wid*NREL;
  int offs[6];
  #pragma unroll
  for(int r=0;r<6;++r) offs[r] = op[r];
  ushortT* mp = Mbuf + (size_t)wid*(NREL*UDIM) + sub*4;
  const ushortT* xp = xsrc + sub*4;
  #pragma unroll
  for(int r=0;r<NREL;++r){
    int e0 = offs[r], e1 = offs[r+1];
    uint2 o = {0u, 0u};
    if(e1 > e0){
      float s0=0.f, s1=0.f, s2=0.f, s3=0.f;
      for(int e=e0; e<e1; ++e){
        int p = edg[e].x >> 3;
        uint2 u = *(const uint2*)(xp + (size_t)p*UDIM);
        s0 += blo(u.x); s1 += bhi(u.x); s2 += blo(u.y); s3 += bhi(u.y);
      }
      float scv = 1.f/(float)(e1-e0);
      o = pk4(s0*scv, s1*scv, s2*scv, s3*scv);
    }
    *(uint2*)(mp + r*UDIM) = o;
  }
}

// ---------------- layer-2 H aggregation: 16-lane group per node, no shuffles ----------------

__global__ __launch_bounds__(256) void agg_h_k(const ushortT* __restrict__ msg, int msgStride,
    const ushortT* __restrict__ root, int rootStride,
    const int2* __restrict__ edg, const int* __restrict__ off5,
    const float* __restrict__ bias, float* __restrict__ outp, int n)
{
  int gid = blockIdx.x*blockDim.x + threadIdx.x;
  int node = gid >> 4;
  int sub = gid & 15;
  if(node >= n) return;
  int e0 = off5[node*NREL], e1 = off5[node*NREL + NREL];
  float a0=0.f,a1=0.f,a2=0.f,a3=0.f;
  for(int e=e0; e<e1; ++e){
    int2 ed = edg[e];
    float scv = __builtin_bit_cast(float, ed.y);
    uint2 u = *(const uint2*)(msg + (size_t)(ed.x>>3)*msgStride + (ed.x&7)*ODIM + sub*4);
    a0 += blo(u.x)*scv; a1 += bhi(u.x)*scv; a2 += blo(u.y)*scv; a3 += bhi(u.y)*scv;
  }
  uint2 rt = *(const uint2*)(root + (size_t)node*rootStride + sub*4);
  float4 bv = *(const float4*)(bias + sub*4);
  float4 o;
  o.x = a0 + blo(rt.x) + bv.x;
  o.y = a1 + bhi(rt.x) + bv.y;
  o.z = a2 + blo(rt.y) + bv.z;
  o.w = a3 + bhi(rt.y) + bv.w;
  *(float4*)(outp + (size_t)node*ODIM + sub*4) = o;
}

// ---------------- fallback M-scheme agg (layer 2, only if ws too small) ----------------

template<int D>
__global__ __launch_bounds__(256) void agg_m_k(const ushortT* __restrict__ xsrc,
    const ushortT* __restrict__ xdst, const int2* __restrict__ edg,
    const int* __restrict__ off5, ushortT* __restrict__ Mbuf, int lo, int cn)
{
  int wid  = (int)((blockIdx.x*(size_t)blockDim.x + threadIdx.x) >> 6);
  int lane = threadIdx.x & 63;
  if(wid >= cn) return;
  int node = lo + wid;
  constexpr int V = D/64;
  ushortT* mp = Mbuf + (size_t)wid*(6*D);
  if(V==2) *(unsigned*)(mp + lane*2) = *(const unsigned*)(xdst + (size_t)node*D + lane*2);
  else     mp[lane] = xdst[(size_t)node*D + lane];
  #pragma unroll
  for(int r=0;r<NREL;++r){
    int base = node*NREL + r;
    int e0 = off5[base], e1 = off5[base+1];
    float s0 = 0.f, s1 = 0.f;
    for(int e=e0; e<e1; ++e){
      int p = edg[e].x >> 3;
      if(V==2){
        unsigned u = *(const unsigned*)(xsrc + (size_t)p*D + lane*2);
        s0 += blo(u); s1 += bhi(u);
      } else {
        s0 += b2f(xsrc[(size_t)p*D + lane]);
      }
    }
    int c = e1 - e0;
    float sc = 1.f/(float)(c>0? c:1);
    if(V==2){
      unsigned o = (unsigned)f2bf(s0*sc) | ((unsigned)f2bf(s1*sc)<<16);
      *(unsigned*)(mp + D + r*D + lane*2) = o;
    } else {
      mp[D + r*D + lane] = f2bf(s0*sc);
    }
  }
}

// ---------------- A-resident multi-slice GEMM (K=128): C[:, s*64..] = A @ BT_s^T ----------------
// One block: stage 64-row A tile ONCE (hoisted to registers), loop over SL B-slices
// (double-buffered, prefetch s+1 while computing s). A fetched exactly once from HBM.
// 256 threads = 4 waves (2x2); wave computes 32x32 per slice. LDS 48KB -> 3 blocks/CU.

template<int SL>
__global__ __launch_bounds__(256) void gemmM_k(
    const ushortT* __restrict__ A,    // [M][128] bf16
    const ushortT* __restrict__ BT,   // [SL*64][128] bf16
    ushortT* __restrict__ C, int ldc, int M)
{
  constexpr int K = 128, ROWB = 256;
  __shared__ alignas(16) unsigned char sA[64*ROWB];
  __shared__ alignas(16) unsigned char sB[2][64*ROWB];
  const int tid = threadIdx.x;
  const int w = tid >> 6, l = tid & 63;
  const int wr = w >> 1, wc = w & 1;
  const int row0 = blockIdx.x * 64;

  // stage A tile (1024 x 16B chunks; linear LDS dest, inverse-swizzled source)
  #pragma unroll
  for(int j=0;j<4;++j){
    int c = j*256 + tid;
    int r = c >> 4;                 // 16 chunks per 256B row
    int jb = (c & 15) * 16;
    int grow = row0 + r; grow = (grow < M) ? grow : (M-1);
    const unsigned char* gp = (const unsigned char*)(A + (size_t)grow*K) + (jb ^ ((r&7)<<4));
    gld_lds16(gp, sA + (size_t)(j*256 + w*64)*16);
  }
  auto stageB = [&](int buf, int s){
    const ushortT* Bp = BT + (size_t)s*64*K;
    #pragma unroll
    for(int j=0;j<4;++j){
      int c = j*256 + tid;
      int r = c >> 4;
      int jb = (c & 15) * 16;
      const unsigned char* gp = (const unsigned char*)(Bp + (size_t)r*K) + (jb ^ ((r&7)<<4));
      gld_lds16(gp, &sB[buf][(size_t)(j*256 + w*64)*16]);
    }
  };
  stageB(0, 0);
  __syncthreads();

  // hoist A fragments to registers (read LDS once)
  bf16x8 af[4][2];
  #pragma unroll
  for(int kk=0;kk<4;++kk){
    int cb = kk*64 + (l>>4)*16;
    #pragma unroll
    for(int i=0;i<2;++i){
      int r = wr*32 + i*16 + (l&15);
      af[kk][i] = *reinterpret_cast<const bf16x8*>(sA + (size_t)r*ROWB + (cb ^ ((r&7)<<4)));
    }
  }

  int cur = 0;
  for(int s=0; s<SL; ++s){
    if(s+1 < SL) stageB(cur^1, s+1);     // prefetch next slice under compute
    f32x4 acc[2][2];
    #pragma unroll
    for(int i=0;i<2;++i)
      #pragma unroll
      for(int j=0;j<2;++j) acc[i][j] = (f32x4){0.f,0.f,0.f,0.f};
    #pragma unroll
    for(int kk=0;kk<4;++kk){
      int cb = kk*64 + (l>>4)*16;
      bf16x8 bfr[2];
      #pragma unroll
      for(int j=0;j<2;++j){
        int cN = wc*32 + j*16 + (l&15);
        bfr[j] = *reinterpret_cast<const bf16x8*>(&sB[cur][(size_t)cN*ROWB + (cb ^ ((cN&7)<<4))]);
      }
      #pragma unroll
      for(int i=0;i<2;++i)
        #pragma unroll
        for(int j=0;j<2;++j)
          acc[i][j] = __builtin_amdgcn_mfma_f32_16x16x32_bf16(af[kk][i], bfr[j], acc[i][j], 0, 0, 0);
    }
    #pragma unroll
    for(int i=0;i<2;++i){
      #pragma unroll
      for(int rr=0;rr<4;++rr){
        int grow = row0 + wr*32 + i*16 + (l>>4)*4 + rr;
        if(grow >= M) continue;
        #pragma unroll
        for(int j=0;j<2;++j){
          int col = s*64 + wc*32 + j*16 + (l&15);
          C[(size_t)grow*ldc + col] = f2bf(acc[i][j][rr]);
        }
      }
    }
    __syncthreads();   // drains prefetch; one barrier per slice
    cur ^= 1;
  }
}

// ---------------- bf16 MFMA GEMM: BM=64, dbuf K-loop (layer-1 + fallback) ----------------

template<int BM, int BN, bool OUTBF, bool RELU>
__global__ __launch_bounds__(256) void gemm2v_k(
    const ushortT* __restrict__ A0, int lda0,
    const ushortT* __restrict__ A1, int lda1, int KSPLIT,
    const ushortT* __restrict__ BT, int K,
    const float* __restrict__ bias,
    void* __restrict__ Cv, int ldc, int M)
{
  constexpr int WGC = (BN>=128)? 2 : 1;
  constexpr int WGR = 4/WGC;
  constexpr int FR  = BM/(16*WGR);
  constexpr int FC  = BN/(16*WGC);
  constexpr int ACH = BM*8;
  constexpr int BCH = BN*8;
  __shared__ alignas(16) unsigned char sA[2][BM*128];
  __shared__ alignas(16) unsigned char sB[2][BN*128];

  const int tid = threadIdx.x;
  const int w = tid >> 6, l = tid & 63;
  const int wr = w / WGC, wc = w % WGC;
  const int row0 = blockIdx.y * BM;
  const int col0 = blockIdx.x * BN;
  const ushortT* BTp = BT + (size_t)col0 * K;

  f32x4 acc[FR][FC];
  #pragma unroll
  for(int i=0;i<FR;++i)
    #pragma unroll
    for(int j=0;j<FC;++j) acc[i][j] = (f32x4){0.f,0.f,0.f,0.f};

  auto stage = [&](int buf, int k0){
    const ushortT* Ab = (k0 < KSPLIT) ? A0 : A1;
    const int ldab    = (k0 < KSPLIT) ? lda0 : lda1;
    const int kc      = (k0 < KSPLIT) ? k0 : (k0 - KSPLIT);
    #pragma unroll
    for(int j=0;j<ACH/256;++j){
      int c = j*256 + tid;
      int r = c >> 3;
      int jb = (c & 7) * 16;
      int grow = row0 + r; grow = (grow < M) ? grow : (M-1);
      const unsigned char* gp = (const unsigned char*)(Ab + (size_t)grow*ldab + kc) + (jb ^ ((r&7)<<4));
      gld_lds16(gp, &sA[buf][(j*256 + w*64)*16]);
    }
    #pragma unroll
    for(int j=0;j<BCH/256;++j){
      int c = j*256 + tid;
      int r = c >> 3;
      int jb = (c & 7) * 16;
      const unsigned char* gp = (const unsigned char*)(BTp + (size_t)r*K + k0) + (jb ^ ((r&7)<<4));
      gld_lds16(gp, &sB[buf][(j*256 + w*64)*16]);
    }
  };

  const int NT = K >> 6;
  stage(0, 0);
  __syncthreads();
  int cur = 0;
  for(int t=0; t<NT; ++t){
    if(t+1 < NT) stage(cur^1, (t+1)<<6);
    #pragma unroll
    for(int kk=0;kk<2;++kk){
      const int cb = kk*64 + (l>>4)*16;
      bf16x8 af[FR], bfr[FC];
      #pragma unroll
      for(int i=0;i<FR;++i){
        int r = wr*(16*FR) + i*16 + (l&15);
        af[i] = *reinterpret_cast<const bf16x8*>(&sA[cur][r*128 + (cb ^ ((r&7)<<4))]);
      }
      #pragma unroll
      for(int j=0;j<FC;++j){
        int c = wc*(16*FC) + j*16 + (l&15);
        bfr[j] = *reinterpret_cast<const bf16x8*>(&sB[cur][c*128 + (cb ^ ((c&7)<<4))]);
      }
      #pragma unroll
      for(int i=0;i<FR;++i)
        #pragma unroll
        for(int j=0;j<FC;++j)
          acc[i][j] = __builtin_amdgcn_mfma_f32_16x16x32_bf16(af[i], bfr[j], acc[i][j], 0, 0, 0);
    }
    __syncthreads();
    cur ^= 1;
  }
  #pragma unroll
  for(int i=0;i<FR;++i){
    #pragma unroll
    for(int rr=0;rr<4;++rr){
      int grow = row0 + wr*(16*FR) + i*16 + (l>>4)*4 + rr;
      if(grow >= M) continue;
      #pragma unroll
      for(int j=0;j<FC;++j){
        int col = col0 + wc*(16*FC) + j*16 + (l&15);
        float v = acc[i][j][rr];
        if(bias) v += bias[col];
        if(RELU) v = fmaxf(v, 0.f);
        if(OUTBF) ((ushortT*)Cv)[(size_t)grow*ldc + col] = f2bf(v);
        else      ((float*)Cv)[(size_t)grow*ldc + col] = v;
      }
    }
  }
}

// ---------------- host ----------------

extern "C" void kernel_launch(void* const* d_in, const int* in_sizes, int n_in,
                              void* d_out, int out_size, void* d_ws, size_t ws_size,
                              hipStream_t stream){
  const float* x_user   = (const float*)d_in[0];
  const float* x_item   = (const float*)d_in[1];
  const int*   ei       = (const int*)d_in[2];
  const int*   et       = (const int*)d_in[3];
  const float* W1_ui    = (const float*)d_in[4];
  const float* root1_ui = (const float*)d_in[5];
  const float* b1_ui    = (const float*)d_in[6];
  const float* W1_iu    = (const float*)d_in[7];
  const float* root1_iu = (const float*)d_in[8];
  const float* b1_iu    = (const float*)d_in[9];
  const float* W2_ui    = (const float*)d_in[10];
  const float* root2_ui = (const float*)d_in[11];
  const float* b2_ui    = (const float*)d_in[12];
  const float* W2_iu    = (const float*)d_in[13];
  const float* root2_iu = (const float*)d_in[14];
  const float* b2_iu    = (const float*)d_in[15];
  const int E = in_sizes[3];
  const int* src = ei;
  const int* dst = ei + E;
  float* out = (float*)d_out;

  const int NI5 = NITEMS*NREL, NU5 = NUSERS*NREL;
  const int NK5 = NI5 + NU5;

  uint8_t* ws = (uint8_t*)d_ws;
  size_t o = 0;
  auto alloc = [&](size_t bytes){ size_t r = o; o = align256(o + bytes); return r; };
  int* cnt  = (int*)(ws + alloc((size_t)NK5*4));
  int* off  = (int*)(ws + alloc((size_t)(NK5+1)*4));
  int* cur  = (int*)(ws + alloc((size_t)NK5*4));
  int2* edg = (int2*)(ws + alloc((size_t)2*E*8));
  int* btot = (int*)(ws + alloc(1024*4));
  int* boff = (int*)(ws + alloc(1024*4));
  ushortT* xu_bf = (ushortT*)(ws + alloc((size_t)NUSERS*UDIM*2));
  ushortT* xi_bf = (ushortT*)(ws + alloc((size_t)NITEMS*UDIM*2));
  ushortT* h1u   = (ushortT*)(ws + alloc((size_t)NUSERS*HID*2));
  ushortT* h1i   = (ushortT*)(ws + alloc((size_t)NITEMS*HID*2));
  ushortT* BT1ui = (ushortT*)(ws + alloc((size_t)HID*(6*UDIM)*2));
  ushortT* BT1iu = (ushortT*)(ws + alloc((size_t)HID*(6*UDIM)*2));
  ushortT* BTm2ui = (ushortT*)(ws + alloc((size_t)NREL*ODIM*HID*2));
  ushortT* BTm2iu = (ushortT*)(ws + alloc((size_t)NREL*ODIM*HID*2));
  ushortT* BTr2ui = (ushortT*)(ws + alloc((size_t)ODIM*HID*2));
  ushortT* BTr2iu = (ushortT*)(ws + alloc((size_t)ODIM*HID*2));
  ushortT* BT2ui = (ushortT*)(ws + alloc((size_t)ODIM*(6*HID)*2));   // M-fallback
  ushortT* BT2iu = (ushortT*)(ws + alloc((size_t)ODIM*(6*HID)*2));
  size_t bigoff = o;
  size_t avail = (ws_size > bigoff)? (ws_size - bigoff) : 0;
  uint8_t* big = ws + bigoff;

  const int* off_i = off;            // item-side segments
  const int* off_u = off + NI5;      // user-side segments

  size_t needH = align256((size_t)NUSERS*NREL*ODIM*2) + align256((size_t)NITEMS*ODIM*2);
  bool useH = (avail >= needH + 4096);

  // ---- CSR build (combined) ----
  hipMemsetAsync(cnt, 0, (size_t)NK5*4, stream);
  int eb = (E+255)/256;
  count_edges_k<<<eb,256,0,stream>>>(src,dst,et,E,cnt);
  int nb = (NK5+2047)/2048;
  scan_s1f<<<nb,256,0,stream>>>(cnt, NK5, btot);
  scan_s2<<<1,1024,0,stream>>>(btot, nb, boff, off+NK5);
  scan_s3f<<<nb,256,0,stream>>>(cnt, NK5, boff, off);
  copy_int_k<<<(NK5+255)/256,256,0,stream>>>(off, cur, NK5);
  scatter_k<<<eb,256,0,stream>>>(src,dst,et,E,cur,off,edg);

  // ---- dtype prep ----
  {
    int n4 = NUSERS*UDIM/4;
    f2bf4_k<<<(n4+255)/256,256,0,stream>>>((const float4*)x_user, (uint2*)xu_bf, n4);
    n4 = NITEMS*UDIM/4;
    f2bf4_k<<<(n4+255)/256,256,0,stream>>>((const float4*)x_item, (uint2*)xi_bf, n4);
  }
  prep_bt_k<<<(HID*6*UDIM+255)/256,256,0,stream>>>(root1_ui, W1_ui, BT1ui, UDIM, HID);
  prep_bt_k<<<(HID*6*UDIM+255)/256,256,0,stream>>>(root1_iu, W1_iu, BT1iu, UDIM, HID);
  if(useH){
    int tot = NREL*ODIM*HID;
    prep_w_k<<<(tot+255)/256,256,0,stream>>>(W2_ui, BTm2ui, HID, ODIM, tot);
    prep_w_k<<<(tot+255)/256,256,0,stream>>>(W2_iu, BTm2iu, HID, ODIM, tot);
    prep_r_k<<<(ODIM*HID+255)/256,256,0,stream>>>(root2_ui, BTr2ui, HID, ODIM);
    prep_r_k<<<(ODIM*HID+255)/256,256,0,stream>>>(root2_iu, BTr2iu, HID, ODIM);
  } else {
    prep_bt_k<<<(ODIM*6*HID+255)/256,256,0,stream>>>(root2_ui, W2_ui, BT2ui, HID, ODIM);
    prep_bt_k<<<(ODIM*6*HID+255)/256,256,0,stream>>>(root2_iu, W2_iu, BT2iu, HID, ODIM);
  }

  // ---- layer 1: M-scheme agg (no-shuffle) + gemm2v (split-A: dst feats | means) ----
  {
    ushortT* Mbuf = (ushortT*)big;
    long long c1 = (long long)(avail / ((size_t)NREL*UDIM*2));
    int CH = (int)(c1 > 65536 ? 65536 : c1); CH &= ~127; if(CH < 128) CH = 128;
    for(int lo=0; lo<NITEMS; lo+=CH){
      int cn = imin(CH, NITEMS-lo);
      agg_m64_k<<<(cn+15)/16,256,0,stream>>>(xu_bf, edg, off_i + lo*NREL, Mbuf, cn);
      gemm2v_k<64,128,true,true><<<dim3(1,(cn+63)/64),256,0,stream>>>(
          xi_bf + (size_t)lo*UDIM, UDIM, Mbuf, NREL*UDIM, UDIM,
          BT1ui, 6*UDIM, b1_ui, h1i + (size_t)lo*HID, HID, cn);
    }
    for(int lo=0; lo<NUSERS; lo+=CH){
      int cn = imin(CH, NUSERS-lo);
      agg_m64_k<<<(cn+15)/16,256,0,stream>>>(xi_bf, edg, off_u + lo*NREL, Mbuf, cn);
      gemm2v_k<64,128,true,true><<<dim3(1,(cn+63)/64),256,0,stream>>>(
          xu_bf + (size_t)lo*UDIM, UDIM, Mbuf, NREL*UDIM, UDIM,
          BT1iu, 6*UDIM, b1_iu, h1u + (size_t)lo*HID, HID, cn);
    }
  }

  // ---- layer 2: phased H-scheme with A-resident multi-slice msg GEMM ----
  float* user2 = out;
  float* item2 = out + (size_t)NUSERS*ODIM;
  if(useH){
    // phase A: user->item messages + item root
    ushortT* Hmsg_u  = (ushortT*)big;                                        // [NUSERS][320]
    ushortT* Hroot_i = (ushortT*)(big + align256((size_t)NUSERS*NREL*ODIM*2)); // [NITEMS][64]
    gemmM_k<NREL><<<(NUSERS+63)/64,256,0,stream>>>(h1u, BTm2ui, Hmsg_u, NREL*ODIM, NUSERS);
    gemmM_k<1><<<(NITEMS+63)/64,256,0,stream>>>(h1i, BTr2ui, Hroot_i, ODIM, NITEMS);
    agg_h_k<<<(NITEMS+15)/16,256,0,stream>>>(Hmsg_u, NREL*ODIM, Hroot_i, ODIM,
        edg, off_i, b2_ui, item2, NITEMS);
    // phase B: item->user messages + user root (overlay)
    ushortT* Hmsg_i  = (ushortT*)big;                                        // [NITEMS][320]
    ushortT* Hroot_u = (ushortT*)(big + align256((size_t)NITEMS*NREL*ODIM*2)); // [NUSERS][64]
    gemmM_k<NREL><<<(NITEMS+63)/64,256,0,stream>>>(h1i, BTm2iu, Hmsg_i, NREL*ODIM, NITEMS);
    gemmM_k<1><<<(NUSERS+63)/64,256,0,stream>>>(h1u, BTr2iu, Hroot_u, ODIM, NUSERS);
    agg_h_k<<<(NUSERS+15)/16,256,0,stream>>>(Hmsg_i, NREL*ODIM, Hroot_u, ODIM,
        edg, off_u, b2_iu, user2, NUSERS);
  } else {
    // fallback M-scheme
    ushortT* Mbuf = (ushortT*)big;
    long long c2 = (long long)(avail / ((size_t)6*HID*2));
    int CH = (int)(c2 > NUSERS ? NUSERS : c2); CH &= ~127; if(CH < 128) CH = 128;
    for(int lo=0; lo<NITEMS; lo+=CH){
      int cn = imin(CH, NITEMS-lo);
      agg_m_k<HID><<<(cn+3)/4,256,0,stream>>>(h1u, h1i, edg, off_i, Mbuf, lo, cn);
      gemm2v_k<64,64,false,false><<<dim3(1,(cn+63)/64),256,0,stream>>>(
          Mbuf, 6*HID, Mbuf, 6*HID, 6*HID, BT2ui, 6*HID, b2_ui, item2 + (size_t)lo*ODIM, ODIM, cn);
    }
    for(int lo=0; lo<NUSERS; lo+=CH){
      int cn = imin(CH, NUSERS-lo);
      agg_m_k<HID><<<(cn+3)/4,256,0,stream>>>(h1i, h1u, edg, off_u, Mbuf, lo, cn);
      gemm2v_k<64,64,false,false><<<dim3(1,(cn+63)/64),256,0,stream>>>(
          Mbuf, 6*HID, Mbuf, 6*HID, 6*HID, BT2iu, 6*HID, b2_iu, user2 + (size_t)lo*ODIM, ODIM, cn);
    }
  }
}

// Round 13
// 550.030 us; speedup vs baseline: 1.3362x; 1.0034x over previous
//
#include <hip/hip_runtime.h>
#include <hip/hip_bf16.h>
#include <cstdint>
#include <cstddef>

#define NUSERS 200000
#define NITEMS 100000
#define UDIM 64
#define HID 128
#define ODIM 64
#define NREL 5

typedef unsigned short ushortT;
typedef __bf16 bf16x8 __attribute__((ext_vector_type(8)));
typedef __bf16 bf16x4p __attribute__((ext_vector_type(4)));
typedef float f32x4 __attribute__((ext_vector_type(4)));

static inline size_t align256(size_t x){ return (x + 255) & ~(size_t)255; }
static inline int imin(int a,int b){ return a<b?a:b; }

__device__ __forceinline__ unsigned short f2bf(float f){
  unsigned int u = __builtin_bit_cast(unsigned int, f);
  unsigned int r = (u + 0x7fffu + ((u>>16)&1u)) >> 16;   // RNE
  return (unsigned short)r;
}
__device__ __forceinline__ float b2f(unsigned short u){
  return __builtin_bit_cast(float, ((unsigned int)u)<<16);
}
__device__ __forceinline__ float blo(unsigned u){ return b2f((unsigned short)(u & 0xffff)); }
__device__ __forceinline__ float bhi(unsigned u){ return b2f((unsigned short)(u >> 16)); }
__device__ __forceinline__ uint2 pk4(float a, float b, float c, float d){
  bf16x4p t; t[0]=(__bf16)a; t[1]=(__bf16)b; t[2]=(__bf16)c; t[3]=(__bf16)d;
  return __builtin_bit_cast(uint2, t);
}
__device__ __forceinline__ void gld_lds16(const void* g, void* s){
  __builtin_amdgcn_global_load_lds((const __attribute__((address_space(1))) void*)g,
                                   (__attribute__((address_space(3))) void*)s, 16, 0, 0);
}

// ---------------- CSR build: ONE combined (node,relation) key space ----------------
// keys: item side [0, NI5), user side [NI5, NI5+NU5). edg sized 2E: {(peer<<3)|rel, scaleBits}.

__global__ void count_edges_k(const int* __restrict__ src, const int* __restrict__ dst,
                              const int* __restrict__ et, int E, int* __restrict__ cnt){
  int e = blockIdx.x*blockDim.x + threadIdx.x;
  if(e < E){
    int t = et[e];
    atomicAdd(&cnt[dst[e]*NREL + t], 1);
    atomicAdd(&cnt[NITEMS*NREL + src[e]*NREL + t], 1);
  }
}

__global__ __launch_bounds__(256) void scan_s1f(const int* __restrict__ c, int n, int* __restrict__ btot){
  int t = threadIdx.x;
  int base = blockIdx.x*2048 + t*8;
  int s = 0;
  #pragma unroll
  for(int j=0;j<8;++j){ int i = base+j; if(i<n) s += c[i]; }
  __shared__ int red[256];
  red[t] = s; __syncthreads();
  for(int o=128;o>0;o>>=1){ if(t<o) red[t]+=red[t+o]; __syncthreads(); }
  if(t==0) btot[blockIdx.x] = red[0];
}

__global__ __launch_bounds__(1024) void scan_s2(const int* __restrict__ btot, int nb,
                                                int* __restrict__ boff, int* __restrict__ total_out){
  __shared__ int sh[1024];
  int t = threadIdx.x;
  int v = (t<nb)? btot[t] : 0;
  sh[t] = v; __syncthreads();
  for(int o=1;o<1024;o<<=1){
    int add = (t>=o)? sh[t-o] : 0;
    __syncthreads();
    sh[t] += add;
    __syncthreads();
  }
  if(t<nb) boff[t] = sh[t]-v;
  if(t==1023) *total_out = sh[1023];
}

__global__ __launch_bounds__(256) void scan_s3f(const int* __restrict__ c, int n,
                                                const int* __restrict__ boff, int* __restrict__ off){
  int t = threadIdx.x, b = blockIdx.x;
  int base = b*2048 + t*8;
  int pre[8]; int s = 0;
  #pragma unroll
  for(int j=0;j<8;++j){
    int i = base+j; int d = (i<n)? c[i] : 0;
    pre[j] = s; s += d;
  }
  __shared__ int sh[256];
  sh[t] = s; __syncthreads();
  int inc = s;
  for(int o=1;o<256;o<<=1){
    int add = (t>=o)? sh[t-o] : 0;
    __syncthreads();
    sh[t] += add;
    __syncthreads();
  }
  int texcl = sh[t] - inc;
  int bo = boff[b];
  #pragma unroll
  for(int j=0;j<8;++j){
    int i = base+j;
    if(i<n) off[i] = bo + texcl + pre[j];
  }
}

__global__ void copy_int_k(const int* __restrict__ a, int* __restrict__ b, int n){
  int i = blockIdx.x*blockDim.x + threadIdx.x;
  if(i < n) b[i] = a[i];
}

// edg entries: {.x = (peer<<3)|rel, .y = bitcast(1/segment_count)}
__global__ void scatter_k(const int* __restrict__ src, const int* __restrict__ dst,
                          const int* __restrict__ et, int E,
                          int* __restrict__ cur, const int* __restrict__ off,
                          int2* __restrict__ edg){
  int e = blockIdx.x*blockDim.x + threadIdx.x;
  if(e < E){
    int s = src[e], d = dst[e], t = et[e];
    int k1 = d*NREL + t;
    int p1 = atomicAdd(&cur[k1], 1);
    edg[p1] = make_int2((s<<3)|t,
        __builtin_bit_cast(int, 1.f/(float)(off[k1+1]-off[k1])));
    int k2 = NITEMS*NREL + s*NREL + t;
    int p2 = atomicAdd(&cur[k2], 1);
    edg[p2] = make_int2((d<<3)|t,
        __builtin_bit_cast(int, 1.f/(float)(off[k2+1]-off[k2])));
  }
}

// ---------------- dtype prep ----------------

__global__ void f2bf4_k(const float4* __restrict__ a, uint2* __restrict__ b, int n4){
  int i = blockIdx.x*blockDim.x + threadIdx.x;
  if(i < n4){
    float4 v = a[i];
    uint2 o;
    o.x = (unsigned)f2bf(v.x) | ((unsigned)f2bf(v.y)<<16);
    o.y = (unsigned)f2bf(v.z) | ((unsigned)f2bf(v.w)<<16);
    b[i] = o;
  }
}

// BT[Dout][6*Din] = [root; W_0..W_4]^T   (layer-1 B)
__global__ void prep_bt_k(const float* __restrict__ root, const float* __restrict__ W,
                          ushortT* __restrict__ BT, int Din, int Dout){
  int K = 6*Din;
  int idx = blockIdx.x*blockDim.x + threadIdx.x;
  if(idx >= Dout*K) return;
  int n = idx / K, k = idx % K;
  float v = (k < Din) ? root[(size_t)k*Dout + n] : W[(size_t)(k-Din)*Dout + n];
  BT[idx] = f2bf(v);
}

// BTm[R*C][K] : row n -> W[n/C][k][n%C]   (layer-2 message weights, transposed)
__global__ void prep_w_k(const float* __restrict__ W, ushortT* __restrict__ BT,
                         int Kdim, int C, int total){
  int idx = blockIdx.x*blockDim.x + threadIdx.x;
  if(idx >= total) return;
  int n = idx / Kdim, k = idx % Kdim;
  int r = n / C, c = n % C;
  BT[idx] = f2bf(W[((size_t)r*Kdim + k)*C + c]);
}

// BTr[C][K] : row n -> root[k][n]
__global__ void prep_r_k(const float* __restrict__ root, ushortT* __restrict__ BT,
                         int Kdim, int C){
  int idx = blockIdx.x*blockDim.x + threadIdx.x;
  if(idx >= C*Kdim) return;
  int n = idx / Kdim, k = idx % Kdim;
  BT[idx] = f2bf(root[(size_t)k*C + n]);
}

// ---------------- layer-1 aggregation (D=64): 16-lane group per node, no shuffles ----------------

__global__ __launch_bounds__(256) void agg_m64_k(const ushortT* __restrict__ xsrc,
    const int2* __restrict__ edg, const int* __restrict__ off5,
    ushortT* __restrict__ Mbuf, int cn)
{
  int gid = blockIdx.x*blockDim.x + threadIdx.x;
  int wid = gid >> 4;
  int sub = gid & 15;
  if(wid >= cn) return;
  const int* op = off5 + wid*NREL;
  int offs[6];
  #pragma unroll
  for(int r=0;r<6;++r) offs[r] = op[r];
  ushortT* mp = Mbuf + (size_t)wid*(NREL*UDIM) + sub*4;
  const ushortT* xp = xsrc + sub*4;
  #pragma unroll
  for(int r=0;r<NREL;++r){
    int e0 = offs[r], e1 = offs[r+1];
    uint2 o = {0u, 0u};
    if(e1 > e0){
      float s0=0.f, s1=0.f, s2=0.f, s3=0.f;
      for(int e=e0; e<e1; ++e){
        int p = edg[e].x >> 3;
        uint2 u = *(const uint2*)(xp + (size_t)p*UDIM);
        s0 += blo(u.x); s1 += bhi(u.x); s2 += blo(u.y); s3 += bhi(u.y);
      }
      float scv = 1.f/(float)(e1-e0);
      o = pk4(s0*scv, s1*scv, s2*scv, s3*scv);
    }
    *(uint2*)(mp + r*UDIM) = o;
  }
}

// ---------------- layer-2 H aggregation: 16-lane group per node, no shuffles ----------------

__global__ __launch_bounds__(256) void agg_h_k(const ushortT* __restrict__ msg, int msgStride,
    const ushortT* __restrict__ root, int rootStride,
    const int2* __restrict__ edg, const int* __restrict__ off5,
    const float* __restrict__ bias, float* __restrict__ outp, int n)
{
  int gid = blockIdx.x*blockDim.x + threadIdx.x;
  int node = gid >> 4;
  int sub = gid & 15;
  if(node >= n) return;
  int e0 = off5[node*NREL], e1 = off5[node*NREL + NREL];
  float a0=0.f,a1=0.f,a2=0.f,a3=0.f;
  for(int e=e0; e<e1; ++e){
    int2 ed = edg[e];
    float scv = __builtin_bit_cast(float, ed.y);
    uint2 u = *(const uint2*)(msg + (size_t)(ed.x>>3)*msgStride + (ed.x&7)*ODIM + sub*4);
    a0 += blo(u.x)*scv; a1 += bhi(u.x)*scv; a2 += blo(u.y)*scv; a3 += bhi(u.y)*scv;
  }
  uint2 rt = *(const uint2*)(root + (size_t)node*rootStride + sub*4);
  float4 bv = *(const float4*)(bias + sub*4);
  float4 o;
  o.x = a0 + blo(rt.x) + bv.x;
  o.y = a1 + bhi(rt.x) + bv.y;
  o.z = a2 + blo(rt.y) + bv.z;
  o.w = a3 + bhi(rt.y) + bv.w;
  *(float4*)(outp + (size_t)node*ODIM + sub*4) = o;
}

// ---------------- fallback M-scheme agg (layer 2, only if ws too small) ----------------

template<int D>
__global__ __launch_bounds__(256) void agg_m_k(const ushortT* __restrict__ xsrc,
    const ushortT* __restrict__ xdst, const int2* __restrict__ edg,
    const int* __restrict__ off5, ushortT* __restrict__ Mbuf, int lo, int cn)
{
  int wid  = (int)((blockIdx.x*(size_t)blockDim.x + threadIdx.x) >> 6);
  int lane = threadIdx.x & 63;
  if(wid >= cn) return;
  int node = lo + wid;
  constexpr int V = D/64;
  ushortT* mp = Mbuf + (size_t)wid*(6*D);
  if(V==2) *(unsigned*)(mp + lane*2) = *(const unsigned*)(xdst + (size_t)node*D + lane*2);
  else     mp[lane] = xdst[(size_t)node*D + lane];
  #pragma unroll
  for(int r=0;r<NREL;++r){
    int base = node*NREL + r;
    int e0 = off5[base], e1 = off5[base+1];
    float s0 = 0.f, s1 = 0.f;
    for(int e=e0; e<e1; ++e){
      int p = edg[e].x >> 3;
      if(V==2){
        unsigned u = *(const unsigned*)(xsrc + (size_t)p*D + lane*2);
        s0 += blo(u); s1 += bhi(u);
      } else {
        s0 += b2f(xsrc[(size_t)p*D + lane]);
      }
    }
    int c = e1 - e0;
    float sc = 1.f/(float)(c>0? c:1);
    if(V==2){
      unsigned o = (unsigned)f2bf(s0*sc) | ((unsigned)f2bf(s1*sc)<<16);
      *(unsigned*)(mp + D + r*D + lane*2) = o;
    } else {
      mp[D + r*D + lane] = f2bf(s0*sc);
    }
  }
}

// ---------------- A-resident multi-slice GEMM (K=128): C[:, s*64..] = A @ BT_s^T ----------------
// A-tile staged once -> register fragments. All SL slice accumulators kept in registers
// (no stores inside the slice loop -> in-loop barriers only drain the B-prefetch).
// Full 16-slot swizzle for 256B rows (mask r&15) -> conflict-free ds_read_b128.

template<int SL>
__global__ __launch_bounds__(256) void gemmM_k(
    const ushortT* __restrict__ A,    // [M][128] bf16
    const ushortT* __restrict__ BT,   // [SL*64][128] bf16
    ushortT* __restrict__ C, int ldc, int M)
{
  constexpr int K = 128, ROWB = 256;
  __shared__ alignas(16) unsigned char sA[64*ROWB];
  __shared__ alignas(16) unsigned char sB[2][64*ROWB];
  const int tid = threadIdx.x;
  const int w = tid >> 6, l = tid & 63;
  const int wr = w >> 1, wc = w & 1;
  const int row0 = blockIdx.x * 64;

  // stage A tile (1024 x 16B chunks; linear LDS dest, inverse-swizzled source, mask 15)
  #pragma unroll
  for(int j=0;j<4;++j){
    int c = j*256 + tid;
    int r = c >> 4;                 // 16 chunks per 256B row
    int jb = (c & 15) * 16;
    int grow = row0 + r; grow = (grow < M) ? grow : (M-1);
    const unsigned char* gp = (const unsigned char*)(A + (size_t)grow*K) + (jb ^ ((r&15)<<4));
    gld_lds16(gp, sA + (size_t)(j*256 + w*64)*16);
  }
  auto stageB = [&](int buf, int s){
    const ushortT* Bp = BT + (size_t)s*64*K;
    #pragma unroll
    for(int j=0;j<4;++j){
      int c = j*256 + tid;
      int r = c >> 4;
      int jb = (c & 15) * 16;
      const unsigned char* gp = (const unsigned char*)(Bp + (size_t)r*K) + (jb ^ ((r&15)<<4));
      gld_lds16(gp, &sB[buf][(size_t)(j*256 + w*64)*16]);
    }
  };
  stageB(0, 0);
  __syncthreads();

  // hoist A fragments to registers (read LDS once)
  bf16x8 af[4][2];
  #pragma unroll
  for(int kk=0;kk<4;++kk){
    int cb = kk*64 + (l>>4)*16;
    #pragma unroll
    for(int i=0;i<2;++i){
      int r = wr*32 + i*16 + (l&15);
      af[kk][i] = *reinterpret_cast<const bf16x8*>(sA + (size_t)r*ROWB + (cb ^ ((r&15)<<4)));
    }
  }

  f32x4 acc[SL][2][2];
  #pragma unroll
  for(int s=0;s<SL;++s)
    #pragma unroll
    for(int i=0;i<2;++i)
      #pragma unroll
      for(int j=0;j<2;++j) acc[s][i][j] = (f32x4){0.f,0.f,0.f,0.f};

  int cur = 0;
  #pragma unroll
  for(int s=0; s<SL; ++s){
    if(s+1 < SL) stageB(cur^1, s+1);     // prefetch next slice under compute
    #pragma unroll
    for(int kk=0;kk<4;++kk){
      int cb = kk*64 + (l>>4)*16;
      bf16x8 bfr[2];
      #pragma unroll
      for(int j=0;j<2;++j){
        int cN = wc*32 + j*16 + (l&15);
        bfr[j] = *reinterpret_cast<const bf16x8*>(&sB[cur][(size_t)cN*ROWB + (cb ^ ((cN&15)<<4))]);
      }
      #pragma unroll
      for(int i=0;i<2;++i)
        #pragma unroll
        for(int j=0;j<2;++j)
          acc[s][i][j] = __builtin_amdgcn_mfma_f32_16x16x32_bf16(af[kk][i], bfr[j], acc[s][i][j], 0, 0, 0);
    }
    __syncthreads();   // drains prefetch only (no stores pending)
    cur ^= 1;
  }

  // single store phase (no intervening barriers -> stores fully pipelined)
  #pragma unroll
  for(int s=0;s<SL;++s){
    #pragma unroll
    for(int i=0;i<2;++i){
      #pragma unroll
      for(int rr=0;rr<4;++rr){
        int grow = row0 + wr*32 + i*16 + (l>>4)*4 + rr;
        if(grow >= M) continue;
        #pragma unroll
        for(int j=0;j<2;++j){
          int col = s*64 + wc*32 + j*16 + (l&15);
          C[(size_t)grow*ldc + col] = f2bf(acc[s][i][j][rr]);
        }
      }
    }
  }
}

// ---------------- bf16 MFMA GEMM: BM=64, dbuf K-loop (layer-1 + fallback) ----------------

template<int BM, int BN, bool OUTBF, bool RELU>
__global__ __launch_bounds__(256) void gemm2v_k(
    const ushortT* __restrict__ A0, int lda0,
    const ushortT* __restrict__ A1, int lda1, int KSPLIT,
    const ushortT* __restrict__ BT, int K,
    const float* __restrict__ bias,
    void* __restrict__ Cv, int ldc, int M)
{
  constexpr int WGC = (BN>=128)? 2 : 1;
  constexpr int WGR = 4/WGC;
  constexpr int FR  = BM/(16*WGR);
  constexpr int FC  = BN/(16*WGC);
  constexpr int ACH = BM*8;
  constexpr int BCH = BN*8;
  __shared__ alignas(16) unsigned char sA[2][BM*128];
  __shared__ alignas(16) unsigned char sB[2][BN*128];

  const int tid = threadIdx.x;
  const int w = tid >> 6, l = tid & 63;
  const int wr = w / WGC, wc = w % WGC;
  const int row0 = blockIdx.y * BM;
  const int col0 = blockIdx.x * BN;
  const ushortT* BTp = BT + (size_t)col0 * K;

  f32x4 acc[FR][FC];
  #pragma unroll
  for(int i=0;i<FR;++i)
    #pragma unroll
    for(int j=0;j<FC;++j) acc[i][j] = (f32x4){0.f,0.f,0.f,0.f};

  auto stage = [&](int buf, int k0){
    const ushortT* Ab = (k0 < KSPLIT) ? A0 : A1;
    const int ldab    = (k0 < KSPLIT) ? lda0 : lda1;
    const int kc      = (k0 < KSPLIT) ? k0 : (k0 - KSPLIT);
    #pragma unroll
    for(int j=0;j<ACH/256;++j){
      int c = j*256 + tid;
      int r = c >> 3;
      int jb = (c & 7) * 16;
      int grow = row0 + r; grow = (grow < M) ? grow : (M-1);
      const unsigned char* gp = (const unsigned char*)(Ab + (size_t)grow*ldab + kc) + (jb ^ ((r&7)<<4));
      gld_lds16(gp, &sA[buf][(j*256 + w*64)*16]);
    }
    #pragma unroll
    for(int j=0;j<BCH/256;++j){
      int c = j*256 + tid;
      int r = c >> 3;
      int jb = (c & 7) * 16;
      const unsigned char* gp = (const unsigned char*)(BTp + (size_t)r*K + k0) + (jb ^ ((r&7)<<4));
      gld_lds16(gp, &sB[buf][(j*256 + w*64)*16]);
    }
  };

  const int NT = K >> 6;
  stage(0, 0);
  __syncthreads();
  int cur = 0;
  for(int t=0; t<NT; ++t){
    if(t+1 < NT) stage(cur^1, (t+1)<<6);
    #pragma unroll
    for(int kk=0;kk<2;++kk){
      const int cb = kk*64 + (l>>4)*16;
      bf16x8 af[FR], bfr[FC];
      #pragma unroll
      for(int i=0;i<FR;++i){
        int r = wr*(16*FR) + i*16 + (l&15);
        af[i] = *reinterpret_cast<const bf16x8*>(&sA[cur][r*128 + (cb ^ ((r&7)<<4))]);
      }
      #pragma unroll
      for(int j=0;j<FC;++j){
        int c = wc*(16*FC) + j*16 + (l&15);
        bfr[j] = *reinterpret_cast<const bf16x8*>(&sB[cur][c*128 + (cb ^ ((c&7)<<4))]);
      }
      #pragma unroll
      for(int i=0;i<FR;++i)
        #pragma unroll
        for(int j=0;j<FC;++j)
          acc[i][j] = __builtin_amdgcn_mfma_f32_16x16x32_bf16(af[i], bfr[j], acc[i][j], 0, 0, 0);
    }
    __syncthreads();
    cur ^= 1;
  }
  #pragma unroll
  for(int i=0;i<FR;++i){
    #pragma unroll
    for(int rr=0;rr<4;++rr){
      int grow = row0 + wr*(16*FR) + i*16 + (l>>4)*4 + rr;
      if(grow >= M) continue;
      #pragma unroll
      for(int j=0;j<FC;++j){
        int col = col0 + wc*(16*FC) + j*16 + (l&15);
        float v = acc[i][j][rr];
        if(bias) v += bias[col];
        if(RELU) v = fmaxf(v, 0.f);
        if(OUTBF) ((ushortT*)Cv)[(size_t)grow*ldc + col] = f2bf(v);
        else      ((float*)Cv)[(size_t)grow*ldc + col] = v;
      }
    }
  }
}

// ---------------- host ----------------

extern "C" void kernel_launch(void* const* d_in, const int* in_sizes, int n_in,
                              void* d_out, int out_size, void* d_ws, size_t ws_size,
                              hipStream_t stream){
  const float* x_user   = (const float*)d_in[0];
  const float* x_item   = (const float*)d_in[1];
  const int*   ei       = (const int*)d_in[2];
  const int*   et       = (const int*)d_in[3];
  const float* W1_ui    = (const float*)d_in[4];
  const float* root1_ui = (const float*)d_in[5];
  const float* b1_ui    = (const float*)d_in[6];
  const float* W1_iu    = (const float*)d_in[7];
  const float* root1_iu = (const float*)d_in[8];
  const float* b1_iu    = (const float*)d_in[9];
  const float* W2_ui    = (const float*)d_in[10];
  const float* root2_ui = (const float*)d_in[11];
  const float* b2_ui    = (const float*)d_in[12];
  const float* W2_iu    = (const float*)d_in[13];
  const float* root2_iu = (const float*)d_in[14];
  const float* b2_iu    = (const float*)d_in[15];
  const int E = in_sizes[3];
  const int* src = ei;
  const int* dst = ei + E;
  float* out = (float*)d_out;

  const int NI5 = NITEMS*NREL, NU5 = NUSERS*NREL;
  const int NK5 = NI5 + NU5;

  uint8_t* ws = (uint8_t*)d_ws;
  size_t o = 0;
  auto alloc = [&](size_t bytes){ size_t r = o; o = align256(o + bytes); return r; };
  int* cnt  = (int*)(ws + alloc((size_t)NK5*4));
  int* off  = (int*)(ws + alloc((size_t)(NK5+1)*4));
  int* cur  = (int*)(ws + alloc((size_t)NK5*4));
  int2* edg = (int2*)(ws + alloc((size_t)2*E*8));
  int* btot = (int*)(ws + alloc(1024*4));
  int* boff = (int*)(ws + alloc(1024*4));
  ushortT* xu_bf = (ushortT*)(ws + alloc((size_t)NUSERS*UDIM*2));
  ushortT* xi_bf = (ushortT*)(ws + alloc((size_t)NITEMS*UDIM*2));
  ushortT* h1u   = (ushortT*)(ws + alloc((size_t)NUSERS*HID*2));
  ushortT* h1i   = (ushortT*)(ws + alloc((size_t)NITEMS*HID*2));
  ushortT* BT1ui = (ushortT*)(ws + alloc((size_t)HID*(6*UDIM)*2));
  ushortT* BT1iu = (ushortT*)(ws + alloc((size_t)HID*(6*UDIM)*2));
  ushortT* BTm2ui = (ushortT*)(ws + alloc((size_t)NREL*ODIM*HID*2));
  ushortT* BTm2iu = (ushortT*)(ws + alloc((size_t)NREL*ODIM*HID*2));
  ushortT* BTr2ui = (ushortT*)(ws + alloc((size_t)ODIM*HID*2));
  ushortT* BTr2iu = (ushortT*)(ws + alloc((size_t)ODIM*HID*2));
  ushortT* BT2ui = (ushortT*)(ws + alloc((size_t)ODIM*(6*HID)*2));   // M-fallback
  ushortT* BT2iu = (ushortT*)(ws + alloc((size_t)ODIM*(6*HID)*2));
  size_t bigoff = o;
  size_t avail = (ws_size > bigoff)? (ws_size - bigoff) : 0;
  uint8_t* big = ws + bigoff;

  const int* off_i = off;            // item-side segments
  const int* off_u = off + NI5;      // user-side segments

  size_t needH = align256((size_t)NUSERS*NREL*ODIM*2) + align256((size_t)NITEMS*ODIM*2);
  bool useH = (avail >= needH + 4096);

  // ---- CSR build (combined) ----
  hipMemsetAsync(cnt, 0, (size_t)NK5*4, stream);
  int eb = (E+255)/256;
  count_edges_k<<<eb,256,0,stream>>>(src,dst,et,E,cnt);
  int nb = (NK5+2047)/2048;
  scan_s1f<<<nb,256,0,stream>>>(cnt, NK5, btot);
  scan_s2<<<1,1024,0,stream>>>(btot, nb, boff, off+NK5);
  scan_s3f<<<nb,256,0,stream>>>(cnt, NK5, boff, off);
  copy_int_k<<<(NK5+255)/256,256,0,stream>>>(off, cur, NK5);
  scatter_k<<<eb,256,0,stream>>>(src,dst,et,E,cur,off,edg);

  // ---- dtype prep ----
  {
    int n4 = NUSERS*UDIM/4;
    f2bf4_k<<<(n4+255)/256,256,0,stream>>>((const float4*)x_user, (uint2*)xu_bf, n4);
    n4 = NITEMS*UDIM/4;
    f2bf4_k<<<(n4+255)/256,256,0,stream>>>((const float4*)x_item, (uint2*)xi_bf, n4);
  }
  prep_bt_k<<<(HID*6*UDIM+255)/256,256,0,stream>>>(root1_ui, W1_ui, BT1ui, UDIM, HID);
  prep_bt_k<<<(HID*6*UDIM+255)/256,256,0,stream>>>(root1_iu, W1_iu, BT1iu, UDIM, HID);
  if(useH){
    int tot = NREL*ODIM*HID;
    prep_w_k<<<(tot+255)/256,256,0,stream>>>(W2_ui, BTm2ui, HID, ODIM, tot);
    prep_w_k<<<(tot+255)/256,256,0,stream>>>(W2_iu, BTm2iu, HID, ODIM, tot);
    prep_r_k<<<(ODIM*HID+255)/256,256,0,stream>>>(root2_ui, BTr2ui, HID, ODIM);
    prep_r_k<<<(ODIM*HID+255)/256,256,0,stream>>>(root2_iu, BTr2iu, HID, ODIM);
  } else {
    prep_bt_k<<<(ODIM*6*HID+255)/256,256,0,stream>>>(root2_ui, W2_ui, BT2ui, HID, ODIM);
    prep_bt_k<<<(ODIM*6*HID+255)/256,256,0,stream>>>(root2_iu, W2_iu, BT2iu, HID, ODIM);
  }

  // ---- layer 1: M-scheme agg (no-shuffle) + gemm2v (split-A: dst feats | means) ----
  {
    ushortT* Mbuf = (ushortT*)big;
    long long c1 = (long long)(avail / ((size_t)NREL*UDIM*2));
    int CH = (int)(c1 > 65536 ? 65536 : c1); CH &= ~127; if(CH < 128) CH = 128;
    for(int lo=0; lo<NITEMS; lo+=CH){
      int cn = imin(CH, NITEMS-lo);
      agg_m64_k<<<(cn+15)/16,256,0,stream>>>(xu_bf, edg, off_i + lo*NREL, Mbuf, cn);
      gemm2v_k<64,128,true,true><<<dim3(1,(cn+63)/64),256,0,stream>>>(
          xi_bf + (size_t)lo*UDIM, UDIM, Mbuf, NREL*UDIM, UDIM,
          BT1ui, 6*UDIM, b1_ui, h1i + (size_t)lo*HID, HID, cn);
    }
    for(int lo=0; lo<NUSERS; lo+=CH){
      int cn = imin(CH, NUSERS-lo);
      agg_m64_k<<<(cn+15)/16,256,0,stream>>>(xi_bf, edg, off_u + lo*NREL, Mbuf, cn);
      gemm2v_k<64,128,true,true><<<dim3(1,(cn+63)/64),256,0,stream>>>(
          xu_bf + (size_t)lo*UDIM, UDIM, Mbuf, NREL*UDIM, UDIM,
          BT1iu, 6*UDIM, b1_iu, h1u + (size_t)lo*HID, HID, cn);
    }
  }

  // ---- layer 2: phased H-scheme with A-resident multi-slice msg GEMM ----
  float* user2 = out;
  float* item2 = out + (size_t)NUSERS*ODIM;
  if(useH){
    // phase A: user->item messages + item root
    ushortT* Hmsg_u  = (ushortT*)big;                                        // [NUSERS][320]
    ushortT* Hroot_i = (ushortT*)(big + align256((size_t)NUSERS*NREL*ODIM*2)); // [NITEMS][64]
    gemmM_k<NREL><<<(NUSERS+63)/64,256,0,stream>>>(h1u, BTm2ui, Hmsg_u, NREL*ODIM, NUSERS);
    gemmM_k<1><<<(NITEMS+63)/64,256,0,stream>>>(h1i, BTr2ui, Hroot_i, ODIM, NITEMS);
    agg_h_k<<<(NITEMS+15)/16,256,0,stream>>>(Hmsg_u, NREL*ODIM, Hroot_i, ODIM,
        edg, off_i, b2_ui, item2, NITEMS);
    // phase B: item->user messages + user root (overlay)
    ushortT* Hmsg_i  = (ushortT*)big;                                        // [NITEMS][320]
    ushortT* Hroot_u = (ushortT*)(big + align256((size_t)NITEMS*NREL*ODIM*2)); // [NUSERS][64]
    gemmM_k<NREL><<<(NITEMS+63)/64,256,0,stream>>>(h1i, BTm2iu, Hmsg_i, NREL*ODIM, NITEMS);
    gemmM_k<1><<<(NUSERS+63)/64,256,0,stream>>>(h1u, BTr2iu, Hroot_u, ODIM, NUSERS);
    agg_h_k<<<(NUSERS+15)/16,256,0,stream>>>(Hmsg_i, NREL*ODIM, Hroot_u, ODIM,
        edg, off_u, b2_iu, user2, NUSERS);
  } else {
    // fallback M-scheme
    ushortT* Mbuf = (ushortT*)big;
    long long c2 = (long long)(avail / ((size_t)6*HID*2));
    int CH = (int)(c2 > NUSERS ? NUSERS : c2); CH &= ~127; if(CH < 128) CH = 128;
    for(int lo=0; lo<NITEMS; lo+=CH){
      int cn = imin(CH, NITEMS-lo);
      agg_m_k<HID><<<(cn+3)/4,256,0,stream>>>(h1u, h1i, edg, off_i, Mbuf, lo, cn);
      gemm2v_k<64,64,false,false><<<dim3(1,(cn+63)/64),256,0,stream>>>(
          Mbuf, 6*HID, Mbuf, 6*HID, 6*HID, BT2ui, 6*HID, b2_ui, item2 + (size_t)lo*ODIM, ODIM, cn);
    }
    for(int lo=0; lo<NUSERS; lo+=CH){
      int cn = imin(CH, NUSERS-lo);
      agg_m_k<HID><<<(cn+3)/4,256,0,stream>>>(h1i, h1u, edg, off_u, Mbuf, lo, cn);
      gemm2v_k<64,64,false,false><<<dim3(1,(cn+63)/64),256,0,stream>>>(
          Mbuf, 6*HID, Mbuf, 6*HID, 6*HID, BT2iu, 6*HID, b2_iu, user2 + (size_t)lo*ODIM, ODIM, cn);
    }
  }
}